// Round 1
// baseline (21500.806 us; speedup 1.0000x reference)
//
#include <hip/hip_runtime.h>
#include <math.h>

// ---- problem constants ----
constexpr int Bv = 2, Tv = 2048, NTv = 512;
constexpr int DIMv = 768, DEPTHv = 8, MELv = 100, TDIMv = 512;
constexpr int DINNER = 1536, NSv = 128, PHv = 64, QQv = 64;
constexpr int NHv = DINNER / PHv;              // 24
constexpr int CONVD = DINNER + 2 * NSv;        // 1792
constexpr int DINP = 2 * DINNER + 2 * NSv + NHv; // 3352
constexpr int KCONVv = 4, FFIv = 2 * DIMv;     // 1536
constexpr int CNv = Tv / QQv;                  // 32

__device__ __forceinline__ float siluf(float x) { return x / (1.f + expf(-x)); }
__device__ __forceinline__ float softplusf(float x) { return x > 20.f ? x : log1pf(expf(x)); }
__device__ __forceinline__ float mishf(float x) { return x * tanhf(softplusf(x)); }

__device__ __forceinline__ float blockReduceSum(float v) {
    __shared__ float red[4];
    #pragma unroll
    for (int off = 32; off > 0; off >>= 1) v += __shfl_down(v, off, 64);
    __syncthreads();
    if ((threadIdx.x & 63) == 0) red[threadIdx.x >> 6] = v;
    __syncthreads();
    return red[0] + red[1] + red[2] + red[3];
}

// ---- generic tiled f32 GEMM: C[M,N] = A[M,K] @ W[K,N] (+bias)(+gelu) ----
// EPI: 0 = none, 1 = +bias, 2 = +bias then tanh-gelu
template <int EPI>
__global__ __launch_bounds__(256) void gemm_f32(const float* __restrict__ A,
                                                const float* __restrict__ W,
                                                const float* __restrict__ bias,
                                                float* __restrict__ C,
                                                int M, int N, int K) {
    constexpr int BM = 64, BN = 64, BK = 32;
    __shared__ float As[BK][BM + 1];
    __shared__ float Ws[BK][BN + 1];
    const int m0 = blockIdx.y * BM, n0 = blockIdx.x * BN;
    const int tid = threadIdx.x;
    const int tx = tid & 15, ty = tid >> 4;
    float acc[4][4] = {};
    for (int k0 = 0; k0 < K; k0 += BK) {
        {   // A tile: 64 rows x 32 k, 8 per thread
            int m = tid >> 2, kq = (tid & 3) * 8;
            #pragma unroll
            for (int i = 0; i < 8; i++) {
                int k = kq + i;
                float v = 0.f;
                if (m0 + m < M && k0 + k < K) v = A[(size_t)(m0 + m) * K + k0 + k];
                As[k][m] = v;
            }
        }
        {   // W tile: 32 k x 64 n, 8 per thread
            int k = tid >> 3, nq = (tid & 7) * 8;
            #pragma unroll
            for (int i = 0; i < 8; i++) {
                int n = nq + i;
                float v = 0.f;
                if (k0 + k < K && n0 + n < N) v = W[(size_t)(k0 + k) * N + n0 + n];
                Ws[k][n] = v;
            }
        }
        __syncthreads();
        #pragma unroll
        for (int kk = 0; kk < BK; kk++) {
            float a[4], w[4];
            #pragma unroll
            for (int i = 0; i < 4; i++) a[i] = As[kk][ty + i * 16];
            #pragma unroll
            for (int j = 0; j < 4; j++) w[j] = Ws[kk][tx + j * 16];
            #pragma unroll
            for (int i = 0; i < 4; i++)
                #pragma unroll
                for (int j = 0; j < 4; j++) acc[i][j] += a[i] * w[j];
        }
        __syncthreads();
    }
    #pragma unroll
    for (int i = 0; i < 4; i++) {
        int m = m0 + ty + i * 16;
        if (m >= M) continue;
        #pragma unroll
        for (int j = 0; j < 4; j++) {
            int n = n0 + tx + j * 16;
            if (n >= N) continue;
            float v = acc[i][j];
            if (EPI >= 1) v += bias[n];
            if (EPI == 2) {
                float xx = v;
                v = 0.5f * xx * (1.f + tanhf(0.7978845608028654f * (xx + 0.044715f * xx * xx * xx)));
            }
            C[(size_t)m * N + n] = v;
        }
    }
}

// ---- time embedding -> st = silu(tvec), one block ----
__global__ __launch_bounds__(256) void time_embed_kernel(const float* __restrict__ timev,
        const float* __restrict__ t_w1, const float* __restrict__ t_b1,
        const float* __restrict__ t_w2, const float* __restrict__ t_b2,
        float* __restrict__ st_out) {
    __shared__ float te[Bv][256];
    __shared__ float hid[Bv][DIMv];
    const int tid = threadIdx.x;
    for (int e = tid; e < Bv * 256; e += 256) {
        int b = e >> 8, j = e & 255;
        int f = j & 127;
        float fr = expf(-logf(10000.f) / 127.f * (float)f);
        float ang = 1000.f * timev[b] * fr;
        te[b][j] = (j < 128) ? sinf(ang) : cosf(ang);
    }
    __syncthreads();
    for (int e = tid; e < Bv * DIMv; e += 256) {
        int b = e / DIMv, o = e % DIMv;
        float acc = t_b1[o];
        for (int k = 0; k < 256; k++) acc += te[b][k] * t_w1[k * DIMv + o];
        hid[b][o] = siluf(acc);
    }
    __syncthreads();
    for (int e = tid; e < Bv * DIMv; e += 256) {
        int b = e / DIMv, o = e % DIMv;
        float acc = t_b2[o];
        for (int k = 0; k < DIMv; k++) acc += hid[b][k] * t_w2[k * DIMv + o];
        st_out[b * DIMv + o] = siluf(acc);
    }
}

// ---- concat [x, cond, temb] ----
__global__ void concat_kernel(const float* __restrict__ x, const float* __restrict__ cond,
                              const float* __restrict__ table, const int* __restrict__ text,
                              float* __restrict__ cat) {
    size_t i = (size_t)blockIdx.x * 256 + threadIdx.x;
    const size_t total = (size_t)Bv * Tv * (2 * MELv + TDIMv);
    if (i >= total) return;
    int j = (int)(i % (2 * MELv + TDIMv));
    size_t row = i / (2 * MELv + TDIMv);
    int t = (int)(row % Tv), b = (int)(row / Tv);
    float v;
    if (j < MELv) v = x[row * MELv + j];
    else if (j < 2 * MELv) v = cond[row * MELv + (j - MELv)];
    else {
        int idx = (t < NTv) ? (text[b * NTv + t] + 1) : 0;
        v = table[(size_t)idx * TDIMv + (j - 2 * MELv)];
    }
    cat[i] = v;
}

// ---- grouped conv1d K=31 pad 15 groups 16, optional mish ----
__global__ __launch_bounds__(256) void posconv_kernel(const float* __restrict__ in,
        const float* __restrict__ w, const float* __restrict__ bias,
        float* __restrict__ out, int apply_mish) {
    const int row = blockIdx.x;                  // b*T + t
    const int o = blockIdx.y * 256 + threadIdx.x;
    const int t = row % Tv, b = row / Tv;
    const int g = o / 48;
    const float* xb = in + (size_t)b * Tv * DIMv;
    float acc = bias[o];
    for (int k = 0; k < 31; k++) {
        int tt = t + k - 15;
        if (tt < 0 || tt >= Tv) continue;
        const float* xr = xb + (size_t)tt * DIMv + g * 48;
        const float* wr = w + (size_t)k * 48 * DIMv + o;
        #pragma unroll 4
        for (int ci = 0; ci < 48; ci++) acc += xr[ci] * wr[(size_t)ci * DIMv];
    }
    if (apply_mish) acc = mishf(acc);
    out[(size_t)row * DIMv + o] = acc;
}

__global__ void mish_add_kernel(float* __restrict__ h, const float* __restrict__ p, size_t n) {
    size_t i = (size_t)blockIdx.x * 256 + threadIdx.x;
    if (i >= n) return;
    h[i] += mishf(p[i]);
}

// ---- LayerNorm with adaLN modulation: out = ln(h)*(1+sc) + sh ----
__global__ __launch_bounds__(256) void ln_mod_kernel(const float* __restrict__ h,
        float* __restrict__ out, const float* __restrict__ modv,
        int sc_off, int sh_off, int mod_stride) {
    const int row = blockIdx.x;
    const int b = row / Tv;
    const float* hr = h + (size_t)row * DIMv;
    float s = 0.f;
    for (int j = threadIdx.x; j < DIMv; j += 256) s += hr[j];
    s = blockReduceSum(s);
    const float m = s / DIMv;
    float v = 0.f;
    for (int j = threadIdx.x; j < DIMv; j += 256) { float d = hr[j] - m; v += d * d; }
    v = blockReduceSum(v);
    const float rstd = rsqrtf(v / DIMv + 1e-6f);
    const float* mb = modv + (size_t)b * mod_stride;
    for (int j = threadIdx.x; j < DIMv; j += 256)
        out[(size_t)row * DIMv + j] = (hr[j] - m) * rstd * (1.f + mb[sc_off + j]) + mb[sh_off + j];
}

// ---- causal depthwise conv K=4 + silu on xBC slice of zxbcdt ----
__global__ void dwconv_kernel(const float* __restrict__ zx, const float* __restrict__ cw,
                              const float* __restrict__ cb, float* __restrict__ xbc) {
    size_t i = (size_t)blockIdx.x * 256 + threadIdx.x;
    if (i >= (size_t)Bv * Tv * CONVD) return;
    int c = (int)(i % CONVD);
    size_t row = i / CONVD;
    int t = (int)(row % Tv);
    const float* base = zx + row * DINP + DINNER + c;
    float acc = cb[c];
    #pragma unroll
    for (int k = 0; k < KCONVv; k++) {
        int d = k - 3;
        if (t + d >= 0) acc += base[(ptrdiff_t)d * DINP] * cw[c * KCONVv + k];
    }
    xbc[i] = siluf(acc);
}

// ---- dt = softplus(raw + bias) ----
__global__ void dt_kernel(const float* __restrict__ zx, const float* __restrict__ dt_bias,
                          float* __restrict__ dtb) {
    int i = blockIdx.x * 256 + threadIdx.x;
    if (i >= Bv * Tv * NHv) return;
    int hh = i % NHv;
    size_t row = (size_t)i / NHv;
    dtb[i] = softplusf(zx[row * DINP + DINNER + CONVD + hh] + dt_bias[hh]);
}

// ---- SSD part 1: per (b,c,h): cumsum, CB, y_in, chunk state S, acum/atot ----
__global__ __launch_bounds__(256) void ssd_part1(const float* __restrict__ xbc,
        const float* __restrict__ dtb, const float* __restrict__ A_log,
        float* __restrict__ ybuf, float* __restrict__ Sg,
        float* __restrict__ acg, float* __restrict__ atg) {
    const int h = blockIdx.x, c = blockIdx.y, b = blockIdx.z;
    __shared__ float xb[QQv][PHv + 1];
    __shared__ float CB[QQv][QQv + 1];
    __shared__ float Bh[QQv][QQv + 1];
    __shared__ float ac[QQv];
    __shared__ float dts[QQv];
    const int tid = threadIdx.x;
    const size_t rowbase = (size_t)b * Tv + (size_t)c * QQv;
    // xb[s][p] = dt[s] * x[s, h, p]
    for (int e = tid; e < QQv * PHv; e += 256) {
        int s = e >> 6, p = e & 63;
        size_t row = rowbase + s;
        float dt_ = dtb[row * NHv + h];
        xb[s][p] = dt_ * xbc[row * CONVD + h * PHv + p];
        if (p == 0) dts[s] = dt_;
    }
    __syncthreads();
    if (tid == 0) {
        float Ah = -expf(A_log[h]);
        float run = 0.f;
        for (int q = 0; q < QQv; q++) { run += dts[q] * Ah; ac[q] = run; }
    }
    __syncthreads();
    const size_t bch = ((size_t)b * CNv + c) * NHv + h;
    for (int q = tid; q < QQv; q += 256) acg[bch * QQv + q] = ac[q];
    if (tid == 0) atg[bch] = expf(ac[QQv - 1]);
    for (int e = tid; e < QQv * QQv; e += 256) CB[e >> 6][e & 63] = 0.f;
    // CB[q][s] = sum_n C[q,n]*B[s,n]  (two n-halves, B staged in LDS)
    for (int nh_ = 0; nh_ < 2; nh_++) {
        __syncthreads();
        for (int e = tid; e < QQv * QQv; e += 256) {
            int s = e >> 6, n = e & 63;
            Bh[s][n] = xbc[(rowbase + s) * CONVD + DINNER + nh_ * 64 + n];
        }
        __syncthreads();
        for (int e = tid; e < QQv * QQv; e += 256) {
            int q = e >> 6, s = e & 63;
            const float* Crow = &xbc[(rowbase + q) * CONVD + DINNER + NSv + nh_ * 64];
            float acc = 0.f;
            for (int n = 0; n < 64; n++) acc += Crow[n] * Bh[s][n];
            CB[q][s] += acc;
        }
    }
    __syncthreads();
    // y_in[q,p] = sum_{s<=q} CB[q][s] * exp(ac[q]-ac[s]) * xb[s][p]
    {
        int q = tid >> 2, pg = tid & 3;
        float acc[16];
        #pragma unroll
        for (int j = 0; j < 16; j++) acc[j] = 0.f;
        float aq = ac[q];
        for (int s = 0; s <= q; s++) {
            float w = CB[q][s] * expf(aq - ac[s]);
            #pragma unroll
            for (int j = 0; j < 16; j++) acc[j] += w * xb[s][pg * 16 + j];
        }
        size_t row = rowbase + q;
        #pragma unroll
        for (int j = 0; j < 16; j++)
            ybuf[row * DINNER + h * PHv + pg * 16 + j] = acc[j];
    }
    __syncthreads();
    // xb -> xbd = dst[s]*xb
    for (int e = tid; e < QQv * PHv; e += 256) {
        int s = e >> 6, p = e & 63;
        xb[s][p] *= expf(ac[QQv - 1] - ac[s]);
    }
    // S[p,n] = sum_q xbd[q][p]*B[q,n]
    for (int nh_ = 0; nh_ < 2; nh_++) {
        __syncthreads();
        for (int e = tid; e < QQv * QQv; e += 256) {
            int s = e >> 6, n = e & 63;
            Bh[s][n] = xbc[(rowbase + s) * CONVD + DINNER + nh_ * 64 + n];
        }
        __syncthreads();
        for (int e = tid; e < QQv * QQv; e += 256) {
            int p = e >> 6, n = e & 63;
            float acc = 0.f;
            for (int q = 0; q < QQv; q++) acc += xb[q][p] * Bh[q][n];
            Sg[bch * PHv * NSv + (size_t)p * NSv + nh_ * 64 + n] = acc;
        }
    }
}

// ---- inter-chunk scan: S -> prev (exclusive, decay atot) in place ----
__global__ void ssd_scan(float* __restrict__ Sg, const float* __restrict__ atg) {
    int idx = blockIdx.x * 256 + threadIdx.x;
    if (idx >= Bv * NHv * PHv * NSv) return;
    int n = idx % NSv;
    int p = (idx / NSv) % PHv;
    int h = (idx / (NSv * PHv)) % NHv;
    int b = idx / (NSv * PHv * NHv);
    float H = 0.f;
    for (int c = 0; c < CNv; c++) {
        size_t bch = ((size_t)b * CNv + c) * NHv + h;
        size_t off = bch * PHv * NSv + (size_t)p * NSv + n;
        float s = Sg[off];
        float at = atg[bch];
        Sg[off] = H;
        H = at * H + s;
    }
}

// ---- SSD part 2: y += (C[q]·prev[p,:]) * exp(ac[q]) + Dp*x ----
__global__ __launch_bounds__(256) void ssd_part2(const float* __restrict__ xbc,
        const float* __restrict__ Sg, const float* __restrict__ acg,
        const float* __restrict__ Dp, float* __restrict__ ybuf) {
    const int h = blockIdx.x, c = blockIdx.y, b = blockIdx.z;
    __shared__ float pv[PHv][NSv + 1];
    __shared__ float eac[QQv];
    const int tid = threadIdx.x;
    const size_t bch = ((size_t)b * CNv + c) * NHv + h;
    for (int e = tid; e < PHv * NSv; e += 256)
        pv[e >> 7][e & 127] = Sg[bch * PHv * NSv + e];
    for (int q = tid; q < QQv; q += 256) eac[q] = expf(acg[bch * QQv + q]);
    __syncthreads();
    const float Dh = Dp[h];
    const size_t rowbase = (size_t)b * Tv + (size_t)c * QQv;
    for (int e = tid; e < QQv * PHv; e += 256) {
        int q = e >> 6, p = e & 63;
        size_t row = rowbase + q;
        const float* Crow = &xbc[row * CONVD + DINNER + NSv];
        float acc = 0.f;
        for (int n = 0; n < NSv; n++) acc += Crow[n] * pv[p][n];
        float xpv = xbc[row * CONVD + h * PHv + p];
        size_t yi = row * DINNER + h * PHv + p;
        ybuf[yi] += acc * eac[q] + Dh * xpv;
    }
}

// ---- gate by silu(z), RMS norm, * rms_w (in place on y) ----
__global__ __launch_bounds__(256) void gate_rms_kernel(float* __restrict__ y,
        const float* __restrict__ zx, const float* __restrict__ rms_w) {
    const int row = blockIdx.x;
    float* yr = y + (size_t)row * DINNER;
    const float* zr = zx + (size_t)row * DINP;
    float local[6];
    float ss = 0.f;
    #pragma unroll
    for (int i = 0; i < 6; i++) {
        int j = threadIdx.x + i * 256;
        float v = yr[j] * siluf(zr[j]);
        local[i] = v;
        ss += v * v;
    }
    ss = blockReduceSum(ss);
    const float scale = rsqrtf(ss / DINNER + 1e-5f);
    #pragma unroll
    for (int i = 0; i < 6; i++) {
        int j = threadIdx.x + i * 256;
        yr[j] = local[i] * scale * rms_w[j];
    }
}

// ---- h += g[b,d] * t ----
__global__ void resid_add_kernel(float* __restrict__ h, const float* __restrict__ t,
                                 const float* __restrict__ modv, int goff, int mstride) {
    size_t i = (size_t)blockIdx.x * 256 + threadIdx.x;
    if (i >= (size_t)Bv * Tv * DIMv) return;
    int d = (int)(i % DIMv);
    int b = (int)(i / ((size_t)Tv * DIMv));
    h[i] += modv[(size_t)b * mstride + goff + d] * t[i];
}

extern "C" void kernel_launch(void* const* d_in, const int* in_sizes, int n_in,
                              void* d_out, int out_size, void* d_ws, size_t ws_size,
                              hipStream_t stream) {
    // input order: setup_inputs() dict order puts 'text' last (index 32);
    // defensively detect signature order (text at index 3, 1024 ints).
    int s3 = (in_sizes[3] == Bv * NTv) ? 1 : 0;
    const float* x      = (const float*)d_in[0];
    const float* cond   = (const float*)d_in[1];
    const float* timev  = (const float*)d_in[2];
    const int*   text   = (const int*)(s3 ? d_in[3] : d_in[32]);
    const float* table  = (const float*)d_in[3 + s3];
    const float* inp_w  = (const float*)d_in[4 + s3];
    const float* inp_b  = (const float*)d_in[5 + s3];
    const float* pos_w1 = (const float*)d_in[6 + s3];
    const float* pos_b1 = (const float*)d_in[7 + s3];
    const float* pos_w2 = (const float*)d_in[8 + s3];
    const float* pos_b2 = (const float*)d_in[9 + s3];
    const float* t_w1   = (const float*)d_in[10 + s3];
    const float* t_b1   = (const float*)d_in[11 + s3];
    const float* t_w2   = (const float*)d_in[12 + s3];
    const float* t_b2   = (const float*)d_in[13 + s3];
    const float* adaln_w= (const float*)d_in[14 + s3];
    const float* adaln_b= (const float*)d_in[15 + s3];
    const float* in_w   = (const float*)d_in[16 + s3];
    const float* conv_w = (const float*)d_in[17 + s3];
    const float* conv_b = (const float*)d_in[18 + s3];
    const float* dt_bias= (const float*)d_in[19 + s3];
    const float* A_log  = (const float*)d_in[20 + s3];
    const float* Dp     = (const float*)d_in[21 + s3];
    const float* rms_w  = (const float*)d_in[22 + s3];
    const float* out_w  = (const float*)d_in[23 + s3];
    const float* ff_w1  = (const float*)d_in[24 + s3];
    const float* ff_b1  = (const float*)d_in[25 + s3];
    const float* ff_w2  = (const float*)d_in[26 + s3];
    const float* ff_b2  = (const float*)d_in[27 + s3];
    const float* fin_w  = (const float*)d_in[28 + s3];
    const float* fin_b  = (const float*)d_in[29 + s3];
    const float* proj_w = (const float*)d_in[30 + s3];
    const float* proj_b = (const float*)d_in[31 + s3];

    // ---- workspace layout (floats) ----
    float* ws = (float*)d_ws;
    const size_t n_h = (size_t)Bv * Tv * DIMv;
    float* h_   = ws;
    float* xn_  = h_   + n_h;
    float* zx_  = xn_  + n_h;                       // B*T*3352; cat aliases here
    float* cat_ = zx_;
    float* xbc_ = zx_  + (size_t)Bv * Tv * DINP;    // B*T*1792; reused for ff1
    float* dtb_ = xbc_ + (size_t)Bv * Tv * CONVD;
    float* y_   = dtb_ + (size_t)Bv * Tv * NHv;
    float* tmp_ = y_   + (size_t)Bv * Tv * DINNER;
    float* S_   = tmp_ + n_h;
    float* ac_  = S_   + (size_t)Bv * CNv * NHv * PHv * NSv;
    float* at_  = ac_  + (size_t)Bv * CNv * NHv * QQv;
    float* st_  = at_  + (size_t)Bv * CNv * NHv;
    float* mod_ = st_  + Bv * DIMv;
    float* fm_  = mod_ + (size_t)DEPTHv * Bv * 6 * DIMv;

    const int MT = Bv * Tv; // 4096 rows

    // time embedding -> st
    time_embed_kernel<<<1, 256, 0, stream>>>(timev, t_w1, t_b1, t_w2, t_b2, st_);
    // adaLN mods for all layers + final modulation
    for (int l = 0; l < DEPTHv; l++)
        gemm_f32<1><<<dim3((6 * DIMv + 63) / 64, 1), 256, 0, stream>>>(
            st_, adaln_w + (size_t)l * DIMv * 6 * DIMv, adaln_b + (size_t)l * 6 * DIMv,
            mod_ + (size_t)l * Bv * 6 * DIMv, Bv, 6 * DIMv, DIMv);
    gemm_f32<1><<<dim3((2 * DIMv + 63) / 64, 1), 256, 0, stream>>>(
        st_, fin_w, fin_b, fm_, Bv, 2 * DIMv, DIMv);

    // input concat + projection
    concat_kernel<<<(unsigned)(((size_t)Bv * Tv * (2 * MELv + TDIMv) + 255) / 256), 256, 0, stream>>>(
        x, cond, table, text, cat_);
    gemm_f32<1><<<dim3((DIMv + 63) / 64, (MT + 63) / 64), 256, 0, stream>>>(
        cat_, inp_w, inp_b, h_, MT, DIMv, 2 * MELv + TDIMv);

    // positional conv block
    posconv_kernel<<<dim3(MT, 3), 256, 0, stream>>>(h_, pos_w1, pos_b1, xn_, 1);
    posconv_kernel<<<dim3(MT, 3), 256, 0, stream>>>(xn_, pos_w2, pos_b2, tmp_, 0);
    mish_add_kernel<<<(unsigned)((n_h + 255) / 256), 256, 0, stream>>>(h_, tmp_, n_h);

    for (int l = 0; l < DEPTHv; l++) {
        const float* modl = mod_ + (size_t)l * Bv * 6 * DIMv;
        // MSA branch
        ln_mod_kernel<<<MT, 256, 0, stream>>>(h_, xn_, modl, DIMv, 0, 6 * DIMv);
        gemm_f32<0><<<dim3((DINP + 63) / 64, (MT + 63) / 64), 256, 0, stream>>>(
            xn_, in_w + (size_t)l * DIMv * DINP, nullptr, zx_, MT, DINP, DIMv);
        dwconv_kernel<<<(unsigned)(((size_t)Bv * Tv * CONVD + 255) / 256), 256, 0, stream>>>(
            zx_, conv_w + (size_t)l * CONVD * KCONVv, conv_b + (size_t)l * CONVD, xbc_);
        dt_kernel<<<(Bv * Tv * NHv + 255) / 256, 256, 0, stream>>>(
            zx_, dt_bias + l * NHv, dtb_);
        ssd_part1<<<dim3(NHv, CNv, Bv), 256, 0, stream>>>(
            xbc_, dtb_, A_log + l * NHv, y_, S_, ac_, at_);
        ssd_scan<<<(Bv * NHv * PHv * NSv + 255) / 256, 256, 0, stream>>>(S_, at_);
        ssd_part2<<<dim3(NHv, CNv, Bv), 256, 0, stream>>>(
            xbc_, S_, ac_, Dp + l * NHv, y_);
        gate_rms_kernel<<<MT, 256, 0, stream>>>(y_, zx_, rms_w + (size_t)l * DINNER);
        gemm_f32<0><<<dim3((DIMv + 63) / 64, (MT + 63) / 64), 256, 0, stream>>>(
            y_, out_w + (size_t)l * DINNER * DIMv, nullptr, tmp_, MT, DIMv, DINNER);
        resid_add_kernel<<<(unsigned)((n_h + 255) / 256), 256, 0, stream>>>(
            h_, tmp_, modl, 2 * DIMv, 6 * DIMv);
        // MLP branch
        ln_mod_kernel<<<MT, 256, 0, stream>>>(h_, xn_, modl, 4 * DIMv, 3 * DIMv, 6 * DIMv);
        gemm_f32<2><<<dim3((FFIv + 63) / 64, (MT + 63) / 64), 256, 0, stream>>>(
            xn_, ff_w1 + (size_t)l * DIMv * FFIv, ff_b1 + (size_t)l * FFIv, xbc_, MT, FFIv, DIMv);
        gemm_f32<1><<<dim3((DIMv + 63) / 64, (MT + 63) / 64), 256, 0, stream>>>(
            xbc_, ff_w2 + (size_t)l * FFIv * DIMv, ff_b2 + (size_t)l * DIMv, tmp_, MT, DIMv, FFIv);
        resid_add_kernel<<<(unsigned)((n_h + 255) / 256), 256, 0, stream>>>(
            h_, tmp_, modl, 5 * DIMv, 6 * DIMv);
    }

    // final modulated LN + projection
    ln_mod_kernel<<<MT, 256, 0, stream>>>(h_, xn_, fm_, 0, DIMv, 2 * DIMv);
    gemm_f32<1><<<dim3((MELv + 63) / 64, (MT + 63) / 64), 256, 0, stream>>>(
        xn_, proj_w, proj_b, (float*)d_out, MT, MELv, DIMv);
}

// Round 2
// 9192.970 us; speedup vs baseline: 2.3388x; 2.3388x over previous
//
#include <hip/hip_runtime.h>
#include <math.h>

// ---- problem constants ----
constexpr int Bv = 2, Tv = 2048, NTv = 512;
constexpr int DIMv = 768, DEPTHv = 8, MELv = 100, TDIMv = 512;
constexpr int DINNER = 1536, NSv = 128, PHv = 64, QQv = 64;
constexpr int NHv = DINNER / PHv;              // 24
constexpr int CONVD = DINNER + 2 * NSv;        // 1792
constexpr int DINP = 2 * DINNER + 2 * NSv + NHv; // 3352
constexpr int KCONVv = 4, FFIv = 2 * DIMv;     // 1536
constexpr int CNv = Tv / QQv;                  // 32

typedef unsigned short u16;
typedef unsigned int u32;
typedef __attribute__((ext_vector_type(8))) short short8v;
typedef __attribute__((ext_vector_type(4))) float f32x4;

__device__ __forceinline__ float siluf(float x) { return x / (1.f + expf(-x)); }
__device__ __forceinline__ float softplusf(float x) { return x > 20.f ? x : log1pf(expf(x)); }
__device__ __forceinline__ float mishf(float x) { return x * tanhf(softplusf(x)); }

__device__ __forceinline__ u16 f2bf(float v) {
    u32 u = __builtin_bit_cast(u32, v);
    u32 r = (u + 0x7fffu + ((u >> 16) & 1u)) >> 16;
    return (u16)r;
}

__device__ __forceinline__ void gload16(const void* g, void* l) {
    __builtin_amdgcn_global_load_lds(
        (const __attribute__((address_space(1))) u32*)g,
        (__attribute__((address_space(3))) u32*)l, 16, 0, 0);
}

__device__ __forceinline__ float blockReduceSum(float v) {
    __shared__ float red[4];
    #pragma unroll
    for (int off = 32; off > 0; off >>= 1) v += __shfl_down(v, off, 64);
    __syncthreads();
    if ((threadIdx.x & 63) == 0) red[threadIdx.x >> 6] = v;
    __syncthreads();
    return red[0] + red[1] + red[2] + red[3];
}

// ---- generic tiled f32 GEMM (small matrices: adaln, input proj, final proj) ----
template <int EPI>  // 0 none, 1 +bias
__global__ __launch_bounds__(256) void gemm_f32(const float* __restrict__ A,
                                                const float* __restrict__ W,
                                                const float* __restrict__ bias,
                                                float* __restrict__ C,
                                                int M, int N, int K) {
    constexpr int BM = 64, BN = 64, BK = 32;
    __shared__ float As[BK][BM + 1];
    __shared__ float Ws[BK][BN + 1];
    const int m0 = blockIdx.y * BM, n0 = blockIdx.x * BN;
    const int tid = threadIdx.x;
    const int tx = tid & 15, ty = tid >> 4;
    float acc[4][4] = {};
    for (int k0 = 0; k0 < K; k0 += BK) {
        {
            int m = tid >> 2, kq = (tid & 3) * 8;
            #pragma unroll
            for (int i = 0; i < 8; i++) {
                int k = kq + i;
                float v = 0.f;
                if (m0 + m < M && k0 + k < K) v = A[(size_t)(m0 + m) * K + k0 + k];
                As[k][m] = v;
            }
        }
        {
            int k = tid >> 3, nq = (tid & 7) * 8;
            #pragma unroll
            for (int i = 0; i < 8; i++) {
                int n = nq + i;
                float v = 0.f;
                if (k0 + k < K && n0 + n < N) v = W[(size_t)(k0 + k) * N + n0 + n];
                Ws[k][n] = v;
            }
        }
        __syncthreads();
        #pragma unroll
        for (int kk = 0; kk < BK; kk++) {
            float a[4], w[4];
            #pragma unroll
            for (int i = 0; i < 4; i++) a[i] = As[kk][ty + i * 16];
            #pragma unroll
            for (int j = 0; j < 4; j++) w[j] = Ws[kk][tx + j * 16];
            #pragma unroll
            for (int i = 0; i < 4; i++)
                #pragma unroll
                for (int j = 0; j < 4; j++) acc[i][j] += a[i] * w[j];
        }
        __syncthreads();
    }
    #pragma unroll
    for (int i = 0; i < 4; i++) {
        int m = m0 + ty + i * 16;
        if (m >= M) continue;
        #pragma unroll
        for (int j = 0; j < 4; j++) {
            int n = n0 + tx + j * 16;
            if (n >= N) continue;
            float v = acc[i][j];
            if (EPI >= 1) v += bias[n];
            C[(size_t)m * N + n] = v;
        }
    }
}

// ---- bf16 MFMA GEMM, m97 structure: 128x128 tile, BK=32, global_load_lds 16B ----
// A [M,K] bf16 row-major, BT [Npad,K] bf16 (pre-transposed weight), C = A @ BT^T
// EPI: 0 = write f32, 1 = +bias write f32, 2 = +bias,gelu write bf16
template <int EPI>
__global__ __launch_bounds__(256) void gemm_bf16(const u16* __restrict__ A,
        const u16* __restrict__ BT, const float* __restrict__ bias,
        float* __restrict__ Cf, u16* __restrict__ Cb,
        int M, int N, int K, int ldc) {
    __shared__ __align__(16) u16 As[128 * 32];
    __shared__ __align__(16) u16 Bs[128 * 32];
    const int tid = threadIdx.x;
    const int m0 = blockIdx.y * 128, n0 = blockIdx.x * 128;
    const int lane = tid & 63;
    const int wid = tid >> 6;
    const int wm = (wid >> 1) * 64, wn = (wid & 1) * 64;
    f32x4 acc[4][4] = {};
    const int srow = tid >> 2, sseg = (tid & 3) * 8;
    const u16* Ag = A + (size_t)(m0 + srow) * K + sseg;
    const u16* Bg = BT + (size_t)(n0 + srow) * K + sseg;
    u16* Asl = As + tid * 8;   // 16B per lane, wave-uniform base + lane*16
    u16* Bsl = Bs + tid * 8;
    const int lr = lane & 15, lk = (lane >> 4) * 8;
    for (int k0 = 0; k0 < K; k0 += 32) {
        __syncthreads();  // protect LDS from previous iteration's readers
        gload16(Ag + k0, Asl);
        gload16(Ag + k0 + (size_t)64 * K, Asl + 64 * 32);
        gload16(Bg + k0, Bsl);
        gload16(Bg + k0 + (size_t)64 * K, Bsl + 64 * 32);
        __syncthreads();  // drains vmcnt before ds_read
        short8v a_f[4], b_f[4];
        #pragma unroll
        for (int i = 0; i < 4; i++)
            a_f[i] = *(const short8v*)&As[(wm + i * 16 + lr) * 32 + lk];
        #pragma unroll
        for (int j = 0; j < 4; j++)
            b_f[j] = *(const short8v*)&Bs[(wn + j * 16 + lr) * 32 + lk];
        #pragma unroll
        for (int i = 0; i < 4; i++)
            #pragma unroll
            for (int j = 0; j < 4; j++)
                acc[i][j] = __builtin_amdgcn_mfma_f32_16x16x32_bf16(a_f[i], b_f[j], acc[i][j], 0, 0, 0);
    }
    const int r0 = (lane >> 4) * 4;
    #pragma unroll
    for (int i = 0; i < 4; i++) {
        #pragma unroll
        for (int j = 0; j < 4; j++) {
            const int col = n0 + wn + j * 16 + lr;
            if (col >= N) continue;
            const int row = m0 + wm + i * 16 + r0;
            const float bv = (EPI >= 1) ? bias[col] : 0.f;
            #pragma unroll
            for (int r = 0; r < 4; r++) {
                float v = acc[i][j][r] + bv;
                if (EPI == 2) {
                    float xx = v;
                    v = 0.5f * xx * (1.f + tanhf(0.7978845608028654f * (xx + 0.044715f * xx * xx * xx)));
                    Cb[(size_t)(row + r) * ldc + col] = f2bf(v);
                } else {
                    Cf[(size_t)(row + r) * ldc + col] = v;
                }
            }
        }
    }
}

// ---- weight f32 [K,N] -> bf16 transposed [Npad,K], zero-fill n>=N ----
__global__ __launch_bounds__(256) void wt_convert(const float* __restrict__ W,
        u16* __restrict__ WT, int K, int N) {
    __shared__ float t[32][33];
    const int n0 = blockIdx.x * 32, k0 = blockIdx.y * 32;
    const int c = threadIdx.x & 31, rq = (threadIdx.x >> 5) * 4;
    #pragma unroll
    for (int i = 0; i < 4; i++) {
        int n = n0 + c;
        t[rq + i][c] = (n < N) ? W[(size_t)(k0 + rq + i) * N + n] : 0.f;
    }
    __syncthreads();
    #pragma unroll
    for (int i = 0; i < 4; i++)
        WT[(size_t)(n0 + rq + i) * K + k0 + c] = f2bf(t[c][rq + i]);
}

// ---- time embedding -> st = silu(tvec), one block ----
__global__ __launch_bounds__(256) void time_embed_kernel(const float* __restrict__ timev,
        const float* __restrict__ t_w1, const float* __restrict__ t_b1,
        const float* __restrict__ t_w2, const float* __restrict__ t_b2,
        float* __restrict__ st_out) {
    __shared__ float te[Bv][256];
    __shared__ float hid[Bv][DIMv];
    const int tid = threadIdx.x;
    for (int e = tid; e < Bv * 256; e += 256) {
        int b = e >> 8, j = e & 255;
        int f = j & 127;
        float fr = expf(-logf(10000.f) / 127.f * (float)f);
        float ang = 1000.f * timev[b] * fr;
        te[b][j] = (j < 128) ? sinf(ang) : cosf(ang);
    }
    __syncthreads();
    for (int e = tid; e < Bv * DIMv; e += 256) {
        int b = e / DIMv, o = e % DIMv;
        float acc = t_b1[o];
        for (int k = 0; k < 256; k++) acc += te[b][k] * t_w1[k * DIMv + o];
        hid[b][o] = siluf(acc);
    }
    __syncthreads();
    for (int e = tid; e < Bv * DIMv; e += 256) {
        int b = e / DIMv, o = e % DIMv;
        float acc = t_b2[o];
        for (int k = 0; k < DIMv; k++) acc += hid[b][k] * t_w2[k * DIMv + o];
        st_out[b * DIMv + o] = siluf(acc);
    }
}

// ---- concat [x, cond, temb] ----
__global__ void concat_kernel(const float* __restrict__ x, const float* __restrict__ cond,
                              const float* __restrict__ table, const int* __restrict__ text,
                              float* __restrict__ cat) {
    size_t i = (size_t)blockIdx.x * 256 + threadIdx.x;
    const size_t total = (size_t)Bv * Tv * (2 * MELv + TDIMv);
    if (i >= total) return;
    int j = (int)(i % (2 * MELv + TDIMv));
    size_t row = i / (2 * MELv + TDIMv);
    int t = (int)(row % Tv), b = (int)(row / Tv);
    float v;
    if (j < MELv) v = x[row * MELv + j];
    else if (j < 2 * MELv) v = cond[row * MELv + (j - MELv)];
    else {
        int idx = (t < NTv) ? (text[b * NTv + t] + 1) : 0;
        v = table[(size_t)idx * TDIMv + (j - 2 * MELv)];
    }
    cat[i] = v;
}

// ---- grouped conv1d K=31 pad 15 groups 16: LDS-staged, 4t x 3o register tile ----
__global__ __launch_bounds__(256) void posconv2(const float* __restrict__ in,
        const float* __restrict__ w, const float* __restrict__ bias,
        float* __restrict__ out, int apply_mish) {
    const int t0 = blockIdx.x * 64;
    const int g = blockIdx.y;
    const int b = blockIdx.z;
    __shared__ float xs[94][49];   // +1 pad: t-strided reads hit distinct banks
    __shared__ float wsh[48][48];
    const int tid = threadIdx.x;
    for (int e = tid; e < 94 * 48; e += 256) {
        int rr = e / 48, cc = e % 48;
        int t = t0 - 15 + rr;
        xs[rr][cc] = (t >= 0 && t < Tv) ? in[((size_t)b * Tv + t) * DIMv + g * 48 + cc] : 0.f;
    }
    const int ti = (tid >> 4) * 4;   // 0..60
    const int oi = (tid & 15) * 3;   // 0..45
    float acc[4][3] = {};
    for (int k = 0; k < 31; k++) {
        __syncthreads();
        for (int e = tid; e < 48 * 48; e += 256) {
            int ci = e / 48, oo = e % 48;
            wsh[ci][oo] = w[((size_t)k * 48 + ci) * DIMv + g * 48 + oo];
        }
        __syncthreads();
        #pragma unroll 8
        for (int ci = 0; ci < 48; ci++) {
            float w0 = wsh[ci][oi], w1 = wsh[ci][oi + 1], w2 = wsh[ci][oi + 2];
            #pragma unroll
            for (int i = 0; i < 4; i++) {
                float xv = xs[ti + i + k][ci];
                acc[i][0] += xv * w0;
                acc[i][1] += xv * w1;
                acc[i][2] += xv * w2;
            }
        }
    }
    #pragma unroll
    for (int i = 0; i < 4; i++)
        #pragma unroll
        for (int j = 0; j < 3; j++) {
            float v = acc[i][j] + bias[g * 48 + oi + j];
            if (apply_mish) v = mishf(v);
            out[((size_t)b * Tv + t0 + ti + i) * DIMv + g * 48 + oi + j] = v;
        }
}

__global__ void mish_add_kernel(float* __restrict__ h, const float* __restrict__ p, size_t n) {
    size_t i = (size_t)blockIdx.x * 256 + threadIdx.x;
    if (i >= n) return;
    h[i] += mishf(p[i]);
}

// ---- LayerNorm with adaLN modulation; BF=1 writes bf16 ----
template <int BF>
__global__ __launch_bounds__(256) void ln_mod_kernel(const float* __restrict__ h,
        void* __restrict__ outv, const float* __restrict__ modv,
        int sc_off, int sh_off, int mod_stride) {
    const int row = blockIdx.x;
    const int b = row / Tv;
    const float* hr = h + (size_t)row * DIMv;
    float s = 0.f;
    for (int j = threadIdx.x; j < DIMv; j += 256) s += hr[j];
    s = blockReduceSum(s);
    const float m = s / DIMv;
    float v = 0.f;
    for (int j = threadIdx.x; j < DIMv; j += 256) { float d = hr[j] - m; v += d * d; }
    v = blockReduceSum(v);
    const float rstd = rsqrtf(v / DIMv + 1e-6f);
    const float* mb = modv + (size_t)b * mod_stride;
    for (int j = threadIdx.x; j < DIMv; j += 256) {
        float val = (hr[j] - m) * rstd * (1.f + mb[sc_off + j]) + mb[sh_off + j];
        if (BF) ((u16*)outv)[(size_t)row * DIMv + j] = f2bf(val);
        else ((float*)outv)[(size_t)row * DIMv + j] = val;
    }
}

// ---- causal depthwise conv K=4 + silu on xBC slice of zxbcdt ----
__global__ void dwconv_kernel(const float* __restrict__ zx, const float* __restrict__ cw,
                              const float* __restrict__ cb, float* __restrict__ xbc) {
    size_t i = (size_t)blockIdx.x * 256 + threadIdx.x;
    if (i >= (size_t)Bv * Tv * CONVD) return;
    int c = (int)(i % CONVD);
    size_t row = i / CONVD;
    int t = (int)(row % Tv);
    const float* base = zx + row * DINP + DINNER + c;
    float acc = cb[c];
    #pragma unroll
    for (int k = 0; k < KCONVv; k++) {
        int d = k - 3;
        if (t + d >= 0) acc += base[(ptrdiff_t)d * DINP] * cw[c * KCONVv + k];
    }
    xbc[i] = siluf(acc);
}

// ---- dt = softplus(raw + bias) ----
__global__ void dt_kernel(const float* __restrict__ zx, const float* __restrict__ dt_bias,
                          float* __restrict__ dtb) {
    int i = blockIdx.x * 256 + threadIdx.x;
    if (i >= Bv * Tv * NHv) return;
    int hh = i % NHv;
    size_t row = (size_t)i / NHv;
    dtb[i] = softplusf(zx[row * DINP + DINNER + CONVD + hh] + dt_bias[hh]);
}

// ---- SSD part 1 ----
__global__ __launch_bounds__(256) void ssd_part1(const float* __restrict__ xbc,
        const float* __restrict__ dtb, const float* __restrict__ A_log,
        float* __restrict__ ybuf, float* __restrict__ Sg,
        float* __restrict__ acg, float* __restrict__ atg) {
    const int h = blockIdx.x, c = blockIdx.y, b = blockIdx.z;
    __shared__ float xb[QQv][PHv + 1];
    __shared__ float CB[QQv][QQv + 1];
    __shared__ float Bh[QQv][QQv + 1];
    __shared__ float ac[QQv];
    __shared__ float dts[QQv];
    const int tid = threadIdx.x;
    const size_t rowbase = (size_t)b * Tv + (size_t)c * QQv;
    for (int e = tid; e < QQv * PHv; e += 256) {
        int s = e >> 6, p = e & 63;
        size_t row = rowbase + s;
        float dt_ = dtb[row * NHv + h];
        xb[s][p] = dt_ * xbc[row * CONVD + h * PHv + p];
        if (p == 0) dts[s] = dt_;
    }
    __syncthreads();
    if (tid == 0) {
        float Ah = -expf(A_log[h]);
        float run = 0.f;
        for (int q = 0; q < QQv; q++) { run += dts[q] * Ah; ac[q] = run; }
    }
    __syncthreads();
    const size_t bch = ((size_t)b * CNv + c) * NHv + h;
    for (int q = tid; q < QQv; q += 256) acg[bch * QQv + q] = ac[q];
    if (tid == 0) atg[bch] = expf(ac[QQv - 1]);
    for (int e = tid; e < QQv * QQv; e += 256) CB[e >> 6][e & 63] = 0.f;
    for (int nh_ = 0; nh_ < 2; nh_++) {
        __syncthreads();
        for (int e = tid; e < QQv * QQv; e += 256) {
            int s = e >> 6, n = e & 63;
            Bh[s][n] = xbc[(rowbase + s) * CONVD + DINNER + nh_ * 64 + n];
        }
        __syncthreads();
        for (int e = tid; e < QQv * QQv; e += 256) {
            int q = e >> 6, s = e & 63;
            const float* Crow = &xbc[(rowbase + q) * CONVD + DINNER + NSv + nh_ * 64];
            float acc = 0.f;
            for (int n = 0; n < 64; n++) acc += Crow[n] * Bh[s][n];
            CB[q][s] += acc;
        }
    }
    __syncthreads();
    {
        int q = tid >> 2, pg = tid & 3;
        float acc[16];
        #pragma unroll
        for (int j = 0; j < 16; j++) acc[j] = 0.f;
        float aq = ac[q];
        for (int s = 0; s <= q; s++) {
            float w = CB[q][s] * expf(aq - ac[s]);
            #pragma unroll
            for (int j = 0; j < 16; j++) acc[j] += w * xb[s][pg * 16 + j];
        }
        size_t row = rowbase + q;
        #pragma unroll
        for (int j = 0; j < 16; j++)
            ybuf[row * DINNER + h * PHv + pg * 16 + j] = acc[j];
    }
    __syncthreads();
    for (int e = tid; e < QQv * PHv; e += 256) {
        int s = e >> 6, p = e & 63;
        xb[s][p] *= expf(ac[QQv - 1] - ac[s]);
    }
    for (int nh_ = 0; nh_ < 2; nh_++) {
        __syncthreads();
        for (int e = tid; e < QQv * QQv; e += 256) {
            int s = e >> 6, n = e & 63;
            Bh[s][n] = xbc[(rowbase + s) * CONVD + DINNER + nh_ * 64 + n];
        }
        __syncthreads();
        for (int e = tid; e < QQv * QQv; e += 256) {
            int p = e >> 6, n = e & 63;
            float acc = 0.f;
            for (int q = 0; q < QQv; q++) acc += xb[q][p] * Bh[q][n];
            Sg[bch * PHv * NSv + (size_t)p * NSv + nh_ * 64 + n] = acc;
        }
    }
}

// ---- inter-chunk scan ----
__global__ void ssd_scan(float* __restrict__ Sg, const float* __restrict__ atg) {
    int idx = blockIdx.x * 256 + threadIdx.x;
    if (idx >= Bv * NHv * PHv * NSv) return;
    int n = idx % NSv;
    int p = (idx / NSv) % PHv;
    int h = (idx / (NSv * PHv)) % NHv;
    int b = idx / (NSv * PHv * NHv);
    float H = 0.f;
    for (int c = 0; c < CNv; c++) {
        size_t bch = ((size_t)b * CNv + c) * NHv + h;
        size_t off = bch * PHv * NSv + (size_t)p * NSv + n;
        float s = Sg[off];
        float at = atg[bch];
        Sg[off] = H;
        H = at * H + s;
    }
}

// ---- SSD part 2 ----
__global__ __launch_bounds__(256) void ssd_part2(const float* __restrict__ xbc,
        const float* __restrict__ Sg, const float* __restrict__ acg,
        const float* __restrict__ Dp, float* __restrict__ ybuf) {
    const int h = blockIdx.x, c = blockIdx.y, b = blockIdx.z;
    __shared__ float pv[PHv][NSv + 1];
    __shared__ float eac[QQv];
    const int tid = threadIdx.x;
    const size_t bch = ((size_t)b * CNv + c) * NHv + h;
    for (int e = tid; e < PHv * NSv; e += 256)
        pv[e >> 7][e & 127] = Sg[bch * PHv * NSv + e];
    for (int q = tid; q < QQv; q += 256) eac[q] = expf(acg[bch * QQv + q]);
    __syncthreads();
    const float Dh = Dp[h];
    const size_t rowbase = (size_t)b * Tv + (size_t)c * QQv;
    for (int e = tid; e < QQv * PHv; e += 256) {
        int q = e >> 6, p = e & 63;
        size_t row = rowbase + q;
        const float* Crow = &xbc[row * CONVD + DINNER + NSv];
        float acc = 0.f;
        for (int n = 0; n < NSv; n++) acc += Crow[n] * pv[p][n];
        float xpv = xbc[row * CONVD + h * PHv + p];
        size_t yi = row * DINNER + h * PHv + p;
        ybuf[yi] += acc * eac[q] + Dh * xpv;
    }
}

// ---- gate by silu(z), RMS norm, * rms_w -> bf16 ----
__global__ __launch_bounds__(256) void gate_rms_kernel(const float* __restrict__ y,
        const float* __restrict__ zx, const float* __restrict__ rms_w,
        u16* __restrict__ yb) {
    const int row = blockIdx.x;
    const float* yr = y + (size_t)row * DINNER;
    const float* zr = zx + (size_t)row * DINP;
    float local[6];
    float ss = 0.f;
    #pragma unroll
    for (int i = 0; i < 6; i++) {
        int j = threadIdx.x + i * 256;
        float v = yr[j] * siluf(zr[j]);
        local[i] = v;
        ss += v * v;
    }
    ss = blockReduceSum(ss);
    const float scale = rsqrtf(ss / DINNER + 1e-5f);
    #pragma unroll
    for (int i = 0; i < 6; i++) {
        int j = threadIdx.x + i * 256;
        yb[(size_t)row * DINNER + j] = f2bf(local[i] * scale * rms_w[j]);
    }
}

// ---- h += g[b,d] * t ----
__global__ void resid_add_kernel(float* __restrict__ h, const float* __restrict__ t,
                                 const float* __restrict__ modv, int goff, int mstride) {
    size_t i = (size_t)blockIdx.x * 256 + threadIdx.x;
    if (i >= (size_t)Bv * Tv * DIMv) return;
    int d = (int)(i % DIMv);
    int b = (int)(i / ((size_t)Tv * DIMv));
    h[i] += modv[(size_t)b * mstride + goff + d] * t[i];
}

extern "C" void kernel_launch(void* const* d_in, const int* in_sizes, int n_in,
                              void* d_out, int out_size, void* d_ws, size_t ws_size,
                              hipStream_t stream) {
    int s3 = (in_sizes[3] == Bv * NTv) ? 1 : 0;
    const float* x      = (const float*)d_in[0];
    const float* cond   = (const float*)d_in[1];
    const float* timev  = (const float*)d_in[2];
    const int*   text   = (const int*)(s3 ? d_in[3] : d_in[32]);
    const float* table  = (const float*)d_in[3 + s3];
    const float* inp_w  = (const float*)d_in[4 + s3];
    const float* inp_b  = (const float*)d_in[5 + s3];
    const float* pos_w1 = (const float*)d_in[6 + s3];
    const float* pos_b1 = (const float*)d_in[7 + s3];
    const float* pos_w2 = (const float*)d_in[8 + s3];
    const float* pos_b2 = (const float*)d_in[9 + s3];
    const float* t_w1   = (const float*)d_in[10 + s3];
    const float* t_b1   = (const float*)d_in[11 + s3];
    const float* t_w2   = (const float*)d_in[12 + s3];
    const float* t_b2   = (const float*)d_in[13 + s3];
    const float* adaln_w= (const float*)d_in[14 + s3];
    const float* adaln_b= (const float*)d_in[15 + s3];
    const float* in_w   = (const float*)d_in[16 + s3];
    const float* conv_w = (const float*)d_in[17 + s3];
    const float* conv_b = (const float*)d_in[18 + s3];
    const float* dt_bias= (const float*)d_in[19 + s3];
    const float* A_log  = (const float*)d_in[20 + s3];
    const float* Dp     = (const float*)d_in[21 + s3];
    const float* rms_w  = (const float*)d_in[22 + s3];
    const float* out_w  = (const float*)d_in[23 + s3];
    const float* ff_w1  = (const float*)d_in[24 + s3];
    const float* ff_b1  = (const float*)d_in[25 + s3];
    const float* ff_w2  = (const float*)d_in[26 + s3];
    const float* ff_b2  = (const float*)d_in[27 + s3];
    const float* fin_w  = (const float*)d_in[28 + s3];
    const float* fin_b  = (const float*)d_in[29 + s3];
    const float* proj_w = (const float*)d_in[30 + s3];
    const float* proj_b = (const float*)d_in[31 + s3];

    // ---- workspace layout ----
    float* ws = (float*)d_ws;
    const size_t n_h = (size_t)Bv * Tv * DIMv;
    size_t off = 0;
    auto nx = [&](size_t n) { float* p = ws + off; off += n; return p; };
    float* h_   = nx(n_h);
    float* xn_  = nx(n_h);
    float* zx_  = nx((size_t)Bv * Tv * DINP);   // cat aliases here
    float* cat_ = zx_;
    float* xbc_ = nx((size_t)Bv * Tv * CONVD);
    float* dtb_ = nx((size_t)Bv * Tv * NHv);
    float* y_   = nx((size_t)Bv * Tv * DINNER);
    float* tmp_ = nx(n_h);
    float* S_   = nx((size_t)Bv * CNv * NHv * PHv * NSv);
    float* ac_  = nx((size_t)Bv * CNv * NHv * QQv);
    float* at_  = nx((size_t)Bv * CNv * NHv);
    float* st_  = nx((size_t)Bv * DIMv);
    float* mod_ = nx((size_t)DEPTHv * Bv * 6 * DIMv);
    float* fm_  = nx((size_t)Bv * 2 * DIMv);
    off = (off + 15) & ~(size_t)15;             // 64B align for bf16 region
    u16* wt_   = (u16*)(ws + off);              // max 3456*768
    u16* xnb_  = wt_  + (size_t)3456 * 768;     // 4096x768 bf16
    u16* actb_ = xnb_ + (size_t)4096 * 768;     // 4096x1536 bf16 (y_bf then ff1)

    const int MT = Bv * Tv; // 4096

    time_embed_kernel<<<1, 256, 0, stream>>>(timev, t_w1, t_b1, t_w2, t_b2, st_);
    for (int l = 0; l < DEPTHv; l++)
        gemm_f32<1><<<dim3((6 * DIMv + 63) / 64, 1), 256, 0, stream>>>(
            st_, adaln_w + (size_t)l * DIMv * 6 * DIMv, adaln_b + (size_t)l * 6 * DIMv,
            mod_ + (size_t)l * Bv * 6 * DIMv, Bv, 6 * DIMv, DIMv);
    gemm_f32<1><<<dim3((2 * DIMv + 63) / 64, 1), 256, 0, stream>>>(
        st_, fin_w, fin_b, fm_, Bv, 2 * DIMv, DIMv);

    concat_kernel<<<(unsigned)(((size_t)Bv * Tv * (2 * MELv + TDIMv) + 255) / 256), 256, 0, stream>>>(
        x, cond, table, text, cat_);
    gemm_f32<1><<<dim3((DIMv + 63) / 64, (MT + 63) / 64), 256, 0, stream>>>(
        cat_, inp_w, inp_b, h_, MT, DIMv, 2 * MELv + TDIMv);

    posconv2<<<dim3(Tv / 64, 16, Bv), 256, 0, stream>>>(h_, pos_w1, pos_b1, xn_, 1);
    posconv2<<<dim3(Tv / 64, 16, Bv), 256, 0, stream>>>(xn_, pos_w2, pos_b2, tmp_, 0);
    mish_add_kernel<<<(unsigned)((n_h + 255) / 256), 256, 0, stream>>>(h_, tmp_, n_h);

    for (int l = 0; l < DEPTHv; l++) {
        const float* modl = mod_ + (size_t)l * Bv * 6 * DIMv;
        // ---- MSA/SSD branch ----
        ln_mod_kernel<1><<<MT, 256, 0, stream>>>(h_, xnb_, modl, DIMv, 0, 6 * DIMv);
        wt_convert<<<dim3(3456 / 32, 768 / 32), 256, 0, stream>>>(
            in_w + (size_t)l * DIMv * DINP, wt_, DIMv, DINP);
        gemm_bf16<0><<<dim3(27, 32), 256, 0, stream>>>(
            xnb_, wt_, nullptr, zx_, nullptr, MT, DINP, DIMv, DINP);
        dwconv_kernel<<<(unsigned)(((size_t)Bv * Tv * CONVD + 255) / 256), 256, 0, stream>>>(
            zx_, conv_w + (size_t)l * CONVD * KCONVv, conv_b + (size_t)l * CONVD, xbc_);
        dt_kernel<<<(Bv * Tv * NHv + 255) / 256, 256, 0, stream>>>(
            zx_, dt_bias + l * NHv, dtb_);
        ssd_part1<<<dim3(NHv, CNv, Bv), 256, 0, stream>>>(
            xbc_, dtb_, A_log + l * NHv, y_, S_, ac_, at_);
        ssd_scan<<<(Bv * NHv * PHv * NSv + 255) / 256, 256, 0, stream>>>(S_, at_);
        ssd_part2<<<dim3(NHv, CNv, Bv), 256, 0, stream>>>(
            xbc_, S_, ac_, Dp + l * NHv, y_);
        gate_rms_kernel<<<MT, 256, 0, stream>>>(y_, zx_, rms_w + (size_t)l * DINNER, actb_);
        wt_convert<<<dim3(768 / 32, 1536 / 32), 256, 0, stream>>>(
            out_w + (size_t)l * DINNER * DIMv, wt_, DINNER, DIMv);
        gemm_bf16<0><<<dim3(6, 32), 256, 0, stream>>>(
            actb_, wt_, nullptr, tmp_, nullptr, MT, DIMv, DINNER, DIMv);
        resid_add_kernel<<<(unsigned)((n_h + 255) / 256), 256, 0, stream>>>(
            h_, tmp_, modl, 2 * DIMv, 6 * DIMv);
        // ---- MLP branch ----
        ln_mod_kernel<1><<<MT, 256, 0, stream>>>(h_, xnb_, modl, 4 * DIMv, 3 * DIMv, 6 * DIMv);
        wt_convert<<<dim3(1536 / 32, 768 / 32), 256, 0, stream>>>(
            ff_w1 + (size_t)l * DIMv * FFIv, wt_, DIMv, FFIv);
        gemm_bf16<2><<<dim3(12, 32), 256, 0, stream>>>(
            xnb_, wt_, ff_b1 + (size_t)l * FFIv, nullptr, actb_, MT, FFIv, DIMv, FFIv);
        wt_convert<<<dim3(768 / 32, 1536 / 32), 256, 0, stream>>>(
            ff_w2 + (size_t)l * FFIv * DIMv, wt_, FFIv, DIMv);
        gemm_bf16<1><<<dim3(6, 32), 256, 0, stream>>>(
            actb_, wt_, ff_b2 + (size_t)l * DIMv, tmp_, nullptr, MT, DIMv, FFIv, DIMv);
        resid_add_kernel<<<(unsigned)((n_h + 255) / 256), 256, 0, stream>>>(
            h_, tmp_, modl, 5 * DIMv, 6 * DIMv);
    }

    ln_mod_kernel<0><<<MT, 256, 0, stream>>>(h_, xn_, fm_, 0, DIMv, 2 * DIMv);
    gemm_f32<1><<<dim3((MELv + 63) / 64, (MT + 63) / 64), 256, 0, stream>>>(
        xn_, proj_w, proj_b, (float*)d_out, MT, MELv, DIMv);
}

// Round 3
// 4760.872 us; speedup vs baseline: 4.5161x; 1.9309x over previous
//
#include <hip/hip_runtime.h>
#include <math.h>

// ---- problem constants ----
constexpr int Bv = 2, Tv = 2048, NTv = 512;
constexpr int DIMv = 768, DEPTHv = 8, MELv = 100, TDIMv = 512;
constexpr int DINNER = 1536, NSv = 128, PHv = 64, QQv = 64;
constexpr int NHv = DINNER / PHv;              // 24
constexpr int CONVD = DINNER + 2 * NSv;        // 1792
constexpr int DINP = 2 * DINNER + 2 * NSv + NHv; // 3352
constexpr int KCONVv = 4, FFIv = 2 * DIMv;     // 1536
constexpr int CNv = Tv / QQv;                  // 32

typedef unsigned short u16;
typedef unsigned int u32;
typedef __attribute__((ext_vector_type(8))) short short8v;
typedef __attribute__((ext_vector_type(4))) float f32x4;

__device__ __forceinline__ float siluf(float x) { return x / (1.f + expf(-x)); }
__device__ __forceinline__ float softplusf(float x) { return x > 20.f ? x : log1pf(expf(x)); }
__device__ __forceinline__ float mishf(float x) { return x * tanhf(softplusf(x)); }

__device__ __forceinline__ u16 f2bf(float v) {
    u32 u = __builtin_bit_cast(u32, v);
    u32 r = (u + 0x7fffu + ((u >> 16) & 1u)) >> 16;
    return (u16)r;
}
__device__ __forceinline__ float bf2f(u16 v) {
    u32 u = (u32)v << 16;
    return __builtin_bit_cast(float, u);
}

__device__ __forceinline__ void gload16(const void* g, void* l) {
    __builtin_amdgcn_global_load_lds(
        (const __attribute__((address_space(1))) u32*)g,
        (__attribute__((address_space(3))) u32*)l, 16, 0, 0);
}

__device__ __forceinline__ float blockReduceSum(float v) {
    __shared__ float red[4];
    #pragma unroll
    for (int off = 32; off > 0; off >>= 1) v += __shfl_down(v, off, 64);
    __syncthreads();
    if ((threadIdx.x & 63) == 0) red[threadIdx.x >> 6] = v;
    __syncthreads();
    return red[0] + red[1] + red[2] + red[3];
}

// ---- generic tiled f32 GEMM (small matrices: adaln, input proj, final proj) ----
template <int EPI>  // 0 none, 1 +bias
__global__ __launch_bounds__(256) void gemm_f32(const float* __restrict__ A,
                                                const float* __restrict__ W,
                                                const float* __restrict__ bias,
                                                float* __restrict__ C,
                                                int M, int N, int K) {
    constexpr int BM = 64, BN = 64, BK = 32;
    __shared__ float As[BK][BM + 1];
    __shared__ float Ws[BK][BN + 1];
    const int m0 = blockIdx.y * BM, n0 = blockIdx.x * BN;
    const int tid = threadIdx.x;
    const int tx = tid & 15, ty = tid >> 4;
    float acc[4][4] = {};
    for (int k0 = 0; k0 < K; k0 += BK) {
        {
            int m = tid >> 2, kq = (tid & 3) * 8;
            #pragma unroll
            for (int i = 0; i < 8; i++) {
                int k = kq + i;
                float v = 0.f;
                if (m0 + m < M && k0 + k < K) v = A[(size_t)(m0 + m) * K + k0 + k];
                As[k][m] = v;
            }
        }
        {
            int k = tid >> 3, nq = (tid & 7) * 8;
            #pragma unroll
            for (int i = 0; i < 8; i++) {
                int n = nq + i;
                float v = 0.f;
                if (k0 + k < K && n0 + n < N) v = W[(size_t)(k0 + k) * N + n0 + n];
                Ws[k][n] = v;
            }
        }
        __syncthreads();
        #pragma unroll
        for (int kk = 0; kk < BK; kk++) {
            float a[4], w[4];
            #pragma unroll
            for (int i = 0; i < 4; i++) a[i] = As[kk][ty + i * 16];
            #pragma unroll
            for (int j = 0; j < 4; j++) w[j] = Ws[kk][tx + j * 16];
            #pragma unroll
            for (int i = 0; i < 4; i++)
                #pragma unroll
                for (int j = 0; j < 4; j++) acc[i][j] += a[i] * w[j];
        }
        __syncthreads();
    }
    #pragma unroll
    for (int i = 0; i < 4; i++) {
        int m = m0 + ty + i * 16;
        if (m >= M) continue;
        #pragma unroll
        for (int j = 0; j < 4; j++) {
            int n = n0 + tx + j * 16;
            if (n >= N) continue;
            float v = acc[i][j];
            if (EPI >= 1) v += bias[n];
            C[(size_t)m * N + n] = v;
        }
    }
}

// ---- bf16 MFMA GEMM, m97 structure ----
template <int EPI>  // 0 f32, 1 +bias f32, 2 +bias gelu bf16
__global__ __launch_bounds__(256) void gemm_bf16(const u16* __restrict__ A,
        const u16* __restrict__ BT, const float* __restrict__ bias,
        float* __restrict__ Cf, u16* __restrict__ Cb,
        int M, int N, int K, int ldc) {
    __shared__ __align__(16) u16 As[128 * 32];
    __shared__ __align__(16) u16 Bs[128 * 32];
    const int tid = threadIdx.x;
    const int m0 = blockIdx.y * 128, n0 = blockIdx.x * 128;
    const int lane = tid & 63;
    const int wid = tid >> 6;
    const int wm = (wid >> 1) * 64, wn = (wid & 1) * 64;
    f32x4 acc[4][4] = {};
    const int srow = tid >> 2, sseg = (tid & 3) * 8;
    const u16* Ag = A + (size_t)(m0 + srow) * K + sseg;
    const u16* Bg = BT + (size_t)(n0 + srow) * K + sseg;
    u16* Asl = As + tid * 8;
    u16* Bsl = Bs + tid * 8;
    const int lr = lane & 15, lk = (lane >> 4) * 8;
    for (int k0 = 0; k0 < K; k0 += 32) {
        __syncthreads();
        gload16(Ag + k0, Asl);
        gload16(Ag + k0 + (size_t)64 * K, Asl + 64 * 32);
        gload16(Bg + k0, Bsl);
        gload16(Bg + k0 + (size_t)64 * K, Bsl + 64 * 32);
        __syncthreads();
        short8v a_f[4], b_f[4];
        #pragma unroll
        for (int i = 0; i < 4; i++)
            a_f[i] = *(const short8v*)&As[(wm + i * 16 + lr) * 32 + lk];
        #pragma unroll
        for (int j = 0; j < 4; j++)
            b_f[j] = *(const short8v*)&Bs[(wn + j * 16 + lr) * 32 + lk];
        #pragma unroll
        for (int i = 0; i < 4; i++)
            #pragma unroll
            for (int j = 0; j < 4; j++)
                acc[i][j] = __builtin_amdgcn_mfma_f32_16x16x32_bf16(a_f[i], b_f[j], acc[i][j], 0, 0, 0);
    }
    const int r0 = (lane >> 4) * 4;
    #pragma unroll
    for (int i = 0; i < 4; i++) {
        #pragma unroll
        for (int j = 0; j < 4; j++) {
            const int col = n0 + wn + j * 16 + lr;
            if (col >= N) continue;
            const int row = m0 + wm + i * 16 + r0;
            const float bv = (EPI >= 1) ? bias[col] : 0.f;
            #pragma unroll
            for (int r = 0; r < 4; r++) {
                float v = acc[i][j][r] + bv;
                if (EPI == 2) {
                    float xx = v;
                    v = 0.5f * xx * (1.f + tanhf(0.7978845608028654f * (xx + 0.044715f * xx * xx * xx)));
                    Cb[(size_t)(row + r) * ldc + col] = f2bf(v);
                } else {
                    Cf[(size_t)(row + r) * ldc + col] = v;
                }
            }
        }
    }
}

// ---- weight f32 [K,N] -> bf16 transposed [Npad,K] ----
__global__ __launch_bounds__(256) void wt_convert(const float* __restrict__ W,
        u16* __restrict__ WT, int K, int N) {
    __shared__ float t[32][33];
    const int n0 = blockIdx.x * 32, k0 = blockIdx.y * 32;
    const int c = threadIdx.x & 31, rq = (threadIdx.x >> 5) * 4;
    #pragma unroll
    for (int i = 0; i < 4; i++) {
        int n = n0 + c;
        t[rq + i][c] = (n < N) ? W[(size_t)(k0 + rq + i) * N + n] : 0.f;
    }
    __syncthreads();
    #pragma unroll
    for (int i = 0; i < 4; i++)
        WT[(size_t)(n0 + rq + i) * K + k0 + c] = f2bf(t[c][rq + i]);
}

// ---- time embedding ----
__global__ __launch_bounds__(256) void time_embed_kernel(const float* __restrict__ timev,
        const float* __restrict__ t_w1, const float* __restrict__ t_b1,
        const float* __restrict__ t_w2, const float* __restrict__ t_b2,
        float* __restrict__ st_out) {
    __shared__ float te[Bv][256];
    __shared__ float hid[Bv][DIMv];
    const int tid = threadIdx.x;
    for (int e = tid; e < Bv * 256; e += 256) {
        int b = e >> 8, j = e & 255;
        int f = j & 127;
        float fr = expf(-logf(10000.f) / 127.f * (float)f);
        float ang = 1000.f * timev[b] * fr;
        te[b][j] = (j < 128) ? sinf(ang) : cosf(ang);
    }
    __syncthreads();
    for (int e = tid; e < Bv * DIMv; e += 256) {
        int b = e / DIMv, o = e % DIMv;
        float acc = t_b1[o];
        for (int k = 0; k < 256; k++) acc += te[b][k] * t_w1[k * DIMv + o];
        hid[b][o] = siluf(acc);
    }
    __syncthreads();
    for (int e = tid; e < Bv * DIMv; e += 256) {
        int b = e / DIMv, o = e % DIMv;
        float acc = t_b2[o];
        for (int k = 0; k < DIMv; k++) acc += hid[b][k] * t_w2[k * DIMv + o];
        st_out[b * DIMv + o] = siluf(acc);
    }
}

// ---- concat [x, cond, temb] ----
__global__ void concat_kernel(const float* __restrict__ x, const float* __restrict__ cond,
                              const float* __restrict__ table, const int* __restrict__ text,
                              float* __restrict__ cat) {
    size_t i = (size_t)blockIdx.x * 256 + threadIdx.x;
    const size_t total = (size_t)Bv * Tv * (2 * MELv + TDIMv);
    if (i >= total) return;
    int j = (int)(i % (2 * MELv + TDIMv));
    size_t row = i / (2 * MELv + TDIMv);
    int t = (int)(row % Tv), b = (int)(row / Tv);
    float v;
    if (j < MELv) v = x[row * MELv + j];
    else if (j < 2 * MELv) v = cond[row * MELv + (j - MELv)];
    else {
        int idx = (t < NTv) ? (text[b * NTv + t] + 1) : 0;
        v = table[(size_t)idx * TDIMv + (j - 2 * MELv)];
    }
    cat[i] = v;
}

// ---- grouped conv1d K=31 ----
__global__ __launch_bounds__(256) void posconv2(const float* __restrict__ in,
        const float* __restrict__ w, const float* __restrict__ bias,
        float* __restrict__ out, int apply_mish) {
    const int t0 = blockIdx.x * 64;
    const int g = blockIdx.y;
    const int b = blockIdx.z;
    __shared__ float xs[94][49];
    __shared__ float wsh[48][48];
    const int tid = threadIdx.x;
    for (int e = tid; e < 94 * 48; e += 256) {
        int rr = e / 48, cc = e % 48;
        int t = t0 - 15 + rr;
        xs[rr][cc] = (t >= 0 && t < Tv) ? in[((size_t)b * Tv + t) * DIMv + g * 48 + cc] : 0.f;
    }
    const int ti = (tid >> 4) * 4;
    const int oi = (tid & 15) * 3;
    float acc[4][3] = {};
    for (int k = 0; k < 31; k++) {
        __syncthreads();
        for (int e = tid; e < 48 * 48; e += 256) {
            int ci = e / 48, oo = e % 48;
            wsh[ci][oo] = w[((size_t)k * 48 + ci) * DIMv + g * 48 + oo];
        }
        __syncthreads();
        #pragma unroll 8
        for (int ci = 0; ci < 48; ci++) {
            float w0 = wsh[ci][oi], w1 = wsh[ci][oi + 1], w2 = wsh[ci][oi + 2];
            #pragma unroll
            for (int i = 0; i < 4; i++) {
                float xv = xs[ti + i + k][ci];
                acc[i][0] += xv * w0;
                acc[i][1] += xv * w1;
                acc[i][2] += xv * w2;
            }
        }
    }
    #pragma unroll
    for (int i = 0; i < 4; i++)
        #pragma unroll
        for (int j = 0; j < 3; j++) {
            float v = acc[i][j] + bias[g * 48 + oi + j];
            if (apply_mish) v = mishf(v);
            out[((size_t)b * Tv + t0 + ti + i) * DIMv + g * 48 + oi + j] = v;
        }
}

__global__ void mish_add_kernel(float* __restrict__ h, const float* __restrict__ p, size_t n) {
    size_t i = (size_t)blockIdx.x * 256 + threadIdx.x;
    if (i >= n) return;
    h[i] += mishf(p[i]);
}

// ---- LayerNorm with adaLN modulation; BF=1 writes bf16 ----
template <int BF>
__global__ __launch_bounds__(256) void ln_mod_kernel(const float* __restrict__ h,
        void* __restrict__ outv, const float* __restrict__ modv,
        int sc_off, int sh_off, int mod_stride) {
    const int row = blockIdx.x;
    const int b = row / Tv;
    const float* hr = h + (size_t)row * DIMv;
    float s = 0.f;
    for (int j = threadIdx.x; j < DIMv; j += 256) s += hr[j];
    s = blockReduceSum(s);
    const float m = s / DIMv;
    float v = 0.f;
    for (int j = threadIdx.x; j < DIMv; j += 256) { float d = hr[j] - m; v += d * d; }
    v = blockReduceSum(v);
    const float rstd = rsqrtf(v / DIMv + 1e-6f);
    const float* mb = modv + (size_t)b * mod_stride;
    for (int j = threadIdx.x; j < DIMv; j += 256) {
        float val = (hr[j] - m) * rstd * (1.f + mb[sc_off + j]) + mb[sh_off + j];
        if (BF) ((u16*)outv)[(size_t)row * DIMv + j] = f2bf(val);
        else ((float*)outv)[(size_t)row * DIMv + j] = val;
    }
}

// ---- causal depthwise conv K=4 + silu ----
__global__ void dwconv_kernel(const float* __restrict__ zx, const float* __restrict__ cw,
                              const float* __restrict__ cb, float* __restrict__ xbc) {
    size_t i = (size_t)blockIdx.x * 256 + threadIdx.x;
    if (i >= (size_t)Bv * Tv * CONVD) return;
    int c = (int)(i % CONVD);
    size_t row = i / CONVD;
    int t = (int)(row % Tv);
    const float* base = zx + row * DINP + DINNER + c;
    float acc = cb[c];
    #pragma unroll
    for (int k = 0; k < KCONVv; k++) {
        int d = k - 3;
        if (t + d >= 0) acc += base[(ptrdiff_t)d * DINP] * cw[c * KCONVv + k];
    }
    xbc[i] = siluf(acc);
}

// ---- dt = softplus(raw + bias) ----
__global__ void dt_kernel(const float* __restrict__ zx, const float* __restrict__ dt_bias,
                          float* __restrict__ dtb) {
    int i = blockIdx.x * 256 + threadIdx.x;
    if (i >= Bv * Tv * NHv) return;
    int hh = i % NHv;
    size_t row = (size_t)i / NHv;
    dtb[i] = softplusf(zx[row * DINP + DINNER + CONVD + hh] + dt_bias[hh]);
}

// ---- SSD: CB[q][s] = sum_n C[q,n]*B[s,n], h-independent, MFMA ----
__global__ __launch_bounds__(256) void ssd_cb(const float* __restrict__ xbc,
                                              float* __restrict__ CBg) {
    constexpr int ST = 136;   // 128 + 8 pad (16B-aligned rows, conflict-free b128 reads)
    __shared__ __align__(16) u16 Cs[64 * ST];
    __shared__ __align__(16) u16 Bs[64 * ST];
    const int c = blockIdx.x, b = blockIdx.y;
    const int tid = threadIdx.x;
    const size_t rowbase = (size_t)b * Tv + (size_t)c * QQv;
    for (int e = tid; e < 64 * 128; e += 256) {
        int r = e >> 7, n = e & 127;
        const float* src = &xbc[(rowbase + r) * CONVD + DINNER];
        Bs[r * ST + n] = f2bf(src[n]);
        Cs[r * ST + n] = f2bf(src[NSv + n]);
    }
    __syncthreads();
    const int lane = tid & 63, w = tid >> 6;
    const int lr = lane & 15, lk8 = (lane >> 4) * 8, rq = (lane >> 4) * 4;
    f32x4 acc[4] = {};
    #pragma unroll
    for (int ks = 0; ks < 4; ks++) {
        short8v a = *(const short8v*)&Cs[(w * 16 + lr) * ST + ks * 32 + lk8];
        #pragma unroll
        for (int j = 0; j < 4; j++) {
            short8v bf = *(const short8v*)&Bs[(j * 16 + lr) * ST + ks * 32 + lk8];
            acc[j] = __builtin_amdgcn_mfma_f32_16x16x32_bf16(a, bf, acc[j], 0, 0, 0);
        }
    }
    float* out = CBg + ((size_t)(b * CNv + c)) * 4096;
    #pragma unroll
    for (int j = 0; j < 4; j++)
        #pragma unroll
        for (int r = 0; r < 4; r++)
            out[(w * 16 + rq + r) * 64 + j * 16 + lr] = acc[j][r];
}

// ---- SSD part1: prefix-scan, y_in = (CB.exp-decay masked) @ xb, S = xbd^T @ B ----
__global__ __launch_bounds__(256) void ssd_part1m(const float* __restrict__ xbc,
        const float* __restrict__ dtb, const float* __restrict__ A_log,
        const float* __restrict__ CBg, float* __restrict__ ybuf,
        float* __restrict__ Sg, float* __restrict__ acg, float* __restrict__ atg) {
    constexpr int ST64 = 72;  // 64 + 8 pad
    __shared__ __align__(16) u16 xbT[64 * ST64];   // [p][s]
    __shared__ __align__(16) u16 Wsm[64 * ST64];   // [q][s]
    __shared__ __align__(16) u16 BT[128 * ST64];   // [n][s]
    __shared__ float ac[64], dts[64], erev[64];
    const int h = blockIdx.x, c = blockIdx.y, b = blockIdx.z;
    const int tid = threadIdx.x;
    const size_t rowbase = (size_t)b * Tv + (size_t)c * QQv;
    const size_t bch = ((size_t)b * CNv + c) * NHv + h;
    // wave-parallel prefix scan of dt*A (wave 0)
    if (tid < 64) {
        float dtv = dtb[(rowbase + tid) * NHv + h];
        dts[tid] = dtv;
        float v = dtv * (-expf(A_log[h]));
        #pragma unroll
        for (int off = 1; off < 64; off <<= 1) {
            float t = __shfl_up(v, off, 64);
            if (tid >= off) v += t;
        }
        ac[tid] = v;
    }
    __syncthreads();
    const float ac63 = ac[63];
    if (tid < 64) {
        erev[tid] = expf(ac63 - ac[tid]);
        acg[bch * 64 + tid] = ac[tid];
        if (tid == 63) atg[bch] = expf(ac63);
    }
    // xbT[p][s] = bf16(dt[s] * x[s][p])
    for (int e = tid; e < 64 * 64; e += 256) {
        int s = e >> 6, p = e & 63;
        xbT[p * ST64 + s] = f2bf(dts[s] * xbc[(rowbase + s) * CONVD + h * PHv + p]);
    }
    // BT[n][s]
    for (int e = tid; e < 64 * 128; e += 256) {
        int s = e >> 7, n = e & 127;
        BT[n * ST64 + s] = f2bf(xbc[(rowbase + s) * CONVD + DINNER + n]);
    }
    // W[q][s] = s<=q ? CB[q][s]*exp(ac[q]-ac[s]) : 0
    {
        const float* cbrow = CBg + ((size_t)(b * CNv + c)) * 4096;
        for (int e = tid; e < 64 * 64; e += 256) {
            int q = e >> 6, s = e & 63;
            float wv = (s <= q) ? cbrow[e] * expf(ac[q] - ac[s]) : 0.f;
            Wsm[q * ST64 + s] = f2bf(wv);
        }
    }
    __syncthreads();
    const int lane = tid & 63, w = tid >> 6;
    const int lr = lane & 15, lk8 = (lane >> 4) * 8, rq = (lane >> 4) * 4;
    // y_in: each wave computes 64q x 16p (p = w*16..)
    {
        f32x4 acc[4] = {};
        #pragma unroll
        for (int ks = 0; ks < 2; ks++) {
            short8v bf = *(const short8v*)&xbT[(w * 16 + lr) * ST64 + ks * 32 + lk8];
            #pragma unroll
            for (int i = 0; i < 4; i++) {
                short8v a = *(const short8v*)&Wsm[(i * 16 + lr) * ST64 + ks * 32 + lk8];
                acc[i] = __builtin_amdgcn_mfma_f32_16x16x32_bf16(a, bf, acc[i], 0, 0, 0);
            }
        }
        #pragma unroll
        for (int i = 0; i < 4; i++)
            #pragma unroll
            for (int r = 0; r < 4; r++) {
                int q = i * 16 + rq + r, p = w * 16 + lr;
                ybuf[(rowbase + q) * DINNER + h * PHv + p] = acc[i][r];
            }
    }
    __syncthreads();
    // xbT -> decayed in place: *= exp(ac63 - ac[s])
    for (int e = tid; e < 64 * 64; e += 256) {
        int p = e >> 6, s = e & 63;
        xbT[p * ST64 + s] = f2bf(bf2f(xbT[p * ST64 + s]) * erev[s]);
    }
    __syncthreads();
    // S[p][n] = sum_q xbd[q][p]*B[q][n]; each wave: 64p x 32n
    {
        f32x4 acc[4][2] = {};
        #pragma unroll
        for (int ks = 0; ks < 2; ks++) {
            short8v a[4];
            #pragma unroll
            for (int i = 0; i < 4; i++)
                a[i] = *(const short8v*)&xbT[(i * 16 + lr) * ST64 + ks * 32 + lk8];
            #pragma unroll
            for (int j = 0; j < 2; j++) {
                short8v bf = *(const short8v*)&BT[(w * 32 + j * 16 + lr) * ST64 + ks * 32 + lk8];
                #pragma unroll
                for (int i = 0; i < 4; i++)
                    acc[i][j] = __builtin_amdgcn_mfma_f32_16x16x32_bf16(a[i], bf, acc[i][j], 0, 0, 0);
            }
        }
        float* So = Sg + bch * (PHv * NSv);
        #pragma unroll
        for (int i = 0; i < 4; i++)
            #pragma unroll
            for (int j = 0; j < 2; j++)
                #pragma unroll
                for (int r = 0; r < 4; r++)
                    So[(i * 16 + rq + r) * NSv + w * 32 + j * 16 + lr] = acc[i][j][r];
    }
}

// ---- inter-chunk scan ----
__global__ void ssd_scan(float* __restrict__ Sg, const float* __restrict__ atg) {
    int idx = blockIdx.x * 256 + threadIdx.x;
    if (idx >= Bv * NHv * PHv * NSv) return;
    int n = idx % NSv;
    int p = (idx / NSv) % PHv;
    int h = (idx / (NSv * PHv)) % NHv;
    int b = idx / (NSv * PHv * NHv);
    float H = 0.f;
    for (int c = 0; c < CNv; c++) {
        size_t bch = ((size_t)b * CNv + c) * NHv + h;
        size_t off = bch * PHv * NSv + (size_t)p * NSv + n;
        float s = Sg[off];
        float at = atg[bch];
        Sg[off] = H;
        H = at * H + s;
    }
}

// ---- SSD part2: y += (C @ prev^T)*eac + D*x, MFMA K=128 ----
__global__ __launch_bounds__(256) void ssd_part2m(const float* __restrict__ xbc,
        const float* __restrict__ Sg, const float* __restrict__ acg,
        const float* __restrict__ Dp, float* __restrict__ ybuf) {
    constexpr int ST = 136;
    __shared__ __align__(16) u16 Cs[64 * ST];   // [q][n]
    __shared__ __align__(16) u16 Ps[64 * ST];   // [p][n]
    __shared__ float eac[64];
    const int h = blockIdx.x, c = blockIdx.y, b = blockIdx.z;
    const int tid = threadIdx.x;
    const size_t rowbase = (size_t)b * Tv + (size_t)c * QQv;
    const size_t bch = ((size_t)b * CNv + c) * NHv + h;
    if (tid < 64) eac[tid] = expf(acg[bch * 64 + tid]);
    for (int e = tid; e < 64 * 128; e += 256) {
        int r = e >> 7, n = e & 127;
        Cs[r * ST + n] = f2bf(xbc[(rowbase + r) * CONVD + DINNER + NSv + n]);
        Ps[r * ST + n] = f2bf(Sg[bch * (PHv * NSv) + e]);
    }
    __syncthreads();
    const int lane = tid & 63, w = tid >> 6;
    const int lr = lane & 15, lk8 = (lane >> 4) * 8, rq = (lane >> 4) * 4;
    f32x4 acc[4] = {};
    #pragma unroll
    for (int ks = 0; ks < 4; ks++) {
        short8v bf = *(const short8v*)&Ps[(w * 16 + lr) * ST + ks * 32 + lk8];
        #pragma unroll
        for (int i = 0; i < 4; i++) {
            short8v a = *(const short8v*)&Cs[(i * 16 + lr) * ST + ks * 32 + lk8];
            acc[i] = __builtin_amdgcn_mfma_f32_16x16x32_bf16(a, bf, acc[i], 0, 0, 0);
        }
    }
    const float Dh = Dp[h];
    #pragma unroll
    for (int i = 0; i < 4; i++)
        #pragma unroll
        for (int r = 0; r < 4; r++) {
            int q = i * 16 + rq + r, p = w * 16 + lr;
            size_t row = rowbase + q;
            size_t yi = row * DINNER + h * PHv + p;
            float xv = xbc[row * CONVD + h * PHv + p];
            ybuf[yi] += acc[i][r] * eac[q] + Dh * xv;
        }
}

// ---- gate by silu(z), RMS norm, * rms_w -> bf16 ----
__global__ __launch_bounds__(256) void gate_rms_kernel(const float* __restrict__ y,
        const float* __restrict__ zx, const float* __restrict__ rms_w,
        u16* __restrict__ yb) {
    const int row = blockIdx.x;
    const float* yr = y + (size_t)row * DINNER;
    const float* zr = zx + (size_t)row * DINP;
    float local[6];
    float ss = 0.f;
    #pragma unroll
    for (int i = 0; i < 6; i++) {
        int j = threadIdx.x + i * 256;
        float v = yr[j] * siluf(zr[j]);
        local[i] = v;
        ss += v * v;
    }
    ss = blockReduceSum(ss);
    const float scale = rsqrtf(ss / DINNER + 1e-5f);
    #pragma unroll
    for (int i = 0; i < 6; i++) {
        int j = threadIdx.x + i * 256;
        yb[(size_t)row * DINNER + j] = f2bf(local[i] * scale * rms_w[j]);
    }
}

// ---- h += g[b,d] * t ----
__global__ void resid_add_kernel(float* __restrict__ h, const float* __restrict__ t,
                                 const float* __restrict__ modv, int goff, int mstride) {
    size_t i = (size_t)blockIdx.x * 256 + threadIdx.x;
    if (i >= (size_t)Bv * Tv * DIMv) return;
    int d = (int)(i % DIMv);
    int b = (int)(i / ((size_t)Tv * DIMv));
    h[i] += modv[(size_t)b * mstride + goff + d] * t[i];
}

extern "C" void kernel_launch(void* const* d_in, const int* in_sizes, int n_in,
                              void* d_out, int out_size, void* d_ws, size_t ws_size,
                              hipStream_t stream) {
    int s3 = (in_sizes[3] == Bv * NTv) ? 1 : 0;
    const float* x      = (const float*)d_in[0];
    const float* cond   = (const float*)d_in[1];
    const float* timev  = (const float*)d_in[2];
    const int*   text   = (const int*)(s3 ? d_in[3] : d_in[32]);
    const float* table  = (const float*)d_in[3 + s3];
    const float* inp_w  = (const float*)d_in[4 + s3];
    const float* inp_b  = (const float*)d_in[5 + s3];
    const float* pos_w1 = (const float*)d_in[6 + s3];
    const float* pos_b1 = (const float*)d_in[7 + s3];
    const float* pos_w2 = (const float*)d_in[8 + s3];
    const float* pos_b2 = (const float*)d_in[9 + s3];
    const float* t_w1   = (const float*)d_in[10 + s3];
    const float* t_b1   = (const float*)d_in[11 + s3];
    const float* t_w2   = (const float*)d_in[12 + s3];
    const float* t_b2   = (const float*)d_in[13 + s3];
    const float* adaln_w= (const float*)d_in[14 + s3];
    const float* adaln_b= (const float*)d_in[15 + s3];
    const float* in_w   = (const float*)d_in[16 + s3];
    const float* conv_w = (const float*)d_in[17 + s3];
    const float* conv_b = (const float*)d_in[18 + s3];
    const float* dt_bias= (const float*)d_in[19 + s3];
    const float* A_log  = (const float*)d_in[20 + s3];
    const float* Dp     = (const float*)d_in[21 + s3];
    const float* rms_w  = (const float*)d_in[22 + s3];
    const float* out_w  = (const float*)d_in[23 + s3];
    const float* ff_w1  = (const float*)d_in[24 + s3];
    const float* ff_b1  = (const float*)d_in[25 + s3];
    const float* ff_w2  = (const float*)d_in[26 + s3];
    const float* ff_b2  = (const float*)d_in[27 + s3];
    const float* fin_w  = (const float*)d_in[28 + s3];
    const float* fin_b  = (const float*)d_in[29 + s3];
    const float* proj_w = (const float*)d_in[30 + s3];
    const float* proj_b = (const float*)d_in[31 + s3];

    // ---- workspace layout ----
    float* ws = (float*)d_ws;
    const size_t n_h = (size_t)Bv * Tv * DIMv;
    size_t off = 0;
    auto nx = [&](size_t n) { float* p = ws + off; off += n; return p; };
    float* h_   = nx(n_h);
    float* xn_  = nx(n_h);
    float* zx_  = nx((size_t)Bv * Tv * DINP);
    float* cat_ = zx_;
    float* xbc_ = nx((size_t)Bv * Tv * CONVD);
    float* dtb_ = nx((size_t)Bv * Tv * NHv);
    float* y_   = nx((size_t)Bv * Tv * DINNER);
    float* tmp_ = nx(n_h);
    float* S_   = nx((size_t)Bv * CNv * NHv * PHv * NSv);
    float* ac_  = nx((size_t)Bv * CNv * NHv * QQv);
    float* at_  = nx((size_t)Bv * CNv * NHv);
    float* CB_  = nx((size_t)Bv * CNv * QQv * QQv);
    float* st_  = nx((size_t)Bv * DIMv);
    float* mod_ = nx((size_t)DEPTHv * Bv * 6 * DIMv);
    float* fm_  = nx((size_t)Bv * 2 * DIMv);
    off = (off + 15) & ~(size_t)15;
    u16* wt_   = (u16*)(ws + off);
    u16* xnb_  = wt_  + (size_t)3456 * 768;
    u16* actb_ = xnb_ + (size_t)4096 * 768;

    const int MT = Bv * Tv;

    time_embed_kernel<<<1, 256, 0, stream>>>(timev, t_w1, t_b1, t_w2, t_b2, st_);
    for (int l = 0; l < DEPTHv; l++)
        gemm_f32<1><<<dim3((6 * DIMv + 63) / 64, 1), 256, 0, stream>>>(
            st_, adaln_w + (size_t)l * DIMv * 6 * DIMv, adaln_b + (size_t)l * 6 * DIMv,
            mod_ + (size_t)l * Bv * 6 * DIMv, Bv, 6 * DIMv, DIMv);
    gemm_f32<1><<<dim3((2 * DIMv + 63) / 64, 1), 256, 0, stream>>>(
        st_, fin_w, fin_b, fm_, Bv, 2 * DIMv, DIMv);

    concat_kernel<<<(unsigned)(((size_t)Bv * Tv * (2 * MELv + TDIMv) + 255) / 256), 256, 0, stream>>>(
        x, cond, table, text, cat_);
    gemm_f32<1><<<dim3((DIMv + 63) / 64, (MT + 63) / 64), 256, 0, stream>>>(
        cat_, inp_w, inp_b, h_, MT, DIMv, 2 * MELv + TDIMv);

    posconv2<<<dim3(Tv / 64, 16, Bv), 256, 0, stream>>>(h_, pos_w1, pos_b1, xn_, 1);
    posconv2<<<dim3(Tv / 64, 16, Bv), 256, 0, stream>>>(xn_, pos_w2, pos_b2, tmp_, 0);
    mish_add_kernel<<<(unsigned)((n_h + 255) / 256), 256, 0, stream>>>(h_, tmp_, n_h);

    for (int l = 0; l < DEPTHv; l++) {
        const float* modl = mod_ + (size_t)l * Bv * 6 * DIMv;
        // ---- MSA/SSD branch ----
        ln_mod_kernel<1><<<MT, 256, 0, stream>>>(h_, xnb_, modl, DIMv, 0, 6 * DIMv);
        wt_convert<<<dim3(3456 / 32, 768 / 32), 256, 0, stream>>>(
            in_w + (size_t)l * DIMv * DINP, wt_, DIMv, DINP);
        gemm_bf16<0><<<dim3(27, 32), 256, 0, stream>>>(
            xnb_, wt_, nullptr, zx_, nullptr, MT, DINP, DIMv, DINP);
        dwconv_kernel<<<(unsigned)(((size_t)Bv * Tv * CONVD + 255) / 256), 256, 0, stream>>>(
            zx_, conv_w + (size_t)l * CONVD * KCONVv, conv_b + (size_t)l * CONVD, xbc_);
        dt_kernel<<<(Bv * Tv * NHv + 255) / 256, 256, 0, stream>>>(
            zx_, dt_bias + l * NHv, dtb_);
        ssd_cb<<<dim3(CNv, Bv), 256, 0, stream>>>(xbc_, CB_);
        ssd_part1m<<<dim3(NHv, CNv, Bv), 256, 0, stream>>>(
            xbc_, dtb_, A_log + l * NHv, CB_, y_, S_, ac_, at_);
        ssd_scan<<<(Bv * NHv * PHv * NSv + 255) / 256, 256, 0, stream>>>(S_, at_);
        ssd_part2m<<<dim3(NHv, CNv, Bv), 256, 0, stream>>>(
            xbc_, S_, ac_, Dp + l * NHv, y_);
        gate_rms_kernel<<<MT, 256, 0, stream>>>(y_, zx_, rms_w + (size_t)l * DINNER, actb_);
        wt_convert<<<dim3(768 / 32, 1536 / 32), 256, 0, stream>>>(
            out_w + (size_t)l * DINNER * DIMv, wt_, DINNER, DIMv);
        gemm_bf16<0><<<dim3(6, 32), 256, 0, stream>>>(
            actb_, wt_, nullptr, tmp_, nullptr, MT, DIMv, DINNER, DIMv);
        resid_add_kernel<<<(unsigned)((n_h + 255) / 256), 256, 0, stream>>>(
            h_, tmp_, modl, 2 * DIMv, 6 * DIMv);
        // ---- MLP branch ----
        ln_mod_kernel<1><<<MT, 256, 0, stream>>>(h_, xnb_, modl, 4 * DIMv, 3 * DIMv, 6 * DIMv);
        wt_convert<<<dim3(1536 / 32, 768 / 32), 256, 0, stream>>>(
            ff_w1 + (size_t)l * DIMv * FFIv, wt_, DIMv, FFIv);
        gemm_bf16<2><<<dim3(12, 32), 256, 0, stream>>>(
            xnb_, wt_, ff_b1 + (size_t)l * FFIv, nullptr, actb_, MT, FFIv, DIMv, FFIv);
        wt_convert<<<dim3(768 / 32, 1536 / 32), 256, 0, stream>>>(
            ff_w2 + (size_t)l * FFIv * DIMv, wt_, FFIv, DIMv);
        gemm_bf16<1><<<dim3(6, 32), 256, 0, stream>>>(
            actb_, wt_, ff_b2 + (size_t)l * DIMv, tmp_, nullptr, MT, DIMv, FFIv, DIMv);
        resid_add_kernel<<<(unsigned)((n_h + 255) / 256), 256, 0, stream>>>(
            h_, tmp_, modl, 5 * DIMv, 6 * DIMv);
    }

    ln_mod_kernel<0><<<MT, 256, 0, stream>>>(h_, xn_, fm_, 0, DIMv, 2 * DIMv);
    gemm_f32<1><<<dim3((MELv + 63) / 64, (MT + 63) / 64), 256, 0, stream>>>(
        xn_, proj_w, proj_b, (float*)d_out, MT, MELv, DIMv);
}

// Round 4
// 4351.674 us; speedup vs baseline: 4.9408x; 1.0940x over previous
//
#include <hip/hip_runtime.h>
#include <math.h>

// ---- problem constants ----
constexpr int Bv = 2, Tv = 2048, NTv = 512;
constexpr int DIMv = 768, DEPTHv = 8, MELv = 100, TDIMv = 512;
constexpr int DINNER = 1536, NSv = 128, PHv = 64, QQv = 64;
constexpr int NHv = DINNER / PHv;              // 24
constexpr int CONVD = DINNER + 2 * NSv;        // 1792
constexpr int DINP = 2 * DINNER + 2 * NSv + NHv; // 3352
constexpr int KCONVv = 4, FFIv = 2 * DIMv;     // 1536
constexpr int CNv = Tv / QQv;                  // 32
constexpr int PCK = 1504;                      // 31*48=1488 padded to 32-mult

typedef unsigned short u16;
typedef unsigned int u32;
typedef __attribute__((ext_vector_type(8))) short short8v;
typedef __attribute__((ext_vector_type(4))) float f32x4;

__device__ __forceinline__ float siluf(float x) { return x / (1.f + expf(-x)); }
__device__ __forceinline__ float softplusf(float x) { return x > 20.f ? x : log1pf(expf(x)); }
__device__ __forceinline__ float mishf(float x) { return x * tanhf(softplusf(x)); }

__device__ __forceinline__ u16 f2bf(float v) {
    u32 u = __builtin_bit_cast(u32, v);
    u32 r = (u + 0x7fffu + ((u >> 16) & 1u)) >> 16;
    return (u16)r;
}
__device__ __forceinline__ float bf2f(u16 v) {
    u32 u = (u32)v << 16;
    return __builtin_bit_cast(float, u);
}

__device__ __forceinline__ void gload16(const void* g, void* l) {
    __builtin_amdgcn_global_load_lds(
        (const __attribute__((address_space(1))) u32*)g,
        (__attribute__((address_space(3))) u32*)l, 16, 0, 0);
}

__device__ __forceinline__ float blockReduceSum(float v) {
    __shared__ float red[4];
    #pragma unroll
    for (int off = 32; off > 0; off >>= 1) v += __shfl_down(v, off, 64);
    __syncthreads();
    if ((threadIdx.x & 63) == 0) red[threadIdx.x >> 6] = v;
    __syncthreads();
    return red[0] + red[1] + red[2] + red[3];
}

// ---- generic tiled f32 GEMM (small matrices) ----
template <int EPI>  // 0 none, 1 +bias
__global__ __launch_bounds__(256) void gemm_f32(const float* __restrict__ A,
                                                const float* __restrict__ W,
                                                const float* __restrict__ bias,
                                                float* __restrict__ C,
                                                int M, int N, int K) {
    constexpr int BM = 64, BN = 64, BK = 32;
    __shared__ float As[BK][BM + 1];
    __shared__ float Ws[BK][BN + 1];
    const int m0 = blockIdx.y * BM, n0 = blockIdx.x * BN;
    const int tid = threadIdx.x;
    const int tx = tid & 15, ty = tid >> 4;
    float acc[4][4] = {};
    for (int k0 = 0; k0 < K; k0 += BK) {
        {
            int m = tid >> 2, kq = (tid & 3) * 8;
            #pragma unroll
            for (int i = 0; i < 8; i++) {
                int k = kq + i;
                float v = 0.f;
                if (m0 + m < M && k0 + k < K) v = A[(size_t)(m0 + m) * K + k0 + k];
                As[k][m] = v;
            }
        }
        {
            int k = tid >> 3, nq = (tid & 7) * 8;
            #pragma unroll
            for (int i = 0; i < 8; i++) {
                int n = nq + i;
                float v = 0.f;
                if (k0 + k < K && n0 + n < N) v = W[(size_t)(k0 + k) * N + n0 + n];
                Ws[k][n] = v;
            }
        }
        __syncthreads();
        #pragma unroll
        for (int kk = 0; kk < BK; kk++) {
            float a[4], w[4];
            #pragma unroll
            for (int i = 0; i < 4; i++) a[i] = As[kk][ty + i * 16];
            #pragma unroll
            for (int j = 0; j < 4; j++) w[j] = Ws[kk][tx + j * 16];
            #pragma unroll
            for (int i = 0; i < 4; i++)
                #pragma unroll
                for (int j = 0; j < 4; j++) acc[i][j] += a[i] * w[j];
        }
        __syncthreads();
    }
    #pragma unroll
    for (int i = 0; i < 4; i++) {
        int m = m0 + ty + i * 16;
        if (m >= M) continue;
        #pragma unroll
        for (int j = 0; j < 4; j++) {
            int n = n0 + tx + j * 16;
            if (n >= N) continue;
            float v = acc[i][j];
            if (EPI >= 1) v += bias[n];
            C[(size_t)m * N + n] = v;
        }
    }
}

// ---- bf16 MFMA GEMM, m97 structure ----
// EPI: 0 f32, 1 +bias f32, 2 +bias gelu bf16, 3 h+=g*acc, 4 h+=g*(acc+bias)
template <int EPI>
__global__ __launch_bounds__(256) void gemm_bf16(const u16* __restrict__ A,
        const u16* __restrict__ BT, const float* __restrict__ bias,
        float* __restrict__ Cf, u16* __restrict__ Cb,
        int M, int N, int K, int ldc,
        const float* __restrict__ modv, int goff, int mstride) {
    __shared__ __align__(16) u16 As[128 * 32];
    __shared__ __align__(16) u16 Bs[128 * 32];
    const int tid = threadIdx.x;
    const int m0 = blockIdx.y * 128, n0 = blockIdx.x * 128;
    const int lane = tid & 63;
    const int wid = tid >> 6;
    const int wm = (wid >> 1) * 64, wn = (wid & 1) * 64;
    f32x4 acc[4][4] = {};
    const int srow = tid >> 2, sseg = (tid & 3) * 8;
    const u16* Ag = A + (size_t)(m0 + srow) * K + sseg;
    const u16* Bg = BT + (size_t)(n0 + srow) * K + sseg;
    u16* Asl = As + tid * 8;
    u16* Bsl = Bs + tid * 8;
    const int lr = lane & 15, lk = (lane >> 4) * 8;
    for (int k0 = 0; k0 < K; k0 += 32) {
        __syncthreads();
        gload16(Ag + k0, Asl);
        gload16(Ag + k0 + (size_t)64 * K, Asl + 64 * 32);
        gload16(Bg + k0, Bsl);
        gload16(Bg + k0 + (size_t)64 * K, Bsl + 64 * 32);
        __syncthreads();
        short8v a_f[4], b_f[4];
        #pragma unroll
        for (int i = 0; i < 4; i++)
            a_f[i] = *(const short8v*)&As[(wm + i * 16 + lr) * 32 + lk];
        #pragma unroll
        for (int j = 0; j < 4; j++)
            b_f[j] = *(const short8v*)&Bs[(wn + j * 16 + lr) * 32 + lk];
        #pragma unroll
        for (int i = 0; i < 4; i++)
            #pragma unroll
            for (int j = 0; j < 4; j++)
                acc[i][j] = __builtin_amdgcn_mfma_f32_16x16x32_bf16(a_f[i], b_f[j], acc[i][j], 0, 0, 0);
    }
    const int r0 = (lane >> 4) * 4;
    #pragma unroll
    for (int i = 0; i < 4; i++) {
        #pragma unroll
        for (int j = 0; j < 4; j++) {
            const int col = n0 + wn + j * 16 + lr;
            if (col >= N) continue;
            const int row = m0 + wm + i * 16 + r0;
            const float bv = (EPI == 1 || EPI == 2 || EPI == 4) ? bias[col] : 0.f;
            #pragma unroll
            for (int r = 0; r < 4; r++) {
                float v = acc[i][j][r] + bv;
                if (EPI == 2) {
                    float xx = v;
                    v = 0.5f * xx * (1.f + tanhf(0.7978845608028654f * (xx + 0.044715f * xx * xx * xx)));
                    Cb[(size_t)(row + r) * ldc + col] = f2bf(v);
                } else if (EPI == 3 || EPI == 4) {
                    const int bb = (row + r) >> 11;   // row / Tv
                    float g = modv[(size_t)bb * mstride + goff + col];
                    Cf[(size_t)(row + r) * ldc + col] += g * v;
                } else {
                    Cf[(size_t)(row + r) * ldc + col] = v;
                }
            }
        }
    }
}

// ---- weight f32 [K,N] -> bf16 transposed [Npad,K] ----
__global__ __launch_bounds__(256) void wt_convert(const float* __restrict__ W,
        u16* __restrict__ WT, int K, int N) {
    __shared__ float t[32][33];
    const int n0 = blockIdx.x * 32, k0 = blockIdx.y * 32;
    const int c = threadIdx.x & 31, rq = (threadIdx.x >> 5) * 4;
    #pragma unroll
    for (int i = 0; i < 4; i++) {
        int n = n0 + c;
        t[rq + i][c] = (n < N) ? W[(size_t)(k0 + rq + i) * N + n] : 0.f;
    }
    __syncthreads();
    #pragma unroll
    for (int i = 0; i < 4; i++)
        WT[(size_t)(n0 + rq + i) * K + k0 + c] = f2bf(t[c][rq + i]);
}

// ---- pos-conv weight: w[31][48][768] -> WT[768][1504] bf16 (kk = k*48+ci) ----
__global__ __launch_bounds__(256) void pw_convert(const float* __restrict__ w,
        u16* __restrict__ WT) {
    __shared__ float t[32][33];
    const int kk0 = blockIdx.x * 32, o0 = blockIdx.y * 32;
    const int c = threadIdx.x & 31, rq = (threadIdx.x >> 5) * 4;
    #pragma unroll
    for (int i = 0; i < 4; i++) {
        int kk = kk0 + rq + i;
        t[rq + i][c] = (kk < 1488) ? w[(size_t)kk * DIMv + o0 + c] : 0.f;
    }
    __syncthreads();
    #pragma unroll
    for (int i = 0; i < 4; i++)
        WT[(size_t)(o0 + rq + i) * PCK + kk0 + c] = f2bf(t[c][rq + i]);
}

// ---- grouped conv K=31 via implicit-im2col MFMA ----
// FUSE=0: out bf16 = mish(v) ; FUSE=1: out f32 += mish(v)   (h residual)
template <int IN_BF, int FUSE>
__global__ __launch_bounds__(256) void posconv_mfma(const void* __restrict__ inv,
        const u16* __restrict__ WT, const float* __restrict__ bias,
        void* __restrict__ outv) {
    __shared__ __align__(16) u16 xs[95 * 48];
    const int t0 = blockIdx.x * 64, g = blockIdx.y, b = blockIdx.z;
    const int tid = threadIdx.x;
    for (int e = tid; e < 95 * 48; e += 256) {
        int rr = e / 48, cc = e % 48;
        int t = t0 - 15 + rr;
        float v = 0.f;
        if (t >= 0 && t < Tv) {
            size_t gi = ((size_t)b * Tv + t) * DIMv + g * 48 + cc;
            v = IN_BF ? bf2f(((const u16*)inv)[gi]) : ((const float*)inv)[gi];
        }
        xs[e] = f2bf(v);
    }
    __syncthreads();
    const int lane = tid & 63, w = tid >> 6;
    const int lr = lane & 15, lq8 = (lane >> 4) * 8, rq = (lane >> 4) * 4;
    const u16* arow = &xs[(w * 16 + lr) * 48 + lq8];
    const u16* brow = &WT[(size_t)(g * 48 + lr) * PCK + lq8];
    f32x4 acc[3] = {};
    #pragma unroll 2
    for (int ks = 0; ks < PCK / 32; ks++) {
        short8v a = *(const short8v*)(arow + ks * 32);
        #pragma unroll
        for (int j = 0; j < 3; j++) {
            short8v bf = *(const short8v*)(brow + (size_t)j * 16 * PCK + ks * 32);
            acc[j] = __builtin_amdgcn_mfma_f32_16x16x32_bf16(a, bf, acc[j], 0, 0, 0);
        }
    }
    #pragma unroll
    for (int j = 0; j < 3; j++) {
        const int o = g * 48 + j * 16 + lr;
        const float bvv = bias[o];
        #pragma unroll
        for (int r = 0; r < 4; r++) {
            const int t = t0 + w * 16 + rq + r;
            float v = acc[j][r] + bvv;
            size_t gi = ((size_t)b * Tv + t) * DIMv + o;
            if (FUSE == 0) ((u16*)outv)[gi] = f2bf(mishf(v));
            else ((float*)outv)[gi] += mishf(v);
        }
    }
}

// ---- time embedding ----
__global__ __launch_bounds__(256) void time_embed_kernel(const float* __restrict__ timev,
        const float* __restrict__ t_w1, const float* __restrict__ t_b1,
        const float* __restrict__ t_w2, const float* __restrict__ t_b2,
        float* __restrict__ st_out) {
    __shared__ float te[Bv][256];
    __shared__ float hid[Bv][DIMv];
    const int tid = threadIdx.x;
    for (int e = tid; e < Bv * 256; e += 256) {
        int b = e >> 8, j = e & 255;
        int f = j & 127;
        float fr = expf(-logf(10000.f) / 127.f * (float)f);
        float ang = 1000.f * timev[b] * fr;
        te[b][j] = (j < 128) ? sinf(ang) : cosf(ang);
    }
    __syncthreads();
    for (int e = tid; e < Bv * DIMv; e += 256) {
        int b = e / DIMv, o = e % DIMv;
        float acc = t_b1[o];
        for (int k = 0; k < 256; k++) acc += te[b][k] * t_w1[k * DIMv + o];
        hid[b][o] = siluf(acc);
    }
    __syncthreads();
    for (int e = tid; e < Bv * DIMv; e += 256) {
        int b = e / DIMv, o = e % DIMv;
        float acc = t_b2[o];
        for (int k = 0; k < DIMv; k++) acc += hid[b][k] * t_w2[k * DIMv + o];
        st_out[b * DIMv + o] = siluf(acc);
    }
}

// ---- concat [x, cond, temb] ----
__global__ void concat_kernel(const float* __restrict__ x, const float* __restrict__ cond,
                              const float* __restrict__ table, const int* __restrict__ text,
                              float* __restrict__ cat) {
    size_t i = (size_t)blockIdx.x * 256 + threadIdx.x;
    const size_t total = (size_t)Bv * Tv * (2 * MELv + TDIMv);
    if (i >= total) return;
    int j = (int)(i % (2 * MELv + TDIMv));
    size_t row = i / (2 * MELv + TDIMv);
    int t = (int)(row % Tv), b = (int)(row / Tv);
    float v;
    if (j < MELv) v = x[row * MELv + j];
    else if (j < 2 * MELv) v = cond[row * MELv + (j - MELv)];
    else {
        int idx = (t < NTv) ? (text[b * NTv + t] + 1) : 0;
        v = table[(size_t)idx * TDIMv + (j - 2 * MELv)];
    }
    cat[i] = v;
}

// ---- LayerNorm with adaLN modulation; BF=1 writes bf16 ----
template <int BF>
__global__ __launch_bounds__(256) void ln_mod_kernel(const float* __restrict__ h,
        void* __restrict__ outv, const float* __restrict__ modv,
        int sc_off, int sh_off, int mod_stride) {
    const int row = blockIdx.x;
    const int b = row / Tv;
    const float* hr = h + (size_t)row * DIMv;
    float s = 0.f;
    for (int j = threadIdx.x; j < DIMv; j += 256) s += hr[j];
    s = blockReduceSum(s);
    const float m = s / DIMv;
    float v = 0.f;
    for (int j = threadIdx.x; j < DIMv; j += 256) { float d = hr[j] - m; v += d * d; }
    v = blockReduceSum(v);
    const float rstd = rsqrtf(v / DIMv + 1e-6f);
    const float* mb = modv + (size_t)b * mod_stride;
    for (int j = threadIdx.x; j < DIMv; j += 256) {
        float val = (hr[j] - m) * rstd * (1.f + mb[sc_off + j]) + mb[sh_off + j];
        if (BF) ((u16*)outv)[(size_t)row * DIMv + j] = f2bf(val);
        else ((float*)outv)[(size_t)row * DIMv + j] = val;
    }
}

// ---- causal depthwise conv K=4 + silu ----
__global__ void dwconv_kernel(const float* __restrict__ zx, const float* __restrict__ cw,
                              const float* __restrict__ cb, float* __restrict__ xbc) {
    size_t i = (size_t)blockIdx.x * 256 + threadIdx.x;
    if (i >= (size_t)Bv * Tv * CONVD) return;
    int c = (int)(i % CONVD);
    size_t row = i / CONVD;
    int t = (int)(row % Tv);
    const float* base = zx + row * DINP + DINNER + c;
    float acc = cb[c];
    #pragma unroll
    for (int k = 0; k < KCONVv; k++) {
        int d = k - 3;
        if (t + d >= 0) acc += base[(ptrdiff_t)d * DINP] * cw[c * KCONVv + k];
    }
    xbc[i] = siluf(acc);
}

// ---- SSD: CB[q][s] = sum_n C[q,n]*B[s,n], h-independent, MFMA ----
__global__ __launch_bounds__(256) void ssd_cb(const float* __restrict__ xbc,
                                              float* __restrict__ CBg) {
    constexpr int ST = 136;
    __shared__ __align__(16) u16 Cs[64 * ST];
    __shared__ __align__(16) u16 Bs[64 * ST];
    const int c = blockIdx.x, b = blockIdx.y;
    const int tid = threadIdx.x;
    const size_t rowbase = (size_t)b * Tv + (size_t)c * QQv;
    for (int e = tid; e < 64 * 128; e += 256) {
        int r = e >> 7, n = e & 127;
        const float* src = &xbc[(rowbase + r) * CONVD + DINNER];
        Bs[r * ST + n] = f2bf(src[n]);
        Cs[r * ST + n] = f2bf(src[NSv + n]);
    }
    __syncthreads();
    const int lane = tid & 63, w = tid >> 6;
    const int lr = lane & 15, lk8 = (lane >> 4) * 8, rq = (lane >> 4) * 4;
    f32x4 acc[4] = {};
    #pragma unroll
    for (int ks = 0; ks < 4; ks++) {
        short8v a = *(const short8v*)&Cs[(w * 16 + lr) * ST + ks * 32 + lk8];
        #pragma unroll
        for (int j = 0; j < 4; j++) {
            short8v bf = *(const short8v*)&Bs[(j * 16 + lr) * ST + ks * 32 + lk8];
            acc[j] = __builtin_amdgcn_mfma_f32_16x16x32_bf16(a, bf, acc[j], 0, 0, 0);
        }
    }
    float* out = CBg + ((size_t)(b * CNv + c)) * 4096;
    #pragma unroll
    for (int j = 0; j < 4; j++)
        #pragma unroll
        for (int r = 0; r < 4; r++)
            out[(w * 16 + rq + r) * 64 + j * 16 + lr] = acc[j][r];
}

// ---- SSD part1 (dt fused): prefix-scan, y_in, chunk-state S ----
__global__ __launch_bounds__(256) void ssd_part1m(const float* __restrict__ xbc,
        const float* __restrict__ zx, const float* __restrict__ dt_bias,
        const float* __restrict__ A_log,
        const float* __restrict__ CBg, float* __restrict__ ybuf,
        float* __restrict__ Sg, float* __restrict__ acg, float* __restrict__ atg) {
    constexpr int ST64 = 72;
    __shared__ __align__(16) u16 xbT[64 * ST64];   // [p][s]
    __shared__ __align__(16) u16 Wsm[64 * ST64];   // [q][s]
    __shared__ __align__(16) u16 BT[128 * ST64];   // [n][s]
    __shared__ float ac[64], dts[64], erev[64];
    const int h = blockIdx.x, c = blockIdx.y, b = blockIdx.z;
    const int tid = threadIdx.x;
    const size_t rowbase = (size_t)b * Tv + (size_t)c * QQv;
    const size_t bch = ((size_t)b * CNv + c) * NHv + h;
    if (tid < 64) {
        float raw = zx[(rowbase + tid) * DINP + DINNER + CONVD + h] + dt_bias[h];
        float dtv = softplusf(raw);
        dts[tid] = dtv;
        float v = dtv * (-expf(A_log[h]));
        #pragma unroll
        for (int off = 1; off < 64; off <<= 1) {
            float t = __shfl_up(v, off, 64);
            if (tid >= off) v += t;
        }
        ac[tid] = v;
    }
    __syncthreads();
    const float ac63 = ac[63];
    if (tid < 64) {
        erev[tid] = expf(ac63 - ac[tid]);
        acg[bch * 64 + tid] = ac[tid];
        if (tid == 63) atg[bch] = expf(ac63);
    }
    for (int e = tid; e < 64 * 64; e += 256) {
        int s = e >> 6, p = e & 63;
        xbT[p * ST64 + s] = f2bf(dts[s] * xbc[(rowbase + s) * CONVD + h * PHv + p]);
    }
    for (int e = tid; e < 64 * 128; e += 256) {
        int s = e >> 7, n = e & 127;
        BT[n * ST64 + s] = f2bf(xbc[(rowbase + s) * CONVD + DINNER + n]);
    }
    {
        const float* cbrow = CBg + ((size_t)(b * CNv + c)) * 4096;
        for (int e = tid; e < 64 * 64; e += 256) {
            int q = e >> 6, s = e & 63;
            float wv = (s <= q) ? cbrow[e] * expf(ac[q] - ac[s]) : 0.f;
            Wsm[q * ST64 + s] = f2bf(wv);
        }
    }
    __syncthreads();
    const int lane = tid & 63, w = tid >> 6;
    const int lr = lane & 15, lk8 = (lane >> 4) * 8, rq = (lane >> 4) * 4;
    {
        f32x4 acc[4] = {};
        #pragma unroll
        for (int ks = 0; ks < 2; ks++) {
            short8v bf = *(const short8v*)&xbT[(w * 16 + lr) * ST64 + ks * 32 + lk8];
            #pragma unroll
            for (int i = 0; i < 4; i++) {
                short8v a = *(const short8v*)&Wsm[(i * 16 + lr) * ST64 + ks * 32 + lk8];
                acc[i] = __builtin_amdgcn_mfma_f32_16x16x32_bf16(a, bf, acc[i], 0, 0, 0);
            }
        }
        #pragma unroll
        for (int i = 0; i < 4; i++)
            #pragma unroll
            for (int r = 0; r < 4; r++) {
                int q = i * 16 + rq + r, p = w * 16 + lr;
                ybuf[(rowbase + q) * DINNER + h * PHv + p] = acc[i][r];
            }
    }
    __syncthreads();
    for (int e = tid; e < 64 * 64; e += 256) {
        int p = e >> 6, s = e & 63;
        xbT[p * ST64 + s] = f2bf(bf2f(xbT[p * ST64 + s]) * erev[s]);
    }
    __syncthreads();
    {
        f32x4 acc[4][2] = {};
        #pragma unroll
        for (int ks = 0; ks < 2; ks++) {
            short8v a[4];
            #pragma unroll
            for (int i = 0; i < 4; i++)
                a[i] = *(const short8v*)&xbT[(i * 16 + lr) * ST64 + ks * 32 + lk8];
            #pragma unroll
            for (int j = 0; j < 2; j++) {
                short8v bf = *(const short8v*)&BT[(w * 32 + j * 16 + lr) * ST64 + ks * 32 + lk8];
                #pragma unroll
                for (int i = 0; i < 4; i++)
                    acc[i][j] = __builtin_amdgcn_mfma_f32_16x16x32_bf16(a[i], bf, acc[i][j], 0, 0, 0);
            }
        }
        float* So = Sg + bch * (PHv * NSv);
        #pragma unroll
        for (int i = 0; i < 4; i++)
            #pragma unroll
            for (int j = 0; j < 2; j++)
                #pragma unroll
                for (int r = 0; r < 4; r++)
                    So[(i * 16 + rq + r) * NSv + w * 32 + j * 16 + lr] = acc[i][j][r];
    }
}

// ---- inter-chunk scan ----
__global__ void ssd_scan(float* __restrict__ Sg, const float* __restrict__ atg) {
    int idx = blockIdx.x * 256 + threadIdx.x;
    if (idx >= Bv * NHv * PHv * NSv) return;
    int n = idx % NSv;
    int p = (idx / NSv) % PHv;
    int h = (idx / (NSv * PHv)) % NHv;
    int b = idx / (NSv * PHv * NHv);
    float H = 0.f;
    for (int c = 0; c < CNv; c++) {
        size_t bch = ((size_t)b * CNv + c) * NHv + h;
        size_t off = bch * PHv * NSv + (size_t)p * NSv + n;
        float s = Sg[off];
        float at = atg[bch];
        Sg[off] = H;
        H = at * H + s;
    }
}

// ---- SSD part2: y += (C @ prev^T)*eac + D*x ----
__global__ __launch_bounds__(256) void ssd_part2m(const float* __restrict__ xbc,
        const float* __restrict__ Sg, const float* __restrict__ acg,
        const float* __restrict__ Dp, float* __restrict__ ybuf) {
    constexpr int ST = 136;
    __shared__ __align__(16) u16 Cs[64 * ST];
    __shared__ __align__(16) u16 Ps[64 * ST];
    __shared__ float eac[64];
    const int h = blockIdx.x, c = blockIdx.y, b = blockIdx.z;
    const int tid = threadIdx.x;
    const size_t rowbase = (size_t)b * Tv + (size_t)c * QQv;
    const size_t bch = ((size_t)b * CNv + c) * NHv + h;
    if (tid < 64) eac[tid] = expf(acg[bch * 64 + tid]);
    for (int e = tid; e < 64 * 128; e += 256) {
        int r = e >> 7, n = e & 127;
        Cs[r * ST + n] = f2bf(xbc[(rowbase + r) * CONVD + DINNER + NSv + n]);
        Ps[r * ST + n] = f2bf(Sg[bch * (PHv * NSv) + e]);
    }
    __syncthreads();
    const int lane = tid & 63, w = tid >> 6;
    const int lr = lane & 15, lk8 = (lane >> 4) * 8, rq = (lane >> 4) * 4;
    f32x4 acc[4] = {};
    #pragma unroll
    for (int ks = 0; ks < 4; ks++) {
        short8v bf = *(const short8v*)&Ps[(w * 16 + lr) * ST + ks * 32 + lk8];
        #pragma unroll
        for (int i = 0; i < 4; i++) {
            short8v a = *(const short8v*)&Cs[(i * 16 + lr) * ST + ks * 32 + lk8];
            acc[i] = __builtin_amdgcn_mfma_f32_16x16x32_bf16(a, bf, acc[i], 0, 0, 0);
        }
    }
    const float Dh = Dp[h];
    #pragma unroll
    for (int i = 0; i < 4; i++)
        #pragma unroll
        for (int r = 0; r < 4; r++) {
            int q = i * 16 + rq + r, p = w * 16 + lr;
            size_t row = rowbase + q;
            size_t yi = row * DINNER + h * PHv + p;
            float xv = xbc[row * CONVD + h * PHv + p];
            ybuf[yi] += acc[i][r] * eac[q] + Dh * xv;
        }
}

// ---- gate by silu(z), RMS norm, * rms_w -> bf16 ----
__global__ __launch_bounds__(256) void gate_rms_kernel(const float* __restrict__ y,
        const float* __restrict__ zx, const float* __restrict__ rms_w,
        u16* __restrict__ yb) {
    const int row = blockIdx.x;
    const float* yr = y + (size_t)row * DINNER;
    const float* zr = zx + (size_t)row * DINP;
    float local[6];
    float ss = 0.f;
    #pragma unroll
    for (int i = 0; i < 6; i++) {
        int j = threadIdx.x + i * 256;
        float v = yr[j] * siluf(zr[j]);
        local[i] = v;
        ss += v * v;
    }
    ss = blockReduceSum(ss);
    const float scale = rsqrtf(ss / DINNER + 1e-5f);
    #pragma unroll
    for (int i = 0; i < 6; i++) {
        int j = threadIdx.x + i * 256;
        yb[(size_t)row * DINNER + j] = f2bf(local[i] * scale * rms_w[j]);
    }
}

extern "C" void kernel_launch(void* const* d_in, const int* in_sizes, int n_in,
                              void* d_out, int out_size, void* d_ws, size_t ws_size,
                              hipStream_t stream) {
    int s3 = (in_sizes[3] == Bv * NTv) ? 1 : 0;
    const float* x      = (const float*)d_in[0];
    const float* cond   = (const float*)d_in[1];
    const float* timev  = (const float*)d_in[2];
    const int*   text   = (const int*)(s3 ? d_in[3] : d_in[32]);
    const float* table  = (const float*)d_in[3 + s3];
    const float* inp_w  = (const float*)d_in[4 + s3];
    const float* inp_b  = (const float*)d_in[5 + s3];
    const float* pos_w1 = (const float*)d_in[6 + s3];
    const float* pos_b1 = (const float*)d_in[7 + s3];
    const float* pos_w2 = (const float*)d_in[8 + s3];
    const float* pos_b2 = (const float*)d_in[9 + s3];
    const float* t_w1   = (const float*)d_in[10 + s3];
    const float* t_b1   = (const float*)d_in[11 + s3];
    const float* t_w2   = (const float*)d_in[12 + s3];
    const float* t_b2   = (const float*)d_in[13 + s3];
    const float* adaln_w= (const float*)d_in[14 + s3];
    const float* adaln_b= (const float*)d_in[15 + s3];
    const float* in_w   = (const float*)d_in[16 + s3];
    const float* conv_w = (const float*)d_in[17 + s3];
    const float* conv_b = (const float*)d_in[18 + s3];
    const float* dt_bias= (const float*)d_in[19 + s3];
    const float* A_log  = (const float*)d_in[20 + s3];
    const float* Dp     = (const float*)d_in[21 + s3];
    const float* rms_w  = (const float*)d_in[22 + s3];
    const float* out_w  = (const float*)d_in[23 + s3];
    const float* ff_w1  = (const float*)d_in[24 + s3];
    const float* ff_b1  = (const float*)d_in[25 + s3];
    const float* ff_w2  = (const float*)d_in[26 + s3];
    const float* ff_b2  = (const float*)d_in[27 + s3];
    const float* fin_w  = (const float*)d_in[28 + s3];
    const float* fin_b  = (const float*)d_in[29 + s3];
    const float* proj_w = (const float*)d_in[30 + s3];
    const float* proj_b = (const float*)d_in[31 + s3];

    // ---- workspace layout ----
    float* ws = (float*)d_ws;
    const size_t n_h = (size_t)Bv * Tv * DIMv;
    size_t off = 0;
    auto nx = [&](size_t n) { float* p = ws + off; off += n; return p; };
    float* h_   = nx(n_h);
    float* xn_  = nx(n_h);
    float* zx_  = nx((size_t)Bv * Tv * DINP);
    float* cat_ = zx_;
    float* xbc_ = nx((size_t)Bv * Tv * CONVD);
    float* y_   = nx((size_t)Bv * Tv * DINNER);
    float* S_   = nx((size_t)Bv * CNv * NHv * PHv * NSv);
    float* ac_  = nx((size_t)Bv * CNv * NHv * QQv);
    float* at_  = nx((size_t)Bv * CNv * NHv);
    float* CB_  = nx((size_t)Bv * CNv * QQv * QQv);
    float* st_  = nx((size_t)Bv * DIMv);
    float* mod_ = nx((size_t)DEPTHv * Bv * 6 * DIMv);
    float* fm_  = nx((size_t)Bv * 2 * DIMv);
    off = (off + 15) & ~(size_t)15;
    u16* wt_   = (u16*)(ws + off);              // 3456*768
    u16* xnb_  = wt_  + (size_t)3456 * 768;     // 4096x768
    u16* actb_ = xnb_ + (size_t)4096 * 768;     // 4096x1536
    u16* xnb2_ = actb_ + (size_t)4096 * 1536;   // 4096x768 (conv1 out bf16)
    u16* pwt_  = xnb2_ + (size_t)4096 * 768;    // 768*1504 pos-conv weight

    const int MT = Bv * Tv;

    time_embed_kernel<<<1, 256, 0, stream>>>(timev, t_w1, t_b1, t_w2, t_b2, st_);
    for (int l = 0; l < DEPTHv; l++)
        gemm_f32<1><<<dim3((6 * DIMv + 63) / 64, 1), 256, 0, stream>>>(
            st_, adaln_w + (size_t)l * DIMv * 6 * DIMv, adaln_b + (size_t)l * 6 * DIMv,
            mod_ + (size_t)l * Bv * 6 * DIMv, Bv, 6 * DIMv, DIMv);
    gemm_f32<1><<<dim3((2 * DIMv + 63) / 64, 1), 256, 0, stream>>>(
        st_, fin_w, fin_b, fm_, Bv, 2 * DIMv, DIMv);

    concat_kernel<<<(unsigned)(((size_t)Bv * Tv * (2 * MELv + TDIMv) + 255) / 256), 256, 0, stream>>>(
        x, cond, table, text, cat_);
    gemm_f32<1><<<dim3((DIMv + 63) / 64, (MT + 63) / 64), 256, 0, stream>>>(
        cat_, inp_w, inp_b, h_, MT, DIMv, 2 * MELv + TDIMv);

    // pos-conv block (MFMA im2col)
    pw_convert<<<dim3(PCK / 32, DIMv / 32), 256, 0, stream>>>(pos_w1, pwt_);
    posconv_mfma<0, 0><<<dim3(Tv / 64, 16, Bv), 256, 0, stream>>>(h_, pwt_, pos_b1, xnb2_);
    pw_convert<<<dim3(PCK / 32, DIMv / 32), 256, 0, stream>>>(pos_w2, pwt_);
    posconv_mfma<1, 1><<<dim3(Tv / 64, 16, Bv), 256, 0, stream>>>(xnb2_, pwt_, pos_b2, h_);

    for (int l = 0; l < DEPTHv; l++) {
        const float* modl = mod_ + (size_t)l * Bv * 6 * DIMv;
        // ---- MSA/SSD branch ----
        ln_mod_kernel<1><<<MT, 256, 0, stream>>>(h_, xnb_, modl, DIMv, 0, 6 * DIMv);
        wt_convert<<<dim3(3456 / 32, 768 / 32), 256, 0, stream>>>(
            in_w + (size_t)l * DIMv * DINP, wt_, DIMv, DINP);
        gemm_bf16<0><<<dim3(27, 32), 256, 0, stream>>>(
            xnb_, wt_, nullptr, zx_, nullptr, MT, DINP, DIMv, DINP, nullptr, 0, 0);
        dwconv_kernel<<<(unsigned)(((size_t)Bv * Tv * CONVD + 255) / 256), 256, 0, stream>>>(
            zx_, conv_w + (size_t)l * CONVD * KCONVv, conv_b + (size_t)l * CONVD, xbc_);
        ssd_cb<<<dim3(CNv, Bv), 256, 0, stream>>>(xbc_, CB_);
        ssd_part1m<<<dim3(NHv, CNv, Bv), 256, 0, stream>>>(
            xbc_, zx_, dt_bias + l * NHv, A_log + l * NHv, CB_, y_, S_, ac_, at_);
        ssd_scan<<<(Bv * NHv * PHv * NSv + 255) / 256, 256, 0, stream>>>(S_, at_);
        ssd_part2m<<<dim3(NHv, CNv, Bv), 256, 0, stream>>>(
            xbc_, S_, ac_, Dp + l * NHv, y_);
        gate_rms_kernel<<<MT, 256, 0, stream>>>(y_, zx_, rms_w + (size_t)l * DINNER, actb_);
        wt_convert<<<dim3(768 / 32, 1536 / 32), 256, 0, stream>>>(
            out_w + (size_t)l * DINNER * DIMv, wt_, DINNER, DIMv);
        gemm_bf16<3><<<dim3(6, 32), 256, 0, stream>>>(
            actb_, wt_, nullptr, h_, nullptr, MT, DIMv, DINNER, DIMv, modl, 2 * DIMv, 6 * DIMv);
        // ---- MLP branch ----
        ln_mod_kernel<1><<<MT, 256, 0, stream>>>(h_, xnb_, modl, 4 * DIMv, 3 * DIMv, 6 * DIMv);
        wt_convert<<<dim3(1536 / 32, 768 / 32), 256, 0, stream>>>(
            ff_w1 + (size_t)l * DIMv * FFIv, wt_, DIMv, FFIv);
        gemm_bf16<2><<<dim3(12, 32), 256, 0, stream>>>(
            xnb_, wt_, ff_b1 + (size_t)l * FFIv, nullptr, actb_, MT, FFIv, DIMv, FFIv, nullptr, 0, 0);
        wt_convert<<<dim3(768 / 32, 1536 / 32), 256, 0, stream>>>(
            ff_w2 + (size_t)l * FFIv * DIMv, wt_, FFIv, DIMv);
        gemm_bf16<4><<<dim3(6, 32), 256, 0, stream>>>(
            actb_, wt_, ff_b2 + (size_t)l * DIMv, h_, nullptr, MT, DIMv, FFIv, DIMv, modl, 5 * DIMv, 6 * DIMv);
    }

    ln_mod_kernel<0><<<MT, 256, 0, stream>>>(h_, xn_, fm_, 0, DIMv, 2 * DIMv);
    gemm_f32<1><<<dim3((MELv + 63) / 64, (MT + 63) / 64), 256, 0, stream>>>(
        xn_, proj_w, proj_b, (float*)d_out, MT, MELv, DIMv);
}

// Round 5
// 3358.943 us; speedup vs baseline: 6.4011x; 1.2955x over previous
//
#include <hip/hip_runtime.h>
#include <math.h>

// ---- problem constants ----
constexpr int Bv = 2, Tv = 2048, NTv = 512;
constexpr int DIMv = 768, DEPTHv = 8, MELv = 100, TDIMv = 512;
constexpr int DINNER = 1536, NSv = 128, PHv = 64, QQv = 64;
constexpr int NHv = DINNER / PHv;              // 24
constexpr int CONVD = DINNER + 2 * NSv;        // 1792
constexpr int DINP = 2 * DINNER + 2 * NSv + NHv; // 3352
constexpr int KCONVv = 4, FFIv = 2 * DIMv;     // 1536
constexpr int CNv = Tv / QQv;                  // 32
constexpr int PCK = 1504;                      // 31*48 padded
constexpr int KCAT = 736;                      // 712 padded to 32-mult

typedef unsigned short u16;
typedef unsigned int u32;
typedef __attribute__((ext_vector_type(8))) short short8v;
typedef __attribute__((ext_vector_type(4))) float f32x4;

__device__ __forceinline__ float siluf(float x) { return x / (1.f + expf(-x)); }
__device__ __forceinline__ float softplusf(float x) { return x > 20.f ? x : log1pf(expf(x)); }
__device__ __forceinline__ float mishf(float x) { return x * tanhf(softplusf(x)); }

__device__ __forceinline__ u16 f2bf(float v) {
    u32 u = __builtin_bit_cast(u32, v);
    u32 r = (u + 0x7fffu + ((u >> 16) & 1u)) >> 16;
    return (u16)r;
}
__device__ __forceinline__ float bf2f(u16 v) {
    u32 u = (u32)v << 16;
    return __builtin_bit_cast(float, u);
}

__device__ __forceinline__ void gload16(const void* g, void* l) {
    __builtin_amdgcn_global_load_lds(
        (const __attribute__((address_space(1))) u32*)g,
        (__attribute__((address_space(3))) u32*)l, 16, 0, 0);
}

__device__ __forceinline__ float blockReduceSum(float v) {
    __shared__ float red[4];
    #pragma unroll
    for (int off = 32; off > 0; off >>= 1) v += __shfl_down(v, off, 64);
    __syncthreads();
    if ((threadIdx.x & 63) == 0) red[threadIdx.x >> 6] = v;
    __syncthreads();
    return red[0] + red[1] + red[2] + red[3];
}

// ---- generic tiled f32 GEMM (final projection only) ----
template <int EPI>
__global__ __launch_bounds__(256) void gemm_f32(const float* __restrict__ A,
                                                const float* __restrict__ W,
                                                const float* __restrict__ bias,
                                                float* __restrict__ C,
                                                int M, int N, int K) {
    constexpr int BM = 64, BN = 64, BK = 32;
    __shared__ float As[BK][BM + 1];
    __shared__ float Ws[BK][BN + 1];
    const int m0 = blockIdx.y * BM, n0 = blockIdx.x * BN;
    const int tid = threadIdx.x;
    const int tx = tid & 15, ty = tid >> 4;
    float acc[4][4] = {};
    for (int k0 = 0; k0 < K; k0 += BK) {
        {
            int m = tid >> 2, kq = (tid & 3) * 8;
            #pragma unroll
            for (int i = 0; i < 8; i++) {
                int k = kq + i;
                float v = 0.f;
                if (m0 + m < M && k0 + k < K) v = A[(size_t)(m0 + m) * K + k0 + k];
                As[k][m] = v;
            }
        }
        {
            int k = tid >> 3, nq = (tid & 7) * 8;
            #pragma unroll
            for (int i = 0; i < 8; i++) {
                int n = nq + i;
                float v = 0.f;
                if (k0 + k < K && n0 + n < N) v = W[(size_t)(k0 + k) * N + n0 + n];
                Ws[k][n] = v;
            }
        }
        __syncthreads();
        #pragma unroll
        for (int kk = 0; kk < BK; kk++) {
            float a[4], w[4];
            #pragma unroll
            for (int i = 0; i < 4; i++) a[i] = As[kk][ty + i * 16];
            #pragma unroll
            for (int j = 0; j < 4; j++) w[j] = Ws[kk][tx + j * 16];
            #pragma unroll
            for (int i = 0; i < 4; i++)
                #pragma unroll
                for (int j = 0; j < 4; j++) acc[i][j] += a[i] * w[j];
        }
        __syncthreads();
    }
    #pragma unroll
    for (int i = 0; i < 4; i++) {
        int m = m0 + ty + i * 16;
        if (m >= M) continue;
        #pragma unroll
        for (int j = 0; j < 4; j++) {
            int n = n0 + tx + j * 16;
            if (n >= N) continue;
            float v = acc[i][j];
            if (EPI >= 1) v += bias[n];
            C[(size_t)m * N + n] = v;
        }
    }
}

// ---- bf16 MFMA GEMM, 128x128 tile, 2-phase double-buffered staging ----
// EPI: 0 f32, 1 +bias f32, 2 +bias gelu bf16, 3 h+=g*acc, 4 h+=g*(acc+bias)
template <int EPI>
__global__ __launch_bounds__(256) void gemm_bf16(const u16* __restrict__ A,
        const u16* __restrict__ BT, const float* __restrict__ bias,
        float* __restrict__ Cf, u16* __restrict__ Cb,
        int M, int N, int K, int ldc,
        const float* __restrict__ modv, int goff, int mstride) {
    __shared__ __align__(16) u16 As[2][128 * 32];
    __shared__ __align__(16) u16 Bs[2][128 * 32];
    const int tid = threadIdx.x;
    const int m0 = blockIdx.y * 128, n0 = blockIdx.x * 128;
    const int lane = tid & 63;
    const int wid = tid >> 6;
    const int wm = (wid >> 1) * 64, wn = (wid & 1) * 64;
    f32x4 acc[4][4] = {};
    const int srow = tid >> 2, sseg = (tid & 3) * 8;
    const u16* Ag = A + (size_t)(m0 + srow) * K + sseg;
    const u16* Bg = BT + (size_t)(n0 + srow) * K + sseg;
    const int lr = lane & 15, lk = (lane >> 4) * 8;
    // prologue: stage tile 0 into buffer 0
    gload16(Ag, &As[0][tid * 8]);
    gload16(Ag + (size_t)64 * K, &As[0][tid * 8 + 64 * 32]);
    gload16(Bg, &Bs[0][tid * 8]);
    gload16(Bg + (size_t)64 * K, &Bs[0][tid * 8 + 64 * 32]);
    __syncthreads();
    int cur = 0;
    for (int k0 = 0; k0 < K; k0 += 32) {
        if (k0 + 32 < K) {   // stage next tile into the other buffer (overlaps MFMA)
            const int nb = cur ^ 1, kn = k0 + 32;
            gload16(Ag + kn, &As[nb][tid * 8]);
            gload16(Ag + kn + (size_t)64 * K, &As[nb][tid * 8 + 64 * 32]);
            gload16(Bg + kn, &Bs[nb][tid * 8]);
            gload16(Bg + kn + (size_t)64 * K, &Bs[nb][tid * 8 + 64 * 32]);
        }
        short8v a_f[4], b_f[4];
        #pragma unroll
        for (int i = 0; i < 4; i++)
            a_f[i] = *(const short8v*)&As[cur][(wm + i * 16 + lr) * 32 + lk];
        #pragma unroll
        for (int j = 0; j < 4; j++)
            b_f[j] = *(const short8v*)&Bs[cur][(wn + j * 16 + lr) * 32 + lk];
        #pragma unroll
        for (int i = 0; i < 4; i++)
            #pragma unroll
            for (int j = 0; j < 4; j++)
                acc[i][j] = __builtin_amdgcn_mfma_f32_16x16x32_bf16(a_f[i], b_f[j], acc[i][j], 0, 0, 0);
        __syncthreads();   // drains next-tile loads (vmcnt) + protects cur buffer
        cur ^= 1;
    }
    const int r0 = (lane >> 4) * 4;
    #pragma unroll
    for (int i = 0; i < 4; i++) {
        #pragma unroll
        for (int j = 0; j < 4; j++) {
            const int col = n0 + wn + j * 16 + lr;
            if (col >= N) continue;
            const int row = m0 + wm + i * 16 + r0;
            const float bv = (EPI == 1 || EPI == 2 || EPI == 4) ? bias[col] : 0.f;
            #pragma unroll
            for (int r = 0; r < 4; r++) {
                float v = acc[i][j][r] + bv;
                if (EPI == 2) {
                    float xx = v;
                    v = 0.5f * xx * (1.f + tanhf(0.7978845608028654f * (xx + 0.044715f * xx * xx * xx)));
                    Cb[(size_t)(row + r) * ldc + col] = f2bf(v);
                } else if (EPI == 3 || EPI == 4) {
                    const int bb = (row + r) >> 11;   // row / Tv
                    float g = modv[(size_t)bb * mstride + goff + col];
                    Cf[(size_t)(row + r) * ldc + col] += g * v;
                } else {
                    Cf[(size_t)(row + r) * ldc + col] = v;
                }
            }
        }
    }
}

// ---- weight f32 [Kmax,N] -> bf16 transposed [Npad,Kpad], zero-filled ----
__global__ __launch_bounds__(256) void wt_convert(const float* __restrict__ W,
        u16* __restrict__ WT, int K, int N, int Kmax) {
    __shared__ float t[32][33];
    const int n0 = blockIdx.x * 32, k0 = blockIdx.y * 32;
    const int c = threadIdx.x & 31, rq = (threadIdx.x >> 5) * 4;
    #pragma unroll
    for (int i = 0; i < 4; i++) {
        int n = n0 + c, k = k0 + rq + i;
        t[rq + i][c] = (n < N && k < Kmax) ? W[(size_t)k * N + n] : 0.f;
    }
    __syncthreads();
    #pragma unroll
    for (int i = 0; i < 4; i++)
        WT[(size_t)(n0 + rq + i) * K + k0 + c] = f2bf(t[c][rq + i]);
}

// ---- pos-conv weight: w[31][48][768] -> WT[768][1504] bf16 ----
__global__ __launch_bounds__(256) void pw_convert(const float* __restrict__ w,
        u16* __restrict__ WT) {
    __shared__ float t[32][33];
    const int kk0 = blockIdx.x * 32, o0 = blockIdx.y * 32;
    const int c = threadIdx.x & 31, rq = (threadIdx.x >> 5) * 4;
    #pragma unroll
    for (int i = 0; i < 4; i++) {
        int kk = kk0 + rq + i;
        t[rq + i][c] = (kk < 1488) ? w[(size_t)kk * DIMv + o0 + c] : 0.f;
    }
    __syncthreads();
    #pragma unroll
    for (int i = 0; i < 4; i++)
        WT[(size_t)(o0 + rq + i) * PCK + kk0 + c] = f2bf(t[c][rq + i]);
}

// ---- grouped conv K=31 via implicit-im2col MFMA ----
template <int IN_BF, int FUSE>
__global__ __launch_bounds__(256) void posconv_mfma(const void* __restrict__ inv,
        const u16* __restrict__ WT, const float* __restrict__ bias,
        void* __restrict__ outv) {
    __shared__ __align__(16) u16 xs[95 * 48];
    const int t0 = blockIdx.x * 64, g = blockIdx.y, b = blockIdx.z;
    const int tid = threadIdx.x;
    for (int e = tid; e < 95 * 48; e += 256) {
        int rr = e / 48, cc = e % 48;
        int t = t0 - 15 + rr;
        float v = 0.f;
        if (t >= 0 && t < Tv) {
            size_t gi = ((size_t)b * Tv + t) * DIMv + g * 48 + cc;
            v = IN_BF ? bf2f(((const u16*)inv)[gi]) : ((const float*)inv)[gi];
        }
        xs[e] = f2bf(v);
    }
    __syncthreads();
    const int lane = tid & 63, w = tid >> 6;
    const int lr = lane & 15, lq8 = (lane >> 4) * 8, rq = (lane >> 4) * 4;
    const u16* arow = &xs[(w * 16 + lr) * 48 + lq8];
    const u16* brow = &WT[(size_t)(g * 48 + lr) * PCK + lq8];
    f32x4 acc[3] = {};
    #pragma unroll 2
    for (int ks = 0; ks < PCK / 32; ks++) {
        short8v a = *(const short8v*)(arow + ks * 32);
        #pragma unroll
        for (int j = 0; j < 3; j++) {
            short8v bf = *(const short8v*)(brow + (size_t)j * 16 * PCK + ks * 32);
            acc[j] = __builtin_amdgcn_mfma_f32_16x16x32_bf16(a, bf, acc[j], 0, 0, 0);
        }
    }
    #pragma unroll
    for (int j = 0; j < 3; j++) {
        const int o = g * 48 + j * 16 + lr;
        const float bvv = bias[o];
        #pragma unroll
        for (int r = 0; r < 4; r++) {
            const int t = t0 + w * 16 + rq + r;
            float v = acc[j][r] + bvv;
            size_t gi = ((size_t)b * Tv + t) * DIMv + o;
            if (FUSE == 0) ((u16*)outv)[gi] = f2bf(mishf(v));
            else ((float*)outv)[gi] += mishf(v);
        }
    }
}

// ---- time embedding, stage 1: hid = silu(te @ t_w1 + b1) ----
__global__ __launch_bounds__(256) void temb1_kernel(const float* __restrict__ timev,
        const float* __restrict__ t_w1, const float* __restrict__ t_b1,
        float* __restrict__ hid) {
    const int b = blockIdx.y;
    const int o = blockIdx.x * 256 + threadIdx.x;
    __shared__ float te[256];
    {
        int j = threadIdx.x, f = j & 127;
        float fr = expf(-logf(10000.f) / 127.f * (float)f);
        float ang = 1000.f * timev[b] * fr;
        te[j] = (j < 128) ? sinf(ang) : cosf(ang);
    }
    __syncthreads();
    float acc = t_b1[o];
    #pragma unroll 4
    for (int k = 0; k < 256; k++) acc += te[k] * t_w1[(size_t)k * DIMv + o];
    hid[b * DIMv + o] = siluf(acc);
}

// ---- time embedding, stage 2: st = silu(hid @ t_w2 + b2) ----
__global__ __launch_bounds__(256) void temb2_kernel(const float* __restrict__ hid,
        const float* __restrict__ t_w2, const float* __restrict__ t_b2,
        float* __restrict__ st_out) {
    const int b = blockIdx.y;
    const int o = blockIdx.x * 256 + threadIdx.x;
    __shared__ float hv[DIMv];
    for (int j = threadIdx.x; j < DIMv; j += 256) hv[j] = hid[b * DIMv + j];
    __syncthreads();
    float acc = t_b2[o];
    #pragma unroll 4
    for (int k = 0; k < DIMv; k++) acc += hv[k] * t_w2[(size_t)k * DIMv + o];
    st_out[b * DIMv + o] = siluf(acc);
}

// ---- batched modulation vectors: out[l][b][o] = st[b] . W[l][:,o] + bias[l][o] ----
__global__ __launch_bounds__(256) void modvec_kernel(const float* __restrict__ st,
        const float* __restrict__ W, const float* __restrict__ bias,
        float* __restrict__ out, int N) {
    const int l = blockIdx.z, b = blockIdx.y;
    const int o = blockIdx.x * 256 + threadIdx.x;
    __shared__ float sv[DIMv];
    for (int j = threadIdx.x; j < DIMv; j += 256) sv[j] = st[b * DIMv + j];
    __syncthreads();
    const float* Wl = W + (size_t)l * DIMv * N + o;
    float acc = bias[(size_t)l * N + o];
    #pragma unroll 4
    for (int k = 0; k < DIMv; k++) acc += sv[k] * Wl[(size_t)k * N];
    out[((size_t)l * Bv + b) * N + o] = acc;
}

// ---- concat [x, cond, temb] -> bf16, K-padded to 736 ----
__global__ void concat_bf16(const float* __restrict__ x, const float* __restrict__ cond,
                            const float* __restrict__ table, const int* __restrict__ text,
                            u16* __restrict__ cat) {
    size_t i = (size_t)blockIdx.x * 256 + threadIdx.x;
    const size_t total = (size_t)Bv * Tv * KCAT;
    if (i >= total) return;
    int j = (int)(i % KCAT);
    size_t row = i / KCAT;
    int t = (int)(row % Tv), b = (int)(row / Tv);
    float v = 0.f;
    if (j < MELv) v = x[row * MELv + j];
    else if (j < 2 * MELv) v = cond[row * MELv + (j - MELv)];
    else if (j < 712) {
        int idx = (t < NTv) ? (text[b * NTv + t] + 1) : 0;
        v = table[(size_t)idx * TDIMv + (j - 2 * MELv)];
    }
    cat[i] = f2bf(v);
}

// ---- LayerNorm with adaLN modulation; BF=1 writes bf16 ----
template <int BF>
__global__ __launch_bounds__(256) void ln_mod_kernel(const float* __restrict__ h,
        void* __restrict__ outv, const float* __restrict__ modv,
        int sc_off, int sh_off, int mod_stride) {
    const int row = blockIdx.x;
    const int b = row / Tv;
    const float* hr = h + (size_t)row * DIMv;
    float s = 0.f;
    for (int j = threadIdx.x; j < DIMv; j += 256) s += hr[j];
    s = blockReduceSum(s);
    const float m = s / DIMv;
    float v = 0.f;
    for (int j = threadIdx.x; j < DIMv; j += 256) { float d = hr[j] - m; v += d * d; }
    v = blockReduceSum(v);
    const float rstd = rsqrtf(v / DIMv + 1e-6f);
    const float* mb = modv + (size_t)b * mod_stride;
    for (int j = threadIdx.x; j < DIMv; j += 256) {
        float val = (hr[j] - m) * rstd * (1.f + mb[sc_off + j]) + mb[sh_off + j];
        if (BF) ((u16*)outv)[(size_t)row * DIMv + j] = f2bf(val);
        else ((float*)outv)[(size_t)row * DIMv + j] = val;
    }
}

// ---- causal depthwise conv K=4 + silu ----
__global__ void dwconv_kernel(const float* __restrict__ zx, const float* __restrict__ cw,
                              const float* __restrict__ cb, float* __restrict__ xbc) {
    size_t i = (size_t)blockIdx.x * 256 + threadIdx.x;
    if (i >= (size_t)Bv * Tv * CONVD) return;
    int c = (int)(i % CONVD);
    size_t row = i / CONVD;
    int t = (int)(row % Tv);
    const float* base = zx + row * DINP + DINNER + c;
    float acc = cb[c];
    #pragma unroll
    for (int k = 0; k < KCONVv; k++) {
        int d = k - 3;
        if (t + d >= 0) acc += base[(ptrdiff_t)d * DINP] * cw[c * KCONVv + k];
    }
    xbc[i] = siluf(acc);
}

// ---- SSD: CB[q][s] = sum_n C[q,n]*B[s,n], h-independent, MFMA ----
__global__ __launch_bounds__(256) void ssd_cb(const float* __restrict__ xbc,
                                              float* __restrict__ CBg) {
    constexpr int ST = 136;
    __shared__ __align__(16) u16 Cs[64 * ST];
    __shared__ __align__(16) u16 Bs[64 * ST];
    const int c = blockIdx.x, b = blockIdx.y;
    const int tid = threadIdx.x;
    const size_t rowbase = (size_t)b * Tv + (size_t)c * QQv;
    for (int e = tid; e < 64 * 128; e += 256) {
        int r = e >> 7, n = e & 127;
        const float* src = &xbc[(rowbase + r) * CONVD + DINNER];
        Bs[r * ST + n] = f2bf(src[n]);
        Cs[r * ST + n] = f2bf(src[NSv + n]);
    }
    __syncthreads();
    const int lane = tid & 63, w = tid >> 6;
    const int lr = lane & 15, lk8 = (lane >> 4) * 8, rq = (lane >> 4) * 4;
    f32x4 acc[4] = {};
    #pragma unroll
    for (int ks = 0; ks < 4; ks++) {
        short8v a = *(const short8v*)&Cs[(w * 16 + lr) * ST + ks * 32 + lk8];
        #pragma unroll
        for (int j = 0; j < 4; j++) {
            short8v bf = *(const short8v*)&Bs[(j * 16 + lr) * ST + ks * 32 + lk8];
            acc[j] = __builtin_amdgcn_mfma_f32_16x16x32_bf16(a, bf, acc[j], 0, 0, 0);
        }
    }
    float* out = CBg + ((size_t)(b * CNv + c)) * 4096;
    #pragma unroll
    for (int j = 0; j < 4; j++)
        #pragma unroll
        for (int r = 0; r < 4; r++)
            out[(w * 16 + rq + r) * 64 + j * 16 + lr] = acc[j][r];
}

// ---- SSD part1 (dt fused): prefix-scan, y_in, chunk-state S ----
__global__ __launch_bounds__(256) void ssd_part1m(const float* __restrict__ xbc,
        const float* __restrict__ zx, const float* __restrict__ dt_bias,
        const float* __restrict__ A_log,
        const float* __restrict__ CBg, float* __restrict__ ybuf,
        float* __restrict__ Sg, float* __restrict__ acg, float* __restrict__ atg) {
    constexpr int ST64 = 72;
    __shared__ __align__(16) u16 xbT[64 * ST64];   // [p][s]
    __shared__ __align__(16) u16 Wsm[64 * ST64];   // [q][s]
    __shared__ __align__(16) u16 BT[128 * ST64];   // [n][s]
    __shared__ float ac[64], dts[64], erev[64];
    const int h = blockIdx.x, c = blockIdx.y, b = blockIdx.z;
    const int tid = threadIdx.x;
    const size_t rowbase = (size_t)b * Tv + (size_t)c * QQv;
    const size_t bch = ((size_t)b * CNv + c) * NHv + h;
    if (tid < 64) {
        float raw = zx[(rowbase + tid) * DINP + DINNER + CONVD + h] + dt_bias[h];
        float dtv = softplusf(raw);
        dts[tid] = dtv;
        float v = dtv * (-expf(A_log[h]));
        #pragma unroll
        for (int off = 1; off < 64; off <<= 1) {
            float t = __shfl_up(v, off, 64);
            if (tid >= off) v += t;
        }
        ac[tid] = v;
    }
    __syncthreads();
    const float ac63 = ac[63];
    if (tid < 64) {
        erev[tid] = expf(ac63 - ac[tid]);
        acg[bch * 64 + tid] = ac[tid];
        if (tid == 63) atg[bch] = expf(ac63);
    }
    for (int e = tid; e < 64 * 64; e += 256) {
        int s = e >> 6, p = e & 63;
        xbT[p * ST64 + s] = f2bf(dts[s] * xbc[(rowbase + s) * CONVD + h * PHv + p]);
    }
    for (int e = tid; e < 64 * 128; e += 256) {
        int s = e >> 7, n = e & 127;
        BT[n * ST64 + s] = f2bf(xbc[(rowbase + s) * CONVD + DINNER + n]);
    }
    {
        const float* cbrow = CBg + ((size_t)(b * CNv + c)) * 4096;
        for (int e = tid; e < 64 * 64; e += 256) {
            int q = e >> 6, s = e & 63;
            float wv = (s <= q) ? cbrow[e] * expf(ac[q] - ac[s]) : 0.f;
            Wsm[q * ST64 + s] = f2bf(wv);
        }
    }
    __syncthreads();
    const int lane = tid & 63, w = tid >> 6;
    const int lr = lane & 15, lk8 = (lane >> 4) * 8, rq = (lane >> 4) * 4;
    {
        f32x4 acc[4] = {};
        #pragma unroll
        for (int ks = 0; ks < 2; ks++) {
            short8v bf = *(const short8v*)&xbT[(w * 16 + lr) * ST64 + ks * 32 + lk8];
            #pragma unroll
            for (int i = 0; i < 4; i++) {
                short8v a = *(const short8v*)&Wsm[(i * 16 + lr) * ST64 + ks * 32 + lk8];
                acc[i] = __builtin_amdgcn_mfma_f32_16x16x32_bf16(a, bf, acc[i], 0, 0, 0);
            }
        }
        #pragma unroll
        for (int i = 0; i < 4; i++)
            #pragma unroll
            for (int r = 0; r < 4; r++) {
                int q = i * 16 + rq + r, p = w * 16 + lr;
                ybuf[(rowbase + q) * DINNER + h * PHv + p] = acc[i][r];
            }
    }
    __syncthreads();
    for (int e = tid; e < 64 * 64; e += 256) {
        int p = e >> 6, s = e & 63;
        xbT[p * ST64 + s] = f2bf(bf2f(xbT[p * ST64 + s]) * erev[s]);
    }
    __syncthreads();
    {
        f32x4 acc[4][2] = {};
        #pragma unroll
        for (int ks = 0; ks < 2; ks++) {
            short8v a[4];
            #pragma unroll
            for (int i = 0; i < 4; i++)
                a[i] = *(const short8v*)&xbT[(i * 16 + lr) * ST64 + ks * 32 + lk8];
            #pragma unroll
            for (int j = 0; j < 2; j++) {
                short8v bf = *(const short8v*)&BT[(w * 32 + j * 16 + lr) * ST64 + ks * 32 + lk8];
                #pragma unroll
                for (int i = 0; i < 4; i++)
                    acc[i][j] = __builtin_amdgcn_mfma_f32_16x16x32_bf16(a[i], bf, acc[i][j], 0, 0, 0);
            }
        }
        float* So = Sg + bch * (PHv * NSv);
        #pragma unroll
        for (int i = 0; i < 4; i++)
            #pragma unroll
            for (int j = 0; j < 2; j++)
                #pragma unroll
                for (int r = 0; r < 4; r++)
                    So[(i * 16 + rq + r) * NSv + w * 32 + j * 16 + lr] = acc[i][j][r];
    }
}

// ---- inter-chunk scan ----
__global__ void ssd_scan(float* __restrict__ Sg, const float* __restrict__ atg) {
    int idx = blockIdx.x * 256 + threadIdx.x;
    if (idx >= Bv * NHv * PHv * NSv) return;
    int n = idx % NSv;
    int p = (idx / NSv) % PHv;
    int h = (idx / (NSv * PHv)) % NHv;
    int b = idx / (NSv * PHv * NHv);
    float H = 0.f;
    for (int c = 0; c < CNv; c++) {
        size_t bch = ((size_t)b * CNv + c) * NHv + h;
        size_t off = bch * PHv * NSv + (size_t)p * NSv + n;
        float s = Sg[off];
        float at = atg[bch];
        Sg[off] = H;
        H = at * H + s;
    }
}

// ---- SSD part2: y += (C @ prev^T)*eac + D*x ----
__global__ __launch_bounds__(256) void ssd_part2m(const float* __restrict__ xbc,
        const float* __restrict__ Sg, const float* __restrict__ acg,
        const float* __restrict__ Dp, float* __restrict__ ybuf) {
    constexpr int ST = 136;
    __shared__ __align__(16) u16 Cs[64 * ST];
    __shared__ __align__(16) u16 Ps[64 * ST];
    __shared__ float eac[64];
    const int h = blockIdx.x, c = blockIdx.y, b = blockIdx.z;
    const int tid = threadIdx.x;
    const size_t rowbase = (size_t)b * Tv + (size_t)c * QQv;
    const size_t bch = ((size_t)b * CNv + c) * NHv + h;
    if (tid < 64) eac[tid] = expf(acg[bch * 64 + tid]);
    for (int e = tid; e < 64 * 128; e += 256) {
        int r = e >> 7, n = e & 127;
        Cs[r * ST + n] = f2bf(xbc[(rowbase + r) * CONVD + DINNER + NSv + n]);
        Ps[r * ST + n] = f2bf(Sg[bch * (PHv * NSv) + e]);
    }
    __syncthreads();
    const int lane = tid & 63, w = tid >> 6;
    const int lr = lane & 15, lk8 = (lane >> 4) * 8, rq = (lane >> 4) * 4;
    f32x4 acc[4] = {};
    #pragma unroll
    for (int ks = 0; ks < 4; ks++) {
        short8v bf = *(const short8v*)&Ps[(w * 16 + lr) * ST + ks * 32 + lk8];
        #pragma unroll
        for (int i = 0; i < 4; i++) {
            short8v a = *(const short8v*)&Cs[(i * 16 + lr) * ST + ks * 32 + lk8];
            acc[i] = __builtin_amdgcn_mfma_f32_16x16x32_bf16(a, bf, acc[i], 0, 0, 0);
        }
    }
    const float Dh = Dp[h];
    #pragma unroll
    for (int i = 0; i < 4; i++)
        #pragma unroll
        for (int r = 0; r < 4; r++) {
            int q = i * 16 + rq + r, p = w * 16 + lr;
            size_t row = rowbase + q;
            size_t yi = row * DINNER + h * PHv + p;
            float xv = xbc[row * CONVD + h * PHv + p];
            ybuf[yi] += acc[i][r] * eac[q] + Dh * xv;
        }
}

// ---- gate by silu(z), RMS norm, * rms_w -> bf16 ----
__global__ __launch_bounds__(256) void gate_rms_kernel(const float* __restrict__ y,
        const float* __restrict__ zx, const float* __restrict__ rms_w,
        u16* __restrict__ yb) {
    const int row = blockIdx.x;
    const float* yr = y + (size_t)row * DINNER;
    const float* zr = zx + (size_t)row * DINP;
    float local[6];
    float ss = 0.f;
    #pragma unroll
    for (int i = 0; i < 6; i++) {
        int j = threadIdx.x + i * 256;
        float v = yr[j] * siluf(zr[j]);
        local[i] = v;
        ss += v * v;
    }
    ss = blockReduceSum(ss);
    const float scale = rsqrtf(ss / DINNER + 1e-5f);
    #pragma unroll
    for (int i = 0; i < 6; i++) {
        int j = threadIdx.x + i * 256;
        yb[(size_t)row * DINNER + j] = f2bf(local[i] * scale * rms_w[j]);
    }
}

extern "C" void kernel_launch(void* const* d_in, const int* in_sizes, int n_in,
                              void* d_out, int out_size, void* d_ws, size_t ws_size,
                              hipStream_t stream) {
    int s3 = (in_sizes[3] == Bv * NTv) ? 1 : 0;
    const float* x      = (const float*)d_in[0];
    const float* cond   = (const float*)d_in[1];
    const float* timev  = (const float*)d_in[2];
    const int*   text   = (const int*)(s3 ? d_in[3] : d_in[32]);
    const float* table  = (const float*)d_in[3 + s3];
    const float* inp_w  = (const float*)d_in[4 + s3];
    const float* inp_b  = (const float*)d_in[5 + s3];
    const float* pos_w1 = (const float*)d_in[6 + s3];
    const float* pos_b1 = (const float*)d_in[7 + s3];
    const float* pos_w2 = (const float*)d_in[8 + s3];
    const float* pos_b2 = (const float*)d_in[9 + s3];
    const float* t_w1   = (const float*)d_in[10 + s3];
    const float* t_b1   = (const float*)d_in[11 + s3];
    const float* t_w2   = (const float*)d_in[12 + s3];
    const float* t_b2   = (const float*)d_in[13 + s3];
    const float* adaln_w= (const float*)d_in[14 + s3];
    const float* adaln_b= (const float*)d_in[15 + s3];
    const float* in_w   = (const float*)d_in[16 + s3];
    const float* conv_w = (const float*)d_in[17 + s3];
    const float* conv_b = (const float*)d_in[18 + s3];
    const float* dt_bias= (const float*)d_in[19 + s3];
    const float* A_log  = (const float*)d_in[20 + s3];
    const float* Dp     = (const float*)d_in[21 + s3];
    const float* rms_w  = (const float*)d_in[22 + s3];
    const float* out_w  = (const float*)d_in[23 + s3];
    const float* ff_w1  = (const float*)d_in[24 + s3];
    const float* ff_b1  = (const float*)d_in[25 + s3];
    const float* ff_w2  = (const float*)d_in[26 + s3];
    const float* ff_b2  = (const float*)d_in[27 + s3];
    const float* fin_w  = (const float*)d_in[28 + s3];
    const float* fin_b  = (const float*)d_in[29 + s3];
    const float* proj_w = (const float*)d_in[30 + s3];
    const float* proj_b = (const float*)d_in[31 + s3];

    // ---- workspace layout ----
    float* ws = (float*)d_ws;
    const size_t n_h = (size_t)Bv * Tv * DIMv;
    size_t off = 0;
    auto nx = [&](size_t n) { float* p = ws + off; off += n; return p; };
    float* h_   = nx(n_h);
    float* xn_  = nx(n_h);
    float* zx_  = nx((size_t)Bv * Tv * DINP);
    float* xbc_ = nx((size_t)Bv * Tv * CONVD);
    float* y_   = nx((size_t)Bv * Tv * DINNER);
    float* S_   = nx((size_t)Bv * CNv * NHv * PHv * NSv);
    float* ac_  = nx((size_t)Bv * CNv * NHv * QQv);
    float* at_  = nx((size_t)Bv * CNv * NHv);
    float* CB_  = nx((size_t)Bv * CNv * QQv * QQv);
    float* st_  = nx((size_t)Bv * DIMv);
    float* hid_ = nx((size_t)Bv * DIMv);
    float* mod_ = nx((size_t)DEPTHv * Bv * 6 * DIMv);
    float* fm_  = nx((size_t)Bv * 2 * DIMv);
    off = (off + 15) & ~(size_t)15;
    u16* wt_   = (u16*)(ws + off);              // 3456*768
    u16* xnb_  = wt_  + (size_t)3456 * 768;     // 4096x768
    u16* actb_ = xnb_ + (size_t)4096 * 768;     // 4096x1536
    u16* xnb2_ = actb_ + (size_t)4096 * 1536;   // 4096x768 conv1 out
    u16* pwt_  = xnb2_ + (size_t)4096 * 768;    // 768*1504
    u16* catb_ = pwt_ + (size_t)768 * PCK;      // 4096x736

    const int MT = Bv * Tv;

    // time embedding + modulation vectors (parallelized)
    temb1_kernel<<<dim3(3, Bv), 256, 0, stream>>>(timev, t_w1, t_b1, hid_);
    temb2_kernel<<<dim3(3, Bv), 256, 0, stream>>>(hid_, t_w2, t_b2, st_);
    modvec_kernel<<<dim3(18, Bv, DEPTHv), 256, 0, stream>>>(st_, adaln_w, adaln_b, mod_, 6 * DIMv);
    modvec_kernel<<<dim3(6, Bv, 1), 256, 0, stream>>>(st_, fin_w, fin_b, fm_, 2 * DIMv);

    // input concat (bf16) + bf16 MFMA projection
    concat_bf16<<<(unsigned)(((size_t)Bv * Tv * KCAT + 255) / 256), 256, 0, stream>>>(
        x, cond, table, text, catb_);
    wt_convert<<<dim3(768 / 32, KCAT / 32), 256, 0, stream>>>(inp_w, wt_, KCAT, 768, 712);
    gemm_bf16<1><<<dim3(6, 32), 256, 0, stream>>>(
        catb_, wt_, inp_b, h_, nullptr, MT, DIMv, KCAT, DIMv, nullptr, 0, 0);

    // pos-conv block (MFMA im2col)
    pw_convert<<<dim3(PCK / 32, DIMv / 32), 256, 0, stream>>>(pos_w1, pwt_);
    posconv_mfma<0, 0><<<dim3(Tv / 64, 16, Bv), 256, 0, stream>>>(h_, pwt_, pos_b1, xnb2_);
    pw_convert<<<dim3(PCK / 32, DIMv / 32), 256, 0, stream>>>(pos_w2, pwt_);
    posconv_mfma<1, 1><<<dim3(Tv / 64, 16, Bv), 256, 0, stream>>>(xnb2_, pwt_, pos_b2, h_);

    for (int l = 0; l < DEPTHv; l++) {
        const float* modl = mod_ + (size_t)l * Bv * 6 * DIMv;
        // ---- MSA/SSD branch ----
        ln_mod_kernel<1><<<MT, 256, 0, stream>>>(h_, xnb_, modl, DIMv, 0, 6 * DIMv);
        wt_convert<<<dim3(3456 / 32, 768 / 32), 256, 0, stream>>>(
            in_w + (size_t)l * DIMv * DINP, wt_, DIMv, DINP, DIMv);
        gemm_bf16<0><<<dim3(27, 32), 256, 0, stream>>>(
            xnb_, wt_, nullptr, zx_, nullptr, MT, DINP, DIMv, DINP, nullptr, 0, 0);
        dwconv_kernel<<<(unsigned)(((size_t)Bv * Tv * CONVD + 255) / 256), 256, 0, stream>>>(
            zx_, conv_w + (size_t)l * CONVD * KCONVv, conv_b + (size_t)l * CONVD, xbc_);
        ssd_cb<<<dim3(CNv, Bv), 256, 0, stream>>>(xbc_, CB_);
        ssd_part1m<<<dim3(NHv, CNv, Bv), 256, 0, stream>>>(
            xbc_, zx_, dt_bias + l * NHv, A_log + l * NHv, CB_, y_, S_, ac_, at_);
        ssd_scan<<<(Bv * NHv * PHv * NSv + 255) / 256, 256, 0, stream>>>(S_, at_);
        ssd_part2m<<<dim3(NHv, CNv, Bv), 256, 0, stream>>>(
            xbc_, S_, ac_, Dp + l * NHv, y_);
        gate_rms_kernel<<<MT, 256, 0, stream>>>(y_, zx_, rms_w + (size_t)l * DINNER, actb_);
        wt_convert<<<dim3(768 / 32, 1536 / 32), 256, 0, stream>>>(
            out_w + (size_t)l * DINNER * DIMv, wt_, DINNER, DIMv, DINNER);
        gemm_bf16<3><<<dim3(6, 32), 256, 0, stream>>>(
            actb_, wt_, nullptr, h_, nullptr, MT, DIMv, DINNER, DIMv, modl, 2 * DIMv, 6 * DIMv);
        // ---- MLP branch ----
        ln_mod_kernel<1><<<MT, 256, 0, stream>>>(h_, xnb_, modl, 4 * DIMv, 3 * DIMv, 6 * DIMv);
        wt_convert<<<dim3(1536 / 32, 768 / 32), 256, 0, stream>>>(
            ff_w1 + (size_t)l * DIMv * FFIv, wt_, DIMv, FFIv, DIMv);
        gemm_bf16<2><<<dim3(12, 32), 256, 0, stream>>>(
            xnb_, wt_, ff_b1 + (size_t)l * FFIv, nullptr, actb_, MT, FFIv, DIMv, FFIv, nullptr, 0, 0);
        wt_convert<<<dim3(768 / 32, 1536 / 32), 256, 0, stream>>>(
            ff_w2 + (size_t)l * FFIv * DIMv, wt_, FFIv, DIMv, FFIv);
        gemm_bf16<4><<<dim3(6, 32), 256, 0, stream>>>(
            actb_, wt_, ff_b2 + (size_t)l * DIMv, h_, nullptr, MT, DIMv, FFIv, DIMv, modl, 5 * DIMv, 6 * DIMv);
    }

    ln_mod_kernel<0><<<MT, 256, 0, stream>>>(h_, xn_, fm_, 0, DIMv, 2 * DIMv);
    gemm_f32<1><<<dim3((MELv + 63) / 64, (MT + 63) / 64), 256, 0, stream>>>(
        xn_, proj_w, proj_b, (float*)d_out, MT, MELv, DIMv);
}

// Round 6
// 2830.118 us; speedup vs baseline: 7.5971x; 1.1869x over previous
//
#include <hip/hip_runtime.h>
#include <math.h>

// ---- problem constants ----
constexpr int Bv = 2, Tv = 2048, NTv = 512;
constexpr int DIMv = 768, DEPTHv = 8, MELv = 100, TDIMv = 512;
constexpr int DINNER = 1536, NSv = 128, PHv = 64, QQv = 64;
constexpr int NHv = DINNER / PHv;              // 24
constexpr int CONVD = DINNER + 2 * NSv;        // 1792
constexpr int DINP = 2 * DINNER + 2 * NSv + NHv; // 3352
constexpr int KCONVv = 4, FFIv = 2 * DIMv;     // 1536
constexpr int CNv = Tv / QQv;                  // 32
constexpr int PCK = 1504;                      // 31*48 padded
constexpr int KCAT = 736;                      // 712 padded

typedef unsigned short u16;
typedef unsigned int u32;
typedef __attribute__((ext_vector_type(8))) short short8v;
typedef __attribute__((ext_vector_type(4))) float f32x4;

__device__ __forceinline__ float siluf(float x) { return x / (1.f + expf(-x)); }
__device__ __forceinline__ float softplusf(float x) { return x > 20.f ? x : log1pf(expf(x)); }
__device__ __forceinline__ float mishf(float x) { return x * tanhf(softplusf(x)); }

__device__ __forceinline__ u16 f2bf(float v) {
    u32 u = __builtin_bit_cast(u32, v);
    u32 r = (u + 0x7fffu + ((u >> 16) & 1u)) >> 16;
    return (u16)r;
}
__device__ __forceinline__ float bf2f(u16 v) {
    u32 u = (u32)v << 16;
    return __builtin_bit_cast(float, u);
}

__device__ __forceinline__ void gload16(const void* g, void* l) {
    __builtin_amdgcn_global_load_lds(
        (const __attribute__((address_space(1))) u32*)g,
        (__attribute__((address_space(3))) u32*)l, 16, 0, 0);
}

__device__ __forceinline__ float blockReduceSum(float v) {
    __shared__ float red[4];
    #pragma unroll
    for (int off = 32; off > 0; off >>= 1) v += __shfl_down(v, off, 64);
    __syncthreads();
    if ((threadIdx.x & 63) == 0) red[threadIdx.x >> 6] = v;
    __syncthreads();
    return red[0] + red[1] + red[2] + red[3];
}

// ---- bf16 MFMA GEMM: BM=64, BN=128, BK=32, 2-phase double-buffered ----
// EPI: 0 f32, 1 +bias f32, 2 +bias gelu bf16, 3 h+=g*acc, 4 h+=g*(acc+bias)
template <int EPI>
__global__ __launch_bounds__(256) void gemm_bf16(const u16* __restrict__ A,
        const u16* __restrict__ BT, const float* __restrict__ bias,
        float* __restrict__ Cf, u16* __restrict__ Cb,
        int M, int N, int K, int ldc,
        const float* __restrict__ modv, int goff, int mstride) {
    __shared__ __align__(16) u16 As[2][64 * 32];
    __shared__ __align__(16) u16 Bs[2][128 * 32];
    const int tid = threadIdx.x;
    const int m0 = blockIdx.y * 64, n0 = blockIdx.x * 128;
    const int lane = tid & 63;
    const int wid = tid >> 6;
    const int wn = wid * 32;
    f32x4 acc[4][2] = {};
    const int srow = tid >> 2, sseg = (tid & 3) * 8;
    const u16* Ag = A + (size_t)(m0 + srow) * K + sseg;
    const u16* Bg = BT + (size_t)(n0 + srow) * K + sseg;
    const int lr = lane & 15, lk = (lane >> 4) * 8;
    // prologue: stage tile 0
    gload16(Ag, &As[0][tid * 8]);
    gload16(Bg, &Bs[0][tid * 8]);
    gload16(Bg + (size_t)64 * K, &Bs[0][tid * 8 + 64 * 32]);
    __syncthreads();
    int cur = 0;
    for (int k0 = 0; k0 < K; k0 += 32) {
        if (k0 + 32 < K) {
            const int nb = cur ^ 1, kn = k0 + 32;
            gload16(Ag + kn, &As[nb][tid * 8]);
            gload16(Bg + kn, &Bs[nb][tid * 8]);
            gload16(Bg + kn + (size_t)64 * K, &Bs[nb][tid * 8 + 64 * 32]);
        }
        short8v a_f[4], b_f[2];
        #pragma unroll
        for (int i = 0; i < 4; i++)
            a_f[i] = *(const short8v*)&As[cur][(i * 16 + lr) * 32 + lk];
        #pragma unroll
        for (int j = 0; j < 2; j++)
            b_f[j] = *(const short8v*)&Bs[cur][(wn + j * 16 + lr) * 32 + lk];
        #pragma unroll
        for (int i = 0; i < 4; i++)
            #pragma unroll
            for (int j = 0; j < 2; j++)
                acc[i][j] = __builtin_amdgcn_mfma_f32_16x16x32_bf16(a_f[i], b_f[j], acc[i][j], 0, 0, 0);
        __syncthreads();
        cur ^= 1;
    }
    const int r0 = (lane >> 4) * 4;
    #pragma unroll
    for (int i = 0; i < 4; i++) {
        #pragma unroll
        for (int j = 0; j < 2; j++) {
            const int col = n0 + wn + j * 16 + lr;
            if (col >= N) continue;
            const int row = m0 + i * 16 + r0;
            const float bv = (EPI == 1 || EPI == 2 || EPI == 4) ? bias[col] : 0.f;
            #pragma unroll
            for (int r = 0; r < 4; r++) {
                float v = acc[i][j][r] + bv;
                if (EPI == 2) {
                    float xx = v;
                    v = 0.5f * xx * (1.f + tanhf(0.7978845608028654f * (xx + 0.044715f * xx * xx * xx)));
                    Cb[(size_t)(row + r) * ldc + col] = f2bf(v);
                } else if (EPI == 3 || EPI == 4) {
                    const int bb = (row + r) >> 11;   // row / Tv
                    float g = modv[(size_t)bb * mstride + goff + col];
                    Cf[(size_t)(row + r) * ldc + col] += g * v;
                } else {
                    Cf[(size_t)(row + r) * ldc + col] = v;
                }
            }
        }
    }
}

// ---- weight f32 [Kmax,N] -> bf16 transposed [Npad,Kpad], zero-filled ----
__global__ __launch_bounds__(256) void wt_convert(const float* __restrict__ W,
        u16* __restrict__ WT, int K, int N, int Kmax) {
    __shared__ float t[32][33];
    const int n0 = blockIdx.x * 32, k0 = blockIdx.y * 32;
    const int c = threadIdx.x & 31, rq = (threadIdx.x >> 5) * 4;
    #pragma unroll
    for (int i = 0; i < 4; i++) {
        int n = n0 + c, k = k0 + rq + i;
        t[rq + i][c] = (n < N && k < Kmax) ? W[(size_t)k * N + n] : 0.f;
    }
    __syncthreads();
    #pragma unroll
    for (int i = 0; i < 4; i++)
        WT[(size_t)(n0 + rq + i) * K + k0 + c] = f2bf(t[c][rq + i]);
}

// ---- pos-conv weight: w[31][48][768] -> WT[768][1504] bf16 ----
__global__ __launch_bounds__(256) void pw_convert(const float* __restrict__ w,
        u16* __restrict__ WT) {
    __shared__ float t[32][33];
    const int kk0 = blockIdx.x * 32, o0 = blockIdx.y * 32;
    const int c = threadIdx.x & 31, rq = (threadIdx.x >> 5) * 4;
    #pragma unroll
    for (int i = 0; i < 4; i++) {
        int kk = kk0 + rq + i;
        t[rq + i][c] = (kk < 1488) ? w[(size_t)kk * DIMv + o0 + c] : 0.f;
    }
    __syncthreads();
    #pragma unroll
    for (int i = 0; i < 4; i++)
        WT[(size_t)(o0 + rq + i) * PCK + kk0 + c] = f2bf(t[c][rq + i]);
}

// ---- grouped conv K=31 via implicit-im2col MFMA ----
template <int IN_BF, int FUSE>
__global__ __launch_bounds__(256) void posconv_mfma(const void* __restrict__ inv,
        const u16* __restrict__ WT, const float* __restrict__ bias,
        void* __restrict__ outv) {
    __shared__ __align__(16) u16 xs[95 * 48];
    const int t0 = blockIdx.x * 64, g = blockIdx.y, b = blockIdx.z;
    const int tid = threadIdx.x;
    for (int e = tid; e < 95 * 48; e += 256) {
        int rr = e / 48, cc = e % 48;
        int t = t0 - 15 + rr;
        float v = 0.f;
        if (t >= 0 && t < Tv) {
            size_t gi = ((size_t)b * Tv + t) * DIMv + g * 48 + cc;
            v = IN_BF ? bf2f(((const u16*)inv)[gi]) : ((const float*)inv)[gi];
        }
        xs[e] = f2bf(v);
    }
    __syncthreads();
    const int lane = tid & 63, w = tid >> 6;
    const int lr = lane & 15, lq8 = (lane >> 4) * 8, rq = (lane >> 4) * 4;
    const u16* arow = &xs[(w * 16 + lr) * 48 + lq8];
    const u16* brow = &WT[(size_t)(g * 48 + lr) * PCK + lq8];
    f32x4 acc[3] = {};
    #pragma unroll 2
    for (int ks = 0; ks < PCK / 32; ks++) {
        short8v a = *(const short8v*)(arow + ks * 32);
        #pragma unroll
        for (int j = 0; j < 3; j++) {
            short8v bf = *(const short8v*)(brow + (size_t)j * 16 * PCK + ks * 32);
            acc[j] = __builtin_amdgcn_mfma_f32_16x16x32_bf16(a, bf, acc[j], 0, 0, 0);
        }
    }
    #pragma unroll
    for (int j = 0; j < 3; j++) {
        const int o = g * 48 + j * 16 + lr;
        const float bvv = bias[o];
        #pragma unroll
        for (int r = 0; r < 4; r++) {
            const int t = t0 + w * 16 + rq + r;
            float v = acc[j][r] + bvv;
            size_t gi = ((size_t)b * Tv + t) * DIMv + o;
            if (FUSE == 0) ((u16*)outv)[gi] = f2bf(mishf(v));
            else ((float*)outv)[gi] += mishf(v);
        }
    }
}

// ---- time embedding stage 1 (k-split GEMV): hid = silu(te @ t_w1 + b1) ----
__global__ __launch_bounds__(256) void temb1_kernel(const float* __restrict__ timev,
        const float* __restrict__ t_w1, const float* __restrict__ t_b1,
        float* __restrict__ hid) {
    const int b = blockIdx.y;
    const int o = blockIdx.x * 64 + (threadIdx.x & 63);
    const int ks = threadIdx.x >> 6;
    __shared__ float te[256];
    __shared__ float part[4][64];
    {
        int j = threadIdx.x, f = j & 127;
        float fr = expf(-logf(10000.f) / 127.f * (float)f);
        float ang = 1000.f * timev[b] * fr;
        te[j] = (j < 128) ? sinf(ang) : cosf(ang);
    }
    __syncthreads();
    float acc = 0.f;
    #pragma unroll 8
    for (int k = ks * 64; k < ks * 64 + 64; k++) acc += te[k] * t_w1[(size_t)k * DIMv + o];
    part[ks][threadIdx.x & 63] = acc;
    __syncthreads();
    if (threadIdx.x < 64) {
        float r = part[0][threadIdx.x] + part[1][threadIdx.x] + part[2][threadIdx.x] + part[3][threadIdx.x]
                + t_b1[o];
        hid[b * DIMv + o] = siluf(r);
    }
}

// ---- time embedding stage 2 (k-split GEMV): st = silu(hid @ t_w2 + b2) ----
__global__ __launch_bounds__(256) void temb2_kernel(const float* __restrict__ hid,
        const float* __restrict__ t_w2, const float* __restrict__ t_b2,
        float* __restrict__ st_out) {
    const int b = blockIdx.y;
    const int o = blockIdx.x * 64 + (threadIdx.x & 63);
    const int ks = threadIdx.x >> 6;
    __shared__ float hv[DIMv];
    __shared__ float part[4][64];
    for (int j = threadIdx.x; j < DIMv; j += 256) hv[j] = hid[b * DIMv + j];
    __syncthreads();
    float acc = 0.f;
    #pragma unroll 8
    for (int k = ks * 192; k < ks * 192 + 192; k++) acc += hv[k] * t_w2[(size_t)k * DIMv + o];
    part[ks][threadIdx.x & 63] = acc;
    __syncthreads();
    if (threadIdx.x < 64) {
        float r = part[0][threadIdx.x] + part[1][threadIdx.x] + part[2][threadIdx.x] + part[3][threadIdx.x]
                + t_b2[o];
        st_out[b * DIMv + o] = siluf(r);
    }
}

// ---- batched modulation vectors (k-split GEMV), grid (N/64, Bv, L) ----
__global__ __launch_bounds__(256) void modvec_kernel(const float* __restrict__ st,
        const float* __restrict__ W, const float* __restrict__ bias,
        float* __restrict__ out, int N) {
    const int l = blockIdx.z, b = blockIdx.y;
    const int o = blockIdx.x * 64 + (threadIdx.x & 63);
    const int ks = threadIdx.x >> 6;
    __shared__ float sv[DIMv];
    __shared__ float part[4][64];
    for (int j = threadIdx.x; j < DIMv; j += 256) sv[j] = st[b * DIMv + j];
    __syncthreads();
    const float* Wl = W + (size_t)l * DIMv * N + o;
    float acc = 0.f;
    #pragma unroll 8
    for (int k = ks * 192; k < ks * 192 + 192; k++) acc += sv[k] * Wl[(size_t)k * N];
    part[ks][threadIdx.x & 63] = acc;
    __syncthreads();
    if (threadIdx.x < 64) {
        float r = part[0][threadIdx.x] + part[1][threadIdx.x] + part[2][threadIdx.x] + part[3][threadIdx.x]
                + bias[(size_t)l * N + o];
        out[((size_t)l * Bv + b) * N + o] = r;
    }
}

// ---- concat [x, cond, temb] -> bf16, K-padded to 736 ----
__global__ void concat_bf16(const float* __restrict__ x, const float* __restrict__ cond,
                            const float* __restrict__ table, const int* __restrict__ text,
                            u16* __restrict__ cat) {
    size_t i = (size_t)blockIdx.x * 256 + threadIdx.x;
    const size_t total = (size_t)Bv * Tv * KCAT;
    if (i >= total) return;
    int j = (int)(i % KCAT);
    size_t row = i / KCAT;
    int t = (int)(row % Tv), b = (int)(row / Tv);
    float v = 0.f;
    if (j < MELv) v = x[row * MELv + j];
    else if (j < 2 * MELv) v = cond[row * MELv + (j - MELv)];
    else if (j < 712) {
        int idx = (t < NTv) ? (text[b * NTv + t] + 1) : 0;
        v = table[(size_t)idx * TDIMv + (j - 2 * MELv)];
    }
    cat[i] = f2bf(v);
}

// ---- LayerNorm with adaLN modulation; BF=1 writes bf16 ----
template <int BF>
__global__ __launch_bounds__(256) void ln_mod_kernel(const float* __restrict__ h,
        void* __restrict__ outv, const float* __restrict__ modv,
        int sc_off, int sh_off, int mod_stride) {
    const int row = blockIdx.x;
    const int b = row / Tv;
    const float* hr = h + (size_t)row * DIMv;
    float s = 0.f;
    for (int j = threadIdx.x; j < DIMv; j += 256) s += hr[j];
    s = blockReduceSum(s);
    const float m = s / DIMv;
    float v = 0.f;
    for (int j = threadIdx.x; j < DIMv; j += 256) { float d = hr[j] - m; v += d * d; }
    v = blockReduceSum(v);
    const float rstd = rsqrtf(v / DIMv + 1e-6f);
    const float* mb = modv + (size_t)b * mod_stride;
    for (int j = threadIdx.x; j < DIMv; j += 256) {
        float val = (hr[j] - m) * rstd * (1.f + mb[sc_off + j]) + mb[sh_off + j];
        if (BF) ((u16*)outv)[(size_t)row * DIMv + j] = f2bf(val);
        else ((float*)outv)[(size_t)row * DIMv + j] = val;
    }
}

// ---- causal depthwise conv K=4 + silu ----
__global__ void dwconv_kernel(const float* __restrict__ zx, const float* __restrict__ cw,
                              const float* __restrict__ cb, float* __restrict__ xbc) {
    size_t i = (size_t)blockIdx.x * 256 + threadIdx.x;
    if (i >= (size_t)Bv * Tv * CONVD) return;
    int c = (int)(i % CONVD);
    size_t row = i / CONVD;
    int t = (int)(row % Tv);
    const float* base = zx + row * DINP + DINNER + c;
    float acc = cb[c];
    #pragma unroll
    for (int k = 0; k < KCONVv; k++) {
        int d = k - 3;
        if (t + d >= 0) acc += base[(ptrdiff_t)d * DINP] * cw[c * KCONVv + k];
    }
    xbc[i] = siluf(acc);
}

// ---- SSD: CB[q][s] = sum_n C[q,n]*B[s,n], h-independent, MFMA ----
__global__ __launch_bounds__(256) void ssd_cb(const float* __restrict__ xbc,
                                              float* __restrict__ CBg) {
    constexpr int ST = 136;
    __shared__ __align__(16) u16 Cs[64 * ST];
    __shared__ __align__(16) u16 Bs[64 * ST];
    const int c = blockIdx.x, b = blockIdx.y;
    const int tid = threadIdx.x;
    const size_t rowbase = (size_t)b * Tv + (size_t)c * QQv;
    for (int e = tid; e < 64 * 128; e += 256) {
        int r = e >> 7, n = e & 127;
        const float* src = &xbc[(rowbase + r) * CONVD + DINNER];
        Bs[r * ST + n] = f2bf(src[n]);
        Cs[r * ST + n] = f2bf(src[NSv + n]);
    }
    __syncthreads();
    const int lane = tid & 63, w = tid >> 6;
    const int lr = lane & 15, lk8 = (lane >> 4) * 8, rq = (lane >> 4) * 4;
    f32x4 acc[4] = {};
    #pragma unroll
    for (int ks = 0; ks < 4; ks++) {
        short8v a = *(const short8v*)&Cs[(w * 16 + lr) * ST + ks * 32 + lk8];
        #pragma unroll
        for (int j = 0; j < 4; j++) {
            short8v bf = *(const short8v*)&Bs[(j * 16 + lr) * ST + ks * 32 + lk8];
            acc[j] = __builtin_amdgcn_mfma_f32_16x16x32_bf16(a, bf, acc[j], 0, 0, 0);
        }
    }
    float* out = CBg + ((size_t)(b * CNv + c)) * 4096;
    #pragma unroll
    for (int j = 0; j < 4; j++)
        #pragma unroll
        for (int r = 0; r < 4; r++)
            out[(w * 16 + rq + r) * 64 + j * 16 + lr] = acc[j][r];
}

// ---- SSD part1 (dt fused): prefix-scan, y_in, chunk-state S ----
__global__ __launch_bounds__(256) void ssd_part1m(const float* __restrict__ xbc,
        const float* __restrict__ zx, const float* __restrict__ dt_bias,
        const float* __restrict__ A_log,
        const float* __restrict__ CBg, float* __restrict__ ybuf,
        float* __restrict__ Sg, float* __restrict__ acg, float* __restrict__ atg) {
    constexpr int ST64 = 72;
    __shared__ __align__(16) u16 xbT[64 * ST64];   // [p][s]
    __shared__ __align__(16) u16 Wsm[64 * ST64];   // [q][s]
    __shared__ __align__(16) u16 BT[128 * ST64];   // [n][s]
    __shared__ float ac[64], dts[64], erev[64];
    const int h = blockIdx.x, c = blockIdx.y, b = blockIdx.z;
    const int tid = threadIdx.x;
    const size_t rowbase = (size_t)b * Tv + (size_t)c * QQv;
    const size_t bch = ((size_t)b * CNv + c) * NHv + h;
    if (tid < 64) {
        float raw = zx[(rowbase + tid) * DINP + DINNER + CONVD + h] + dt_bias[h];
        float dtv = softplusf(raw);
        dts[tid] = dtv;
        float v = dtv * (-expf(A_log[h]));
        #pragma unroll
        for (int off = 1; off < 64; off <<= 1) {
            float t = __shfl_up(v, off, 64);
            if (tid >= off) v += t;
        }
        ac[tid] = v;
    }
    __syncthreads();
    const float ac63 = ac[63];
    if (tid < 64) {
        erev[tid] = expf(ac63 - ac[tid]);
        acg[bch * 64 + tid] = ac[tid];
        if (tid == 63) atg[bch] = expf(ac63);
    }
    for (int e = tid; e < 64 * 64; e += 256) {
        int s = e >> 6, p = e & 63;
        xbT[p * ST64 + s] = f2bf(dts[s] * xbc[(rowbase + s) * CONVD + h * PHv + p]);
    }
    for (int e = tid; e < 64 * 128; e += 256) {
        int s = e >> 7, n = e & 127;
        BT[n * ST64 + s] = f2bf(xbc[(rowbase + s) * CONVD + DINNER + n]);
    }
    {
        const float* cbrow = CBg + ((size_t)(b * CNv + c)) * 4096;
        for (int e = tid; e < 64 * 64; e += 256) {
            int q = e >> 6, s = e & 63;
            float wv = (s <= q) ? cbrow[e] * expf(ac[q] - ac[s]) : 0.f;
            Wsm[q * ST64 + s] = f2bf(wv);
        }
    }
    __syncthreads();
    const int lane = tid & 63, w = tid >> 6;
    const int lr = lane & 15, lk8 = (lane >> 4) * 8, rq = (lane >> 4) * 4;
    {
        f32x4 acc[4] = {};
        #pragma unroll
        for (int ks = 0; ks < 2; ks++) {
            short8v bf = *(const short8v*)&xbT[(w * 16 + lr) * ST64 + ks * 32 + lk8];
            #pragma unroll
            for (int i = 0; i < 4; i++) {
                short8v a = *(const short8v*)&Wsm[(i * 16 + lr) * ST64 + ks * 32 + lk8];
                acc[i] = __builtin_amdgcn_mfma_f32_16x16x32_bf16(a, bf, acc[i], 0, 0, 0);
            }
        }
        #pragma unroll
        for (int i = 0; i < 4; i++)
            #pragma unroll
            for (int r = 0; r < 4; r++) {
                int q = i * 16 + rq + r, p = w * 16 + lr;
                ybuf[(rowbase + q) * DINNER + h * PHv + p] = acc[i][r];
            }
    }
    __syncthreads();
    for (int e = tid; e < 64 * 64; e += 256) {
        int p = e >> 6, s = e & 63;
        xbT[p * ST64 + s] = f2bf(bf2f(xbT[p * ST64 + s]) * erev[s]);
    }
    __syncthreads();
    {
        f32x4 acc[4][2] = {};
        #pragma unroll
        for (int ks = 0; ks < 2; ks++) {
            short8v a[4];
            #pragma unroll
            for (int i = 0; i < 4; i++)
                a[i] = *(const short8v*)&xbT[(i * 16 + lr) * ST64 + ks * 32 + lk8];
            #pragma unroll
            for (int j = 0; j < 2; j++) {
                short8v bf = *(const short8v*)&BT[(w * 32 + j * 16 + lr) * ST64 + ks * 32 + lk8];
                #pragma unroll
                for (int i = 0; i < 4; i++)
                    acc[i][j] = __builtin_amdgcn_mfma_f32_16x16x32_bf16(a[i], bf, acc[i][j], 0, 0, 0);
            }
        }
        float* So = Sg + bch * (PHv * NSv);
        #pragma unroll
        for (int i = 0; i < 4; i++)
            #pragma unroll
            for (int j = 0; j < 2; j++)
                #pragma unroll
                for (int r = 0; r < 4; r++)
                    So[(i * 16 + rq + r) * NSv + w * 32 + j * 16 + lr] = acc[i][j][r];
    }
}

// ---- inter-chunk scan ----
__global__ void ssd_scan(float* __restrict__ Sg, const float* __restrict__ atg) {
    int idx = blockIdx.x * 256 + threadIdx.x;
    if (idx >= Bv * NHv * PHv * NSv) return;
    int n = idx % NSv;
    int p = (idx / NSv) % PHv;
    int h = (idx / (NSv * PHv)) % NHv;
    int b = idx / (NSv * PHv * NHv);
    float H = 0.f;
    for (int c = 0; c < CNv; c++) {
        size_t bch = ((size_t)b * CNv + c) * NHv + h;
        size_t off = bch * PHv * NSv + (size_t)p * NSv + n;
        float s = Sg[off];
        float at = atg[bch];
        Sg[off] = H;
        H = at * H + s;
    }
}

// ---- SSD part2: y += (C @ prev^T)*eac + D*x ----
__global__ __launch_bounds__(256) void ssd_part2m(const float* __restrict__ xbc,
        const float* __restrict__ Sg, const float* __restrict__ acg,
        const float* __restrict__ Dp, float* __restrict__ ybuf) {
    constexpr int ST = 136;
    __shared__ __align__(16) u16 Cs[64 * ST];
    __shared__ __align__(16) u16 Ps[64 * ST];
    __shared__ float eac[64];
    const int h = blockIdx.x, c = blockIdx.y, b = blockIdx.z;
    const int tid = threadIdx.x;
    const size_t rowbase = (size_t)b * Tv + (size_t)c * QQv;
    const size_t bch = ((size_t)b * CNv + c) * NHv + h;
    if (tid < 64) eac[tid] = expf(acg[bch * 64 + tid]);
    for (int e = tid; e < 64 * 128; e += 256) {
        int r = e >> 7, n = e & 127;
        Cs[r * ST + n] = f2bf(xbc[(rowbase + r) * CONVD + DINNER + NSv + n]);
        Ps[r * ST + n] = f2bf(Sg[bch * (PHv * NSv) + e]);
    }
    __syncthreads();
    const int lane = tid & 63, w = tid >> 6;
    const int lr = lane & 15, lk8 = (lane >> 4) * 8, rq = (lane >> 4) * 4;
    f32x4 acc[4] = {};
    #pragma unroll
    for (int ks = 0; ks < 4; ks++) {
        short8v bf = *(const short8v*)&Ps[(w * 16 + lr) * ST + ks * 32 + lk8];
        #pragma unroll
        for (int i = 0; i < 4; i++) {
            short8v a = *(const short8v*)&Cs[(i * 16 + lr) * ST + ks * 32 + lk8];
            acc[i] = __builtin_amdgcn_mfma_f32_16x16x32_bf16(a, bf, acc[i], 0, 0, 0);
        }
    }
    const float Dh = Dp[h];
    #pragma unroll
    for (int i = 0; i < 4; i++)
        #pragma unroll
        for (int r = 0; r < 4; r++) {
            int q = i * 16 + rq + r, p = w * 16 + lr;
            size_t row = rowbase + q;
            size_t yi = row * DINNER + h * PHv + p;
            float xv = xbc[row * CONVD + h * PHv + p];
            ybuf[yi] += acc[i][r] * eac[q] + Dh * xv;
        }
}

// ---- gate by silu(z), RMS norm, * rms_w -> bf16 ----
__global__ __launch_bounds__(256) void gate_rms_kernel(const float* __restrict__ y,
        const float* __restrict__ zx, const float* __restrict__ rms_w,
        u16* __restrict__ yb) {
    const int row = blockIdx.x;
    const float* yr = y + (size_t)row * DINNER;
    const float* zr = zx + (size_t)row * DINP;
    float local[6];
    float ss = 0.f;
    #pragma unroll
    for (int i = 0; i < 6; i++) {
        int j = threadIdx.x + i * 256;
        float v = yr[j] * siluf(zr[j]);
        local[i] = v;
        ss += v * v;
    }
    ss = blockReduceSum(ss);
    const float scale = rsqrtf(ss / DINNER + 1e-5f);
    #pragma unroll
    for (int i = 0; i < 6; i++) {
        int j = threadIdx.x + i * 256;
        yb[(size_t)row * DINNER + j] = f2bf(local[i] * scale * rms_w[j]);
    }
}

extern "C" void kernel_launch(void* const* d_in, const int* in_sizes, int n_in,
                              void* d_out, int out_size, void* d_ws, size_t ws_size,
                              hipStream_t stream) {
    int s3 = (in_sizes[3] == Bv * NTv) ? 1 : 0;
    const float* x      = (const float*)d_in[0];
    const float* cond   = (const float*)d_in[1];
    const float* timev  = (const float*)d_in[2];
    const int*   text   = (const int*)(s3 ? d_in[3] : d_in[32]);
    const float* table  = (const float*)d_in[3 + s3];
    const float* inp_w  = (const float*)d_in[4 + s3];
    const float* inp_b  = (const float*)d_in[5 + s3];
    const float* pos_w1 = (const float*)d_in[6 + s3];
    const float* pos_b1 = (const float*)d_in[7 + s3];
    const float* pos_w2 = (const float*)d_in[8 + s3];
    const float* pos_b2 = (const float*)d_in[9 + s3];
    const float* t_w1   = (const float*)d_in[10 + s3];
    const float* t_b1   = (const float*)d_in[11 + s3];
    const float* t_w2   = (const float*)d_in[12 + s3];
    const float* t_b2   = (const float*)d_in[13 + s3];
    const float* adaln_w= (const float*)d_in[14 + s3];
    const float* adaln_b= (const float*)d_in[15 + s3];
    const float* in_w   = (const float*)d_in[16 + s3];
    const float* conv_w = (const float*)d_in[17 + s3];
    const float* conv_b = (const float*)d_in[18 + s3];
    const float* dt_bias= (const float*)d_in[19 + s3];
    const float* A_log  = (const float*)d_in[20 + s3];
    const float* Dp     = (const float*)d_in[21 + s3];
    const float* rms_w  = (const float*)d_in[22 + s3];
    const float* out_w  = (const float*)d_in[23 + s3];
    const float* ff_w1  = (const float*)d_in[24 + s3];
    const float* ff_b1  = (const float*)d_in[25 + s3];
    const float* ff_w2  = (const float*)d_in[26 + s3];
    const float* ff_b2  = (const float*)d_in[27 + s3];
    const float* fin_w  = (const float*)d_in[28 + s3];
    const float* fin_b  = (const float*)d_in[29 + s3];
    const float* proj_w = (const float*)d_in[30 + s3];
    const float* proj_b = (const float*)d_in[31 + s3];

    // ---- workspace layout ----
    float* ws = (float*)d_ws;
    const size_t n_h = (size_t)Bv * Tv * DIMv;
    size_t off = 0;
    auto nx = [&](size_t n) { float* p = ws + off; off += n; return p; };
    float* h_   = nx(n_h);
    float* zx_  = nx((size_t)Bv * Tv * DINP);
    float* xbc_ = nx((size_t)Bv * Tv * CONVD);
    float* y_   = nx((size_t)Bv * Tv * DINNER);
    float* S_   = nx((size_t)Bv * CNv * NHv * PHv * NSv);
    float* ac_  = nx((size_t)Bv * CNv * NHv * QQv);
    float* at_  = nx((size_t)Bv * CNv * NHv);
    float* CB_  = nx((size_t)Bv * CNv * QQv * QQv);
    float* st_  = nx((size_t)Bv * DIMv);
    float* hid_ = nx((size_t)Bv * DIMv);
    float* mod_ = nx((size_t)DEPTHv * Bv * 6 * DIMv);
    float* fm_  = nx((size_t)Bv * 2 * DIMv);
    off = (off + 15) & ~(size_t)15;
    u16* wt_   = (u16*)(ws + off);              // 3456*768
    u16* xnb_  = wt_  + (size_t)3456 * 768;     // 4096x768
    u16* actb_ = xnb_ + (size_t)4096 * 768;     // 4096x1536
    u16* xnb2_ = actb_ + (size_t)4096 * 1536;   // 4096x768 conv1 out
    u16* pwt_  = xnb2_ + (size_t)4096 * 768;    // 768*1504
    u16* catb_ = pwt_ + (size_t)768 * PCK;      // 4096x736

    const int MT = Bv * Tv;

    // time embedding + modulation vectors (k-split GEMVs)
    temb1_kernel<<<dim3(DIMv / 64, Bv), 256, 0, stream>>>(timev, t_w1, t_b1, hid_);
    temb2_kernel<<<dim3(DIMv / 64, Bv), 256, 0, stream>>>(hid_, t_w2, t_b2, st_);
    modvec_kernel<<<dim3(6 * DIMv / 64, Bv, DEPTHv), 256, 0, stream>>>(st_, adaln_w, adaln_b, mod_, 6 * DIMv);
    modvec_kernel<<<dim3(2 * DIMv / 64, Bv, 1), 256, 0, stream>>>(st_, fin_w, fin_b, fm_, 2 * DIMv);

    // input concat (bf16) + bf16 MFMA projection
    concat_bf16<<<(unsigned)(((size_t)Bv * Tv * KCAT + 255) / 256), 256, 0, stream>>>(
        x, cond, table, text, catb_);
    wt_convert<<<dim3(768 / 32, KCAT / 32), 256, 0, stream>>>(inp_w, wt_, KCAT, 768, 712);
    gemm_bf16<1><<<dim3(6, 64), 256, 0, stream>>>(
        catb_, wt_, inp_b, h_, nullptr, MT, DIMv, KCAT, DIMv, nullptr, 0, 0);

    // pos-conv block (MFMA im2col)
    pw_convert<<<dim3(PCK / 32, DIMv / 32), 256, 0, stream>>>(pos_w1, pwt_);
    posconv_mfma<0, 0><<<dim3(Tv / 64, 16, Bv), 256, 0, stream>>>(h_, pwt_, pos_b1, xnb2_);
    pw_convert<<<dim3(PCK / 32, DIMv / 32), 256, 0, stream>>>(pos_w2, pwt_);
    posconv_mfma<1, 1><<<dim3(Tv / 64, 16, Bv), 256, 0, stream>>>(xnb2_, pwt_, pos_b2, h_);

    for (int l = 0; l < DEPTHv; l++) {
        const float* modl = mod_ + (size_t)l * Bv * 6 * DIMv;
        // ---- MSA/SSD branch ----
        ln_mod_kernel<1><<<MT, 256, 0, stream>>>(h_, xnb_, modl, DIMv, 0, 6 * DIMv);
        wt_convert<<<dim3(3456 / 32, 768 / 32), 256, 0, stream>>>(
            in_w + (size_t)l * DIMv * DINP, wt_, DIMv, DINP, DIMv);
        gemm_bf16<0><<<dim3(27, 64), 256, 0, stream>>>(
            xnb_, wt_, nullptr, zx_, nullptr, MT, DINP, DIMv, DINP, nullptr, 0, 0);
        dwconv_kernel<<<(unsigned)(((size_t)Bv * Tv * CONVD + 255) / 256), 256, 0, stream>>>(
            zx_, conv_w + (size_t)l * CONVD * KCONVv, conv_b + (size_t)l * CONVD, xbc_);
        ssd_cb<<<dim3(CNv, Bv), 256, 0, stream>>>(xbc_, CB_);
        ssd_part1m<<<dim3(NHv, CNv, Bv), 256, 0, stream>>>(
            xbc_, zx_, dt_bias + l * NHv, A_log + l * NHv, CB_, y_, S_, ac_, at_);
        ssd_scan<<<(Bv * NHv * PHv * NSv + 255) / 256, 256, 0, stream>>>(S_, at_);
        ssd_part2m<<<dim3(NHv, CNv, Bv), 256, 0, stream>>>(
            xbc_, S_, ac_, Dp + l * NHv, y_);
        gate_rms_kernel<<<MT, 256, 0, stream>>>(y_, zx_, rms_w + (size_t)l * DINNER, actb_);
        wt_convert<<<dim3(768 / 32, 1536 / 32), 256, 0, stream>>>(
            out_w + (size_t)l * DINNER * DIMv, wt_, DINNER, DIMv, DINNER);
        gemm_bf16<3><<<dim3(6, 64), 256, 0, stream>>>(
            actb_, wt_, nullptr, h_, nullptr, MT, DIMv, DINNER, DIMv, modl, 2 * DIMv, 6 * DIMv);
        // ---- MLP branch ----
        ln_mod_kernel<1><<<MT, 256, 0, stream>>>(h_, xnb_, modl, 4 * DIMv, 3 * DIMv, 6 * DIMv);
        wt_convert<<<dim3(1536 / 32, 768 / 32), 256, 0, stream>>>(
            ff_w1 + (size_t)l * DIMv * FFIv, wt_, DIMv, FFIv, DIMv);
        gemm_bf16<2><<<dim3(12, 64), 256, 0, stream>>>(
            xnb_, wt_, ff_b1 + (size_t)l * FFIv, nullptr, actb_, MT, FFIv, DIMv, FFIv, nullptr, 0, 0);
        wt_convert<<<dim3(768 / 32, 1536 / 32), 256, 0, stream>>>(
            ff_w2 + (size_t)l * FFIv * DIMv, wt_, FFIv, DIMv, FFIv);
        gemm_bf16<4><<<dim3(6, 64), 256, 0, stream>>>(
            actb_, wt_, ff_b2 + (size_t)l * DIMv, h_, nullptr, MT, DIMv, FFIv, DIMv, modl, 5 * DIMv, 6 * DIMv);
    }

    // final modulated LN (bf16) + bf16 MFMA projection to MEL
    ln_mod_kernel<1><<<MT, 256, 0, stream>>>(h_, xnb_, fm_, 0, DIMv, 2 * DIMv);
    wt_convert<<<dim3(128 / 32, 768 / 32), 256, 0, stream>>>(proj_w, wt_, DIMv, MELv, DIMv);
    gemm_bf16<1><<<dim3(1, 64), 256, 0, stream>>>(
        xnb_, wt_, proj_b, (float*)d_out, nullptr, MT, MELv, DIMv, MELv, nullptr, 0, 0);
}

// Round 7
// 2817.545 us; speedup vs baseline: 7.6310x; 1.0045x over previous
//
#include <hip/hip_runtime.h>
#include <math.h>

// ---- problem constants ----
constexpr int Bv = 2, Tv = 2048, NTv = 512;
constexpr int DIMv = 768, DEPTHv = 8, MELv = 100, TDIMv = 512;
constexpr int DINNER = 1536, NSv = 128, PHv = 64, QQv = 64;
constexpr int NHv = DINNER / PHv;              // 24
constexpr int CONVD = DINNER + 2 * NSv;        // 1792
constexpr int DINP = 2 * DINNER + 2 * NSv + NHv; // 3352
constexpr int KCONVv = 4, FFIv = 2 * DIMv;     // 1536
constexpr int CNv = Tv / QQv;                  // 32
constexpr int PCK = 1504;                      // 31*48 padded
constexpr int KCAT = 736;                      // 712 padded

typedef unsigned short u16;
typedef unsigned int u32;
typedef __attribute__((ext_vector_type(8))) short short8v;
typedef __attribute__((ext_vector_type(4))) float f32x4;

__device__ __forceinline__ float siluf(float x) { return x / (1.f + expf(-x)); }
__device__ __forceinline__ float softplusf(float x) { return x > 20.f ? x : log1pf(expf(x)); }
__device__ __forceinline__ float mishf(float x) { return x * tanhf(softplusf(x)); }

__device__ __forceinline__ u16 f2bf(float v) {
    u32 u = __builtin_bit_cast(u32, v);
    u32 r = (u + 0x7fffu + ((u >> 16) & 1u)) >> 16;
    return (u16)r;
}
__device__ __forceinline__ float bf2f(u16 v) {
    u32 u = (u32)v << 16;
    return __builtin_bit_cast(float, u);
}
__device__ __forceinline__ float bf2fs(short v) { return bf2f((u16)v); }

__device__ __forceinline__ void gload16(const void* g, void* l) {
    __builtin_amdgcn_global_load_lds(
        (const __attribute__((address_space(1))) u32*)g,
        (__attribute__((address_space(3))) u32*)l, 16, 0, 0);
}

__device__ __forceinline__ float blockReduceSum(float v) {
    __shared__ float red[4];
    #pragma unroll
    for (int off = 32; off > 0; off >>= 1) v += __shfl_down(v, off, 64);
    __syncthreads();
    if ((threadIdx.x & 63) == 0) red[threadIdx.x >> 6] = v;
    __syncthreads();
    return red[0] + red[1] + red[2] + red[3];
}

// ---- bf16 MFMA GEMM, 2-phase double-buffered ----
// BIG=1: BM=128,BN=128 ; BIG=0: BM=64,BN=128
// EPI: 0 -> bf16 out (no bias), 1 -> +bias f32, 2 -> +bias gelu bf16,
//      3 -> h += g*acc (f32), 4 -> h += g*(acc+bias) (f32)
template <int EPI, int BIG>
__global__ __launch_bounds__(256) void gemm_bf16(const u16* __restrict__ A,
        const u16* __restrict__ BT, const float* __restrict__ bias,
        float* __restrict__ Cf, u16* __restrict__ Cb,
        int M, int N, int K, int ldc,
        const float* __restrict__ modv, int goff, int mstride) {
    constexpr int BM = BIG ? 128 : 64;
    constexpr int MI = BIG ? 4 : 4;     // m-frags per wave
    constexpr int NJ = BIG ? 4 : 2;     // n-frags per wave
    __shared__ __align__(16) u16 As[2][BM * 32];
    __shared__ __align__(16) u16 Bs[2][128 * 32];
    const int tid = threadIdx.x;
    const int m0 = blockIdx.y * BM, n0 = blockIdx.x * 128;
    const int lane = tid & 63;
    const int wid = tid >> 6;
    const int wm = BIG ? (wid >> 1) * 64 : 0;
    const int wn = BIG ? (wid & 1) * 64 : wid * 32;
    f32x4 acc[MI][NJ] = {};
    const int srow = tid >> 2, sseg = (tid & 3) * 8;
    const u16* Ag = A + (size_t)(m0 + srow) * K + sseg;
    const u16* Bg = BT + (size_t)(n0 + srow) * K + sseg;
    const int lr = lane & 15, lk = (lane >> 4) * 8;
    // prologue: stage tile 0
    gload16(Ag, &As[0][tid * 8]);
    if (BIG) gload16(Ag + (size_t)64 * K, &As[0][tid * 8 + 64 * 32]);
    gload16(Bg, &Bs[0][tid * 8]);
    gload16(Bg + (size_t)64 * K, &Bs[0][tid * 8 + 64 * 32]);
    __syncthreads();
    int cur = 0;
    for (int k0 = 0; k0 < K; k0 += 32) {
        if (k0 + 32 < K) {
            const int nb = cur ^ 1, kn = k0 + 32;
            gload16(Ag + kn, &As[nb][tid * 8]);
            if (BIG) gload16(Ag + kn + (size_t)64 * K, &As[nb][tid * 8 + 64 * 32]);
            gload16(Bg + kn, &Bs[nb][tid * 8]);
            gload16(Bg + kn + (size_t)64 * K, &Bs[nb][tid * 8 + 64 * 32]);
        }
        short8v a_f[MI], b_f[NJ];
        #pragma unroll
        for (int i = 0; i < MI; i++)
            a_f[i] = *(const short8v*)&As[cur][(wm + i * 16 + lr) * 32 + lk];
        #pragma unroll
        for (int j = 0; j < NJ; j++)
            b_f[j] = *(const short8v*)&Bs[cur][(wn + j * 16 + lr) * 32 + lk];
        #pragma unroll
        for (int i = 0; i < MI; i++)
            #pragma unroll
            for (int j = 0; j < NJ; j++)
                acc[i][j] = __builtin_amdgcn_mfma_f32_16x16x32_bf16(a_f[i], b_f[j], acc[i][j], 0, 0, 0);
        __syncthreads();
        cur ^= 1;
    }
    const int r0 = (lane >> 4) * 4;
    #pragma unroll
    for (int i = 0; i < MI; i++) {
        #pragma unroll
        for (int j = 0; j < NJ; j++) {
            const int col = n0 + wn + j * 16 + lr;
            if (col >= N) continue;
            const int row = m0 + wm + i * 16 + r0;
            const float bv = (EPI == 1 || EPI == 2 || EPI == 4) ? bias[col] : 0.f;
            #pragma unroll
            for (int r = 0; r < 4; r++) {
                float v = acc[i][j][r] + bv;
                if (EPI == 0) {
                    Cb[(size_t)(row + r) * ldc + col] = f2bf(v);
                } else if (EPI == 2) {
                    float xx = v;
                    v = 0.5f * xx * (1.f + tanhf(0.7978845608028654f * (xx + 0.044715f * xx * xx * xx)));
                    Cb[(size_t)(row + r) * ldc + col] = f2bf(v);
                } else if (EPI == 3 || EPI == 4) {
                    const int bb = (row + r) >> 11;   // row / Tv
                    float g = modv[(size_t)bb * mstride + goff + col];
                    Cf[(size_t)(row + r) * ldc + col] += g * v;
                } else {
                    Cf[(size_t)(row + r) * ldc + col] = v;
                }
            }
        }
    }
}

// ---- weight f32 [Kmax,N] -> bf16 transposed [Npad,Kpad], zero-filled ----
__global__ __launch_bounds__(256) void wt_convert(const float* __restrict__ W,
        u16* __restrict__ WT, int K, int N, int Kmax) {
    __shared__ float t[32][33];
    const int n0 = blockIdx.x * 32, k0 = blockIdx.y * 32;
    const int c = threadIdx.x & 31, rq = (threadIdx.x >> 5) * 4;
    #pragma unroll
    for (int i = 0; i < 4; i++) {
        int n = n0 + c, k = k0 + rq + i;
        t[rq + i][c] = (n < N && k < Kmax) ? W[(size_t)k * N + n] : 0.f;
    }
    __syncthreads();
    #pragma unroll
    for (int i = 0; i < 4; i++)
        WT[(size_t)(n0 + rq + i) * K + k0 + c] = f2bf(t[c][rq + i]);
}

// ---- pos-conv weight: w[31][48][768] -> WT[768][1504] bf16 ----
__global__ __launch_bounds__(256) void pw_convert(const float* __restrict__ w,
        u16* __restrict__ WT) {
    __shared__ float t[32][33];
    const int kk0 = blockIdx.x * 32, o0 = blockIdx.y * 32;
    const int c = threadIdx.x & 31, rq = (threadIdx.x >> 5) * 4;
    #pragma unroll
    for (int i = 0; i < 4; i++) {
        int kk = kk0 + rq + i;
        t[rq + i][c] = (kk < 1488) ? w[(size_t)kk * DIMv + o0 + c] : 0.f;
    }
    __syncthreads();
    #pragma unroll
    for (int i = 0; i < 4; i++)
        WT[(size_t)(o0 + rq + i) * PCK + kk0 + c] = f2bf(t[c][rq + i]);
}

// ---- grouped conv K=31 via implicit-im2col MFMA ----
template <int IN_BF, int FUSE>
__global__ __launch_bounds__(256) void posconv_mfma(const void* __restrict__ inv,
        const u16* __restrict__ WT, const float* __restrict__ bias,
        void* __restrict__ outv) {
    __shared__ __align__(16) u16 xs[95 * 48];
    const int t0 = blockIdx.x * 64, g = blockIdx.y, b = blockIdx.z;
    const int tid = threadIdx.x;
    for (int e = tid; e < 95 * 48; e += 256) {
        int rr = e / 48, cc = e % 48;
        int t = t0 - 15 + rr;
        float v = 0.f;
        if (t >= 0 && t < Tv) {
            size_t gi = ((size_t)b * Tv + t) * DIMv + g * 48 + cc;
            v = IN_BF ? bf2f(((const u16*)inv)[gi]) : ((const float*)inv)[gi];
        }
        xs[e] = f2bf(v);
    }
    __syncthreads();
    const int lane = tid & 63, w = tid >> 6;
    const int lr = lane & 15, lq8 = (lane >> 4) * 8, rq = (lane >> 4) * 4;
    const u16* arow = &xs[(w * 16 + lr) * 48 + lq8];
    const u16* brow = &WT[(size_t)(g * 48 + lr) * PCK + lq8];
    f32x4 acc[3] = {};
    #pragma unroll 2
    for (int ks = 0; ks < PCK / 32; ks++) {
        short8v a = *(const short8v*)(arow + ks * 32);
        #pragma unroll
        for (int j = 0; j < 3; j++) {
            short8v bf = *(const short8v*)(brow + (size_t)j * 16 * PCK + ks * 32);
            acc[j] = __builtin_amdgcn_mfma_f32_16x16x32_bf16(a, bf, acc[j], 0, 0, 0);
        }
    }
    #pragma unroll
    for (int j = 0; j < 3; j++) {
        const int o = g * 48 + j * 16 + lr;
        const float bvv = bias[o];
        #pragma unroll
        for (int r = 0; r < 4; r++) {
            const int t = t0 + w * 16 + rq + r;
            float v = acc[j][r] + bvv;
            size_t gi = ((size_t)b * Tv + t) * DIMv + o;
            if (FUSE == 0) ((u16*)outv)[gi] = f2bf(mishf(v));
            else ((float*)outv)[gi] += mishf(v);
        }
    }
}

// ---- time embedding stage 1 ----
__global__ __launch_bounds__(256) void temb1_kernel(const float* __restrict__ timev,
        const float* __restrict__ t_w1, const float* __restrict__ t_b1,
        float* __restrict__ hid) {
    const int b = blockIdx.y;
    const int o = blockIdx.x * 64 + (threadIdx.x & 63);
    const int ks = threadIdx.x >> 6;
    __shared__ float te[256];
    __shared__ float part[4][64];
    {
        int j = threadIdx.x, f = j & 127;
        float fr = expf(-logf(10000.f) / 127.f * (float)f);
        float ang = 1000.f * timev[b] * fr;
        te[j] = (j < 128) ? sinf(ang) : cosf(ang);
    }
    __syncthreads();
    float acc = 0.f;
    #pragma unroll 8
    for (int k = ks * 64; k < ks * 64 + 64; k++) acc += te[k] * t_w1[(size_t)k * DIMv + o];
    part[ks][threadIdx.x & 63] = acc;
    __syncthreads();
    if (threadIdx.x < 64) {
        float r = part[0][threadIdx.x] + part[1][threadIdx.x] + part[2][threadIdx.x] + part[3][threadIdx.x]
                + t_b1[o];
        hid[b * DIMv + o] = siluf(r);
    }
}

// ---- time embedding stage 2 ----
__global__ __launch_bounds__(256) void temb2_kernel(const float* __restrict__ hid,
        const float* __restrict__ t_w2, const float* __restrict__ t_b2,
        float* __restrict__ st_out) {
    const int b = blockIdx.y;
    const int o = blockIdx.x * 64 + (threadIdx.x & 63);
    const int ks = threadIdx.x >> 6;
    __shared__ float hv[DIMv];
    __shared__ float part[4][64];
    for (int j = threadIdx.x; j < DIMv; j += 256) hv[j] = hid[b * DIMv + j];
    __syncthreads();
    float acc = 0.f;
    #pragma unroll 8
    for (int k = ks * 192; k < ks * 192 + 192; k++) acc += hv[k] * t_w2[(size_t)k * DIMv + o];
    part[ks][threadIdx.x & 63] = acc;
    __syncthreads();
    if (threadIdx.x < 64) {
        float r = part[0][threadIdx.x] + part[1][threadIdx.x] + part[2][threadIdx.x] + part[3][threadIdx.x]
                + t_b2[o];
        st_out[b * DIMv + o] = siluf(r);
    }
}

// ---- batched modulation vectors ----
__global__ __launch_bounds__(256) void modvec_kernel(const float* __restrict__ st,
        const float* __restrict__ W, const float* __restrict__ bias,
        float* __restrict__ out, int N) {
    const int l = blockIdx.z, b = blockIdx.y;
    const int o = blockIdx.x * 64 + (threadIdx.x & 63);
    const int ks = threadIdx.x >> 6;
    __shared__ float sv[DIMv];
    __shared__ float part[4][64];
    for (int j = threadIdx.x; j < DIMv; j += 256) sv[j] = st[b * DIMv + j];
    __syncthreads();
    const float* Wl = W + (size_t)l * DIMv * N + o;
    float acc = 0.f;
    #pragma unroll 8
    for (int k = ks * 192; k < ks * 192 + 192; k++) acc += sv[k] * Wl[(size_t)k * N];
    part[ks][threadIdx.x & 63] = acc;
    __syncthreads();
    if (threadIdx.x < 64) {
        float r = part[0][threadIdx.x] + part[1][threadIdx.x] + part[2][threadIdx.x] + part[3][threadIdx.x]
                + bias[(size_t)l * N + o];
        out[((size_t)l * Bv + b) * N + o] = r;
    }
}

// ---- concat [x, cond, temb] -> bf16 ----
__global__ void concat_bf16(const float* __restrict__ x, const float* __restrict__ cond,
                            const float* __restrict__ table, const int* __restrict__ text,
                            u16* __restrict__ cat) {
    size_t i = (size_t)blockIdx.x * 256 + threadIdx.x;
    const size_t total = (size_t)Bv * Tv * KCAT;
    if (i >= total) return;
    int j = (int)(i % KCAT);
    size_t row = i / KCAT;
    int t = (int)(row % Tv), b = (int)(row / Tv);
    float v = 0.f;
    if (j < MELv) v = x[row * MELv + j];
    else if (j < 2 * MELv) v = cond[row * MELv + (j - MELv)];
    else if (j < 712) {
        int idx = (t < NTv) ? (text[b * NTv + t] + 1) : 0;
        v = table[(size_t)idx * TDIMv + (j - 2 * MELv)];
    }
    cat[i] = f2bf(v);
}

// ---- LayerNorm with adaLN modulation; BF=1 writes bf16 ----
template <int BF>
__global__ __launch_bounds__(256) void ln_mod_kernel(const float* __restrict__ h,
        void* __restrict__ outv, const float* __restrict__ modv,
        int sc_off, int sh_off, int mod_stride) {
    const int row = blockIdx.x;
    const int b = row / Tv;
    const float* hr = h + (size_t)row * DIMv;
    float s = 0.f;
    for (int j = threadIdx.x; j < DIMv; j += 256) s += hr[j];
    s = blockReduceSum(s);
    const float m = s / DIMv;
    float v = 0.f;
    for (int j = threadIdx.x; j < DIMv; j += 256) { float d = hr[j] - m; v += d * d; }
    v = blockReduceSum(v);
    const float rstd = rsqrtf(v / DIMv + 1e-6f);
    const float* mb = modv + (size_t)b * mod_stride;
    for (int j = threadIdx.x; j < DIMv; j += 256) {
        float val = (hr[j] - m) * rstd * (1.f + mb[sc_off + j]) + mb[sh_off + j];
        if (BF) ((u16*)outv)[(size_t)row * DIMv + j] = f2bf(val);
        else ((float*)outv)[(size_t)row * DIMv + j] = val;
    }
}

// ---- causal depthwise conv K=4 + silu, bf16 in/out, 8 ch/thread ----
__global__ void dwconv_kernel(const u16* __restrict__ zxb, const float* __restrict__ cw,
                              const float* __restrict__ cb, u16* __restrict__ xbcb) {
    size_t i = (size_t)blockIdx.x * 256 + threadIdx.x;
    const size_t total = (size_t)Bv * Tv * (CONVD / 8);
    if (i >= total) return;
    const int c8 = (int)(i % (CONVD / 8)) * 8;
    const size_t row = i / (CONVD / 8);
    const int t = (int)(row % Tv);
    const u16* base = zxb + row * DINP + DINNER + c8;
    float acc[8];
    #pragma unroll
    for (int u = 0; u < 8; u++) acc[u] = cb[c8 + u];
    #pragma unroll
    for (int k = 0; k < KCONVv; k++) {
        const int d = k - 3;
        if (t + d < 0) continue;
        short8v tv = *(const short8v*)(base + (ptrdiff_t)d * DINP);
        #pragma unroll
        for (int u = 0; u < 8; u++)
            acc[u] += bf2fs(tv[u]) * cw[(c8 + u) * KCONVv + k];
    }
    short8v outv;
    #pragma unroll
    for (int u = 0; u < 8; u++) outv[u] = (short)f2bf(siluf(acc[u]));
    *(short8v*)(xbcb + row * CONVD + c8) = outv;
}

// ---- SSD: CB[q][s] = sum_n C[q,n]*B[s,n] ----
__global__ __launch_bounds__(256) void ssd_cb(const u16* __restrict__ xbcb,
                                              float* __restrict__ CBg) {
    constexpr int ST = 136;
    __shared__ __align__(16) u16 Cs[64 * ST];
    __shared__ __align__(16) u16 Bs[64 * ST];
    const int c = blockIdx.x, b = blockIdx.y;
    const int tid = threadIdx.x;
    const size_t rowbase = (size_t)b * Tv + (size_t)c * QQv;
    for (int e = tid; e < 64 * 16; e += 256) {
        int r = e >> 4, n8 = (e & 15) * 8;
        const u16* src = &xbcb[(rowbase + r) * CONVD + DINNER];
        *(short8v*)&Bs[r * ST + n8] = *(const short8v*)(src + n8);
        *(short8v*)&Cs[r * ST + n8] = *(const short8v*)(src + NSv + n8);
    }
    __syncthreads();
    const int lane = tid & 63, w = tid >> 6;
    const int lr = lane & 15, lk8 = (lane >> 4) * 8, rq = (lane >> 4) * 4;
    f32x4 acc[4] = {};
    #pragma unroll
    for (int ks = 0; ks < 4; ks++) {
        short8v a = *(const short8v*)&Cs[(w * 16 + lr) * ST + ks * 32 + lk8];
        #pragma unroll
        for (int j = 0; j < 4; j++) {
            short8v bf = *(const short8v*)&Bs[(j * 16 + lr) * ST + ks * 32 + lk8];
            acc[j] = __builtin_amdgcn_mfma_f32_16x16x32_bf16(a, bf, acc[j], 0, 0, 0);
        }
    }
    float* out = CBg + ((size_t)(b * CNv + c)) * 4096;
    #pragma unroll
    for (int j = 0; j < 4; j++)
        #pragma unroll
        for (int r = 0; r < 4; r++)
            out[(w * 16 + rq + r) * 64 + j * 16 + lr] = acc[j][r];
}

// ---- SSD part1: prefix-scan, y_in, chunk-state S (bf16 xbc/zx/y) ----
__global__ __launch_bounds__(256) void ssd_part1m(const u16* __restrict__ xbcb,
        const u16* __restrict__ zxb, const float* __restrict__ dt_bias,
        const float* __restrict__ A_log,
        const float* __restrict__ CBg, u16* __restrict__ ybuf,
        float* __restrict__ Sg, float* __restrict__ acg, float* __restrict__ atg) {
    constexpr int ST64 = 72;
    __shared__ __align__(16) u16 xbT[64 * ST64];   // [p][s]
    __shared__ __align__(16) u16 Wsm[64 * ST64];   // [q][s]
    __shared__ __align__(16) u16 BT[128 * ST64];   // [n][s]
    __shared__ float ac[64], dts[64], erev[64];
    const int h = blockIdx.x, c = blockIdx.y, b = blockIdx.z;
    const int tid = threadIdx.x;
    const size_t rowbase = (size_t)b * Tv + (size_t)c * QQv;
    const size_t bch = ((size_t)b * CNv + c) * NHv + h;
    if (tid < 64) {
        float raw = bf2f(zxb[(rowbase + tid) * DINP + DINNER + CONVD + h]) + dt_bias[h];
        float dtv = softplusf(raw);
        dts[tid] = dtv;
        float v = dtv * (-expf(A_log[h]));
        #pragma unroll
        for (int off = 1; off < 64; off <<= 1) {
            float t = __shfl_up(v, off, 64);
            if (tid >= off) v += t;
        }
        ac[tid] = v;
    }
    __syncthreads();
    const float ac63 = ac[63];
    if (tid < 64) {
        erev[tid] = expf(ac63 - ac[tid]);
        acg[bch * 64 + tid] = ac[tid];
        if (tid == 63) atg[bch] = expf(ac63);
    }
    for (int e = tid; e < 64 * 64; e += 256) {
        int s = e >> 6, p = e & 63;
        xbT[p * ST64 + s] = f2bf(dts[s] * bf2f(xbcb[(rowbase + s) * CONVD + h * PHv + p]));
    }
    for (int e = tid; e < 64 * 128; e += 256) {
        int s = e >> 7, n = e & 127;
        BT[n * ST64 + s] = xbcb[(rowbase + s) * CONVD + DINNER + n];
    }
    {
        const float* cbrow = CBg + ((size_t)(b * CNv + c)) * 4096;
        for (int e = tid; e < 64 * 64; e += 256) {
            int q = e >> 6, s = e & 63;
            float wv = (s <= q) ? cbrow[e] * expf(ac[q] - ac[s]) : 0.f;
            Wsm[q * ST64 + s] = f2bf(wv);
        }
    }
    __syncthreads();
    const int lane = tid & 63, w = tid >> 6;
    const int lr = lane & 15, lk8 = (lane >> 4) * 8, rq = (lane >> 4) * 4;
    {
        f32x4 acc[4] = {};
        #pragma unroll
        for (int ks = 0; ks < 2; ks++) {
            short8v bf = *(const short8v*)&xbT[(w * 16 + lr) * ST64 + ks * 32 + lk8];
            #pragma unroll
            for (int i = 0; i < 4; i++) {
                short8v a = *(const short8v*)&Wsm[(i * 16 + lr) * ST64 + ks * 32 + lk8];
                acc[i] = __builtin_amdgcn_mfma_f32_16x16x32_bf16(a, bf, acc[i], 0, 0, 0);
            }
        }
        #pragma unroll
        for (int i = 0; i < 4; i++)
            #pragma unroll
            for (int r = 0; r < 4; r++) {
                int q = i * 16 + rq + r, p = w * 16 + lr;
                ybuf[(rowbase + q) * DINNER + h * PHv + p] = f2bf(acc[i][r]);
            }
    }
    __syncthreads();
    for (int e = tid; e < 64 * 64; e += 256) {
        int p = e >> 6, s = e & 63;
        xbT[p * ST64 + s] = f2bf(bf2f(xbT[p * ST64 + s]) * erev[s]);
    }
    __syncthreads();
    {
        f32x4 acc[4][2] = {};
        #pragma unroll
        for (int ks = 0; ks < 2; ks++) {
            short8v a[4];
            #pragma unroll
            for (int i = 0; i < 4; i++)
                a[i] = *(const short8v*)&xbT[(i * 16 + lr) * ST64 + ks * 32 + lk8];
            #pragma unroll
            for (int j = 0; j < 2; j++) {
                short8v bf = *(const short8v*)&BT[(w * 32 + j * 16 + lr) * ST64 + ks * 32 + lk8];
                #pragma unroll
                for (int i = 0; i < 4; i++)
                    acc[i][j] = __builtin_amdgcn_mfma_f32_16x16x32_bf16(a[i], bf, acc[i][j], 0, 0, 0);
            }
        }
        float* So = Sg + bch * (PHv * NSv);
        #pragma unroll
        for (int i = 0; i < 4; i++)
            #pragma unroll
            for (int j = 0; j < 2; j++)
                #pragma unroll
                for (int r = 0; r < 4; r++)
                    So[(i * 16 + rq + r) * NSv + w * 32 + j * 16 + lr] = acc[i][j][r];
    }
}

// ---- inter-chunk scan ----
__global__ void ssd_scan(float* __restrict__ Sg, const float* __restrict__ atg) {
    int idx = blockIdx.x * 256 + threadIdx.x;
    if (idx >= Bv * NHv * PHv * NSv) return;
    int n = idx % NSv;
    int p = (idx / NSv) % PHv;
    int h = (idx / (NSv * PHv)) % NHv;
    int b = idx / (NSv * PHv * NHv);
    float H = 0.f;
    for (int c = 0; c < CNv; c++) {
        size_t bch = ((size_t)b * CNv + c) * NHv + h;
        size_t off = bch * PHv * NSv + (size_t)p * NSv + n;
        float s = Sg[off];
        float at = atg[bch];
        Sg[off] = H;
        H = at * H + s;
    }
}

// ---- SSD part2: y += (C @ prev^T)*eac + D*x (bf16 y) ----
__global__ __launch_bounds__(256) void ssd_part2m(const u16* __restrict__ xbcb,
        const float* __restrict__ Sg, const float* __restrict__ acg,
        const float* __restrict__ Dp, u16* __restrict__ ybuf) {
    constexpr int ST = 136;
    __shared__ __align__(16) u16 Cs[64 * ST];
    __shared__ __align__(16) u16 Ps[64 * ST];
    __shared__ float eac[64];
    const int h = blockIdx.x, c = blockIdx.y, b = blockIdx.z;
    const int tid = threadIdx.x;
    const size_t rowbase = (size_t)b * Tv + (size_t)c * QQv;
    const size_t bch = ((size_t)b * CNv + c) * NHv + h;
    if (tid < 64) eac[tid] = expf(acg[bch * 64 + tid]);
    for (int e = tid; e < 64 * 16; e += 256) {
        int r = e >> 4, n8 = (e & 15) * 8;
        *(short8v*)&Cs[r * ST + n8] =
            *(const short8v*)&xbcb[(rowbase + r) * CONVD + DINNER + NSv + n8];
    }
    for (int e = tid; e < 64 * 32; e += 256) {
        int r = e >> 5, n4 = (e & 31) * 4;
        f32x4 pv = *(const f32x4*)&Sg[bch * (PHv * NSv) + (size_t)r * NSv + n4];
        u16* dst = &Ps[r * ST + n4];
        dst[0] = f2bf(pv[0]); dst[1] = f2bf(pv[1]); dst[2] = f2bf(pv[2]); dst[3] = f2bf(pv[3]);
    }
    __syncthreads();
    const int lane = tid & 63, w = tid >> 6;
    const int lr = lane & 15, lk8 = (lane >> 4) * 8, rq = (lane >> 4) * 4;
    f32x4 acc[4] = {};
    #pragma unroll
    for (int ks = 0; ks < 4; ks++) {
        short8v bf = *(const short8v*)&Ps[(w * 16 + lr) * ST + ks * 32 + lk8];
        #pragma unroll
        for (int i = 0; i < 4; i++) {
            short8v a = *(const short8v*)&Cs[(i * 16 + lr) * ST + ks * 32 + lk8];
            acc[i] = __builtin_amdgcn_mfma_f32_16x16x32_bf16(a, bf, acc[i], 0, 0, 0);
        }
    }
    const float Dh = Dp[h];
    #pragma unroll
    for (int i = 0; i < 4; i++)
        #pragma unroll
        for (int r = 0; r < 4; r++) {
            int q = i * 16 + rq + r, p = w * 16 + lr;
            size_t row = rowbase + q;
            size_t yi = row * DINNER + h * PHv + p;
            float xv = bf2f(xbcb[row * CONVD + h * PHv + p]);
            ybuf[yi] = f2bf(bf2f(ybuf[yi]) + acc[i][r] * eac[q] + Dh * xv);
        }
}

// ---- gate by silu(z), RMS norm, * rms_w (bf16 in/out) ----
__global__ __launch_bounds__(256) void gate_rms_kernel(const u16* __restrict__ y,
        const u16* __restrict__ zxb, const float* __restrict__ rms_w,
        u16* __restrict__ yb) {
    const int row = blockIdx.x;
    const u16* yr = y + (size_t)row * DINNER;
    const u16* zr = zxb + (size_t)row * DINP;
    float vals[8];
    float ss = 0.f;
    const int tid = threadIdx.x;
    if (tid < 192) {
        short8v yv = *(const short8v*)(yr + tid * 8);
        short8v zv = *(const short8v*)(zr + tid * 8);
        #pragma unroll
        for (int u = 0; u < 8; u++) {
            float v = bf2fs(yv[u]) * siluf(bf2fs(zv[u]));
            vals[u] = v;
            ss += v * v;
        }
    }
    ss = blockReduceSum(ss);
    const float scale = rsqrtf(ss / DINNER + 1e-5f);
    if (tid < 192) {
        short8v outv;
        #pragma unroll
        for (int u = 0; u < 8; u++)
            outv[u] = (short)f2bf(vals[u] * scale * rms_w[tid * 8 + u]);
        *(short8v*)(yb + (size_t)row * DINNER + tid * 8) = outv;
    }
}

extern "C" void kernel_launch(void* const* d_in, const int* in_sizes, int n_in,
                              void* d_out, int out_size, void* d_ws, size_t ws_size,
                              hipStream_t stream) {
    int s3 = (in_sizes[3] == Bv * NTv) ? 1 : 0;
    const float* x      = (const float*)d_in[0];
    const float* cond   = (const float*)d_in[1];
    const float* timev  = (const float*)d_in[2];
    const int*   text   = (const int*)(s3 ? d_in[3] : d_in[32]);
    const float* table  = (const float*)d_in[3 + s3];
    const float* inp_w  = (const float*)d_in[4 + s3];
    const float* inp_b  = (const float*)d_in[5 + s3];
    const float* pos_w1 = (const float*)d_in[6 + s3];
    const float* pos_b1 = (const float*)d_in[7 + s3];
    const float* pos_w2 = (const float*)d_in[8 + s3];
    const float* pos_b2 = (const float*)d_in[9 + s3];
    const float* t_w1   = (const float*)d_in[10 + s3];
    const float* t_b1   = (const float*)d_in[11 + s3];
    const float* t_w2   = (const float*)d_in[12 + s3];
    const float* t_b2   = (const float*)d_in[13 + s3];
    const float* adaln_w= (const float*)d_in[14 + s3];
    const float* adaln_b= (const float*)d_in[15 + s3];
    const float* in_w   = (const float*)d_in[16 + s3];
    const float* conv_w = (const float*)d_in[17 + s3];
    const float* conv_b = (const float*)d_in[18 + s3];
    const float* dt_bias= (const float*)d_in[19 + s3];
    const float* A_log  = (const float*)d_in[20 + s3];
    const float* Dp     = (const float*)d_in[21 + s3];
    const float* rms_w  = (const float*)d_in[22 + s3];
    const float* out_w  = (const float*)d_in[23 + s3];
    const float* ff_w1  = (const float*)d_in[24 + s3];
    const float* ff_b1  = (const float*)d_in[25 + s3];
    const float* ff_w2  = (const float*)d_in[26 + s3];
    const float* ff_b2  = (const float*)d_in[27 + s3];
    const float* fin_w  = (const float*)d_in[28 + s3];
    const float* fin_b  = (const float*)d_in[29 + s3];
    const float* proj_w = (const float*)d_in[30 + s3];
    const float* proj_b = (const float*)d_in[31 + s3];

    // ---- workspace layout ----
    float* ws = (float*)d_ws;
    const size_t n_h = (size_t)Bv * Tv * DIMv;
    size_t off = 0;
    auto nx = [&](size_t n) { float* p = ws + off; off += n; return p; };
    float* h_   = nx(n_h);
    float* S_   = nx((size_t)Bv * CNv * NHv * PHv * NSv);
    float* ac_  = nx((size_t)Bv * CNv * NHv * QQv);
    float* at_  = nx((size_t)Bv * CNv * NHv);
    float* CB_  = nx((size_t)Bv * CNv * QQv * QQv);
    float* st_  = nx((size_t)Bv * DIMv);
    float* hid_ = nx((size_t)Bv * DIMv);
    float* mod_ = nx((size_t)DEPTHv * Bv * 6 * DIMv);
    float* fm_  = nx((size_t)Bv * 2 * DIMv);
    off = (off + 15) & ~(size_t)15;
    u16* wt_   = (u16*)(ws + off);              // 3456*768
    u16* zxb_  = wt_   + (size_t)3456 * 768;    // 4096x3352
    u16* xbcb_ = zxb_  + (size_t)4096 * DINP;   // 4096x1792
    u16* yb_   = xbcb_ + (size_t)4096 * CONVD;  // 4096x1536
    u16* xnb_  = yb_   + (size_t)4096 * 1536;   // 4096x768
    u16* actb_ = xnb_  + (size_t)4096 * 768;    // 4096x1536
    u16* xnb2_ = actb_ + (size_t)4096 * 1536;   // 4096x768 conv1 out
    u16* pwt_  = xnb2_ + (size_t)4096 * 768;    // 768*1504
    u16* catb_ = pwt_  + (size_t)768 * PCK;     // 4096x736

    const int MT = Bv * Tv;

    // time embedding + modulation vectors
    temb1_kernel<<<dim3(DIMv / 64, Bv), 256, 0, stream>>>(timev, t_w1, t_b1, hid_);
    temb2_kernel<<<dim3(DIMv / 64, Bv), 256, 0, stream>>>(hid_, t_w2, t_b2, st_);
    modvec_kernel<<<dim3(6 * DIMv / 64, Bv, DEPTHv), 256, 0, stream>>>(st_, adaln_w, adaln_b, mod_, 6 * DIMv);
    modvec_kernel<<<dim3(2 * DIMv / 64, Bv, 1), 256, 0, stream>>>(st_, fin_w, fin_b, fm_, 2 * DIMv);

    // input concat + projection
    concat_bf16<<<(unsigned)(((size_t)Bv * Tv * KCAT + 255) / 256), 256, 0, stream>>>(
        x, cond, table, text, catb_);
    wt_convert<<<dim3(768 / 32, KCAT / 32), 256, 0, stream>>>(inp_w, wt_, KCAT, 768, 712);
    gemm_bf16<1, 0><<<dim3(6, 64), 256, 0, stream>>>(
        catb_, wt_, inp_b, h_, nullptr, MT, DIMv, KCAT, DIMv, nullptr, 0, 0);

    // pos-conv block
    pw_convert<<<dim3(PCK / 32, DIMv / 32), 256, 0, stream>>>(pos_w1, pwt_);
    posconv_mfma<0, 0><<<dim3(Tv / 64, 16, Bv), 256, 0, stream>>>(h_, pwt_, pos_b1, xnb2_);
    pw_convert<<<dim3(PCK / 32, DIMv / 32), 256, 0, stream>>>(pos_w2, pwt_);
    posconv_mfma<1, 1><<<dim3(Tv / 64, 16, Bv), 256, 0, stream>>>(xnb2_, pwt_, pos_b2, h_);

    for (int l = 0; l < DEPTHv; l++) {
        const float* modl = mod_ + (size_t)l * Bv * 6 * DIMv;
        // ---- MSA/SSD branch ----
        ln_mod_kernel<1><<<MT, 256, 0, stream>>>(h_, xnb_, modl, DIMv, 0, 6 * DIMv);
        wt_convert<<<dim3(3456 / 32, 768 / 32), 256, 0, stream>>>(
            in_w + (size_t)l * DIMv * DINP, wt_, DIMv, DINP, DIMv);
        gemm_bf16<0, 1><<<dim3(27, 32), 256, 0, stream>>>(
            xnb_, wt_, nullptr, nullptr, zxb_, MT, DINP, DIMv, DINP, nullptr, 0, 0);
        dwconv_kernel<<<(unsigned)(((size_t)Bv * Tv * (CONVD / 8) + 255) / 256), 256, 0, stream>>>(
            zxb_, conv_w + (size_t)l * CONVD * KCONVv, conv_b + (size_t)l * CONVD, xbcb_);
        ssd_cb<<<dim3(CNv, Bv), 256, 0, stream>>>(xbcb_, CB_);
        ssd_part1m<<<dim3(NHv, CNv, Bv), 256, 0, stream>>>(
            xbcb_, zxb_, dt_bias + l * NHv, A_log + l * NHv, CB_, yb_, S_, ac_, at_);
        ssd_scan<<<(Bv * NHv * PHv * NSv + 255) / 256, 256, 0, stream>>>(S_, at_);
        ssd_part2m<<<dim3(NHv, CNv, Bv), 256, 0, stream>>>(
            xbcb_, S_, ac_, Dp + l * NHv, yb_);
        gate_rms_kernel<<<MT, 256, 0, stream>>>(yb_, zxb_, rms_w + (size_t)l * DINNER, actb_);
        wt_convert<<<dim3(768 / 32, 1536 / 32), 256, 0, stream>>>(
            out_w + (size_t)l * DINNER * DIMv, wt_, DINNER, DIMv, DINNER);
        gemm_bf16<3, 0><<<dim3(6, 64), 256, 0, stream>>>(
            actb_, wt_, nullptr, h_, nullptr, MT, DIMv, DINNER, DIMv, modl, 2 * DIMv, 6 * DIMv);
        // ---- MLP branch ----
        ln_mod_kernel<1><<<MT, 256, 0, stream>>>(h_, xnb_, modl, 4 * DIMv, 3 * DIMv, 6 * DIMv);
        wt_convert<<<dim3(1536 / 32, 768 / 32), 256, 0, stream>>>(
            ff_w1 + (size_t)l * DIMv * FFIv, wt_, DIMv, FFIv, DIMv);
        gemm_bf16<2, 1><<<dim3(12, 32), 256, 0, stream>>>(
            xnb_, wt_, ff_b1 + (size_t)l * FFIv, nullptr, actb_, MT, FFIv, DIMv, FFIv, nullptr, 0, 0);
        wt_convert<<<dim3(768 / 32, 1536 / 32), 256, 0, stream>>>(
            ff_w2 + (size_t)l * FFIv * DIMv, wt_, FFIv, DIMv, FFIv);
        gemm_bf16<4, 0><<<dim3(6, 64), 256, 0, stream>>>(
            actb_, wt_, ff_b2 + (size_t)l * DIMv, h_, nullptr, MT, DIMv, FFIv, DIMv, modl, 5 * DIMv, 6 * DIMv);
    }

    // final modulated LN + projection
    ln_mod_kernel<1><<<MT, 256, 0, stream>>>(h_, xnb_, fm_, 0, DIMv, 2 * DIMv);
    wt_convert<<<dim3(128 / 32, 768 / 32), 256, 0, stream>>>(proj_w, wt_, DIMv, MELv, DIMv);
    gemm_bf16<1, 0><<<dim3(1, 64), 256, 0, stream>>>(
        xnb_, wt_, proj_b, (float*)d_out, nullptr, MT, MELv, DIMv, MELv, nullptr, 0, 0);
}

// Round 8
// 2477.127 us; speedup vs baseline: 8.6797x; 1.1374x over previous
//
#include <hip/hip_runtime.h>
#include <math.h>

// ---- problem constants ----
constexpr int Bv = 2, Tv = 2048, NTv = 512;
constexpr int DIMv = 768, DEPTHv = 8, MELv = 100, TDIMv = 512;
constexpr int DINNER = 1536, NSv = 128, PHv = 64, QQv = 64;
constexpr int NHv = DINNER / PHv;              // 24
constexpr int CONVD = DINNER + 2 * NSv;        // 1792
constexpr int DINP = 2 * DINNER + 2 * NSv + NHv; // 3352
constexpr int KCONVv = 4, FFIv = 2 * DIMv;     // 1536
constexpr int CNv = Tv / QQv;                  // 32
constexpr int PCK = 1504;                      // 31*48 padded
constexpr int KCAT = 736;                      // 712 padded

typedef unsigned short u16;
typedef unsigned int u32;
typedef __attribute__((ext_vector_type(8))) short short8v;
typedef __attribute__((ext_vector_type(4))) float f32x4;

__device__ __forceinline__ float siluf(float x) { return x / (1.f + expf(-x)); }
__device__ __forceinline__ float softplusf(float x) { return x > 20.f ? x : log1pf(expf(x)); }
__device__ __forceinline__ float mishf(float x) { return x * tanhf(softplusf(x)); }

__device__ __forceinline__ u16 f2bf(float v) {
    u32 u = __builtin_bit_cast(u32, v);
    u32 r = (u + 0x7fffu + ((u >> 16) & 1u)) >> 16;
    return (u16)r;
}
__device__ __forceinline__ float bf2f(u16 v) {
    u32 u = (u32)v << 16;
    return __builtin_bit_cast(float, u);
}
__device__ __forceinline__ float bf2fs(short v) { return bf2f((u16)v); }

__device__ __forceinline__ void gload16(const void* g, void* l) {
    __builtin_amdgcn_global_load_lds(
        (const __attribute__((address_space(1))) u32*)g,
        (__attribute__((address_space(3))) u32*)l, 16, 0, 0);
}

__device__ __forceinline__ float blockReduceSum(float v) {
    __shared__ float red[4];
    #pragma unroll
    for (int off = 32; off > 0; off >>= 1) v += __shfl_down(v, off, 64);
    __syncthreads();
    if ((threadIdx.x & 63) == 0) red[threadIdx.x >> 6] = v;
    __syncthreads();
    return red[0] + red[1] + red[2] + red[3];
}

// ---- bf16 MFMA GEMM, 2-phase double-buffered, XCD-swizzled ----
// BIG=1: BM=128 ; BIG=0: BM=64.  Requires grid count % 8 == 0.
// EPI: 0 bf16 out, 1 +bias f32, 2 +bias gelu bf16, 3 h+=g*acc, 4 h+=g*(acc+bias)
template <int EPI, int BIG>
__global__ __launch_bounds__(256) void gemm_bf16(const u16* __restrict__ A,
        const u16* __restrict__ BT, const float* __restrict__ bias,
        float* __restrict__ Cf, u16* __restrict__ Cb,
        int M, int N, int K, int ldc,
        const float* __restrict__ modv, int goff, int mstride) {
    constexpr int BM = BIG ? 128 : 64;
    constexpr int MI = 4;
    constexpr int NJ = BIG ? 4 : 2;
    __shared__ __align__(16) u16 As[2][BM * 32];
    __shared__ __align__(16) u16 Bs[2][128 * 32];
    const int tid = threadIdx.x;
    // XCD-aware bijective swizzle (T1): contiguous chunk per XCD
    const int gx = gridDim.x;
    const int nwg = gx * gridDim.y;
    int flat = blockIdx.y * gx + blockIdx.x;
    const int qq = nwg >> 3;
    flat = (flat & 7) * qq + (flat >> 3);
    const int m0 = (flat / gx) * BM, n0 = (flat % gx) * 128;
    const int lane = tid & 63;
    const int wid = tid >> 6;
    const int wm = BIG ? (wid >> 1) * 64 : 0;
    const int wn = BIG ? (wid & 1) * 64 : wid * 32;
    f32x4 acc[MI][NJ] = {};
    const int srow = tid >> 2, sseg = (tid & 3) * 8;
    const u16* Ag = A + (size_t)(m0 + srow) * K + sseg;
    const u16* Bg = BT + (size_t)(n0 + srow) * K + sseg;
    const int lr = lane & 15, lk = (lane >> 4) * 8;
    gload16(Ag, &As[0][tid * 8]);
    if (BIG) gload16(Ag + (size_t)64 * K, &As[0][tid * 8 + 64 * 32]);
    gload16(Bg, &Bs[0][tid * 8]);
    gload16(Bg + (size_t)64 * K, &Bs[0][tid * 8 + 64 * 32]);
    __syncthreads();
    int cur = 0;
    for (int k0 = 0; k0 < K; k0 += 32) {
        if (k0 + 32 < K) {
            const int nb = cur ^ 1, kn = k0 + 32;
            gload16(Ag + kn, &As[nb][tid * 8]);
            if (BIG) gload16(Ag + kn + (size_t)64 * K, &As[nb][tid * 8 + 64 * 32]);
            gload16(Bg + kn, &Bs[nb][tid * 8]);
            gload16(Bg + kn + (size_t)64 * K, &Bs[nb][tid * 8 + 64 * 32]);
        }
        short8v a_f[MI], b_f[NJ];
        #pragma unroll
        for (int i = 0; i < MI; i++)
            a_f[i] = *(const short8v*)&As[cur][(wm + i * 16 + lr) * 32 + lk];
        #pragma unroll
        for (int j = 0; j < NJ; j++)
            b_f[j] = *(const short8v*)&Bs[cur][(wn + j * 16 + lr) * 32 + lk];
        #pragma unroll
        for (int i = 0; i < MI; i++)
            #pragma unroll
            for (int j = 0; j < NJ; j++)
                acc[i][j] = __builtin_amdgcn_mfma_f32_16x16x32_bf16(a_f[i], b_f[j], acc[i][j], 0, 0, 0);
        __syncthreads();
        cur ^= 1;
    }
    const int r0 = (lane >> 4) * 4;
    #pragma unroll
    for (int i = 0; i < MI; i++) {
        #pragma unroll
        for (int j = 0; j < NJ; j++) {
            const int col = n0 + wn + j * 16 + lr;
            if (col >= N) continue;
            const int row = m0 + wm + i * 16 + r0;
            const float bv = (EPI == 1 || EPI == 2 || EPI == 4) ? bias[col] : 0.f;
            #pragma unroll
            for (int r = 0; r < 4; r++) {
                float v = acc[i][j][r] + bv;
                if (EPI == 0) {
                    Cb[(size_t)(row + r) * ldc + col] = f2bf(v);
                } else if (EPI == 2) {
                    float xx = v;
                    v = 0.5f * xx * (1.f + tanhf(0.7978845608028654f * (xx + 0.044715f * xx * xx * xx)));
                    Cb[(size_t)(row + r) * ldc + col] = f2bf(v);
                } else if (EPI == 3 || EPI == 4) {
                    const int bb = (row + r) >> 11;   // row / Tv
                    float g = modv[(size_t)bb * mstride + goff + col];
                    Cf[(size_t)(row + r) * ldc + col] += g * v;
                } else {
                    Cf[(size_t)(row + r) * ldc + col] = v;
                }
            }
        }
    }
}

// ---- batched weight convert: f32 [Kmax,N] (per layer) -> bf16 [Npad,Kd] ----
__global__ __launch_bounds__(256) void wt_convert_b(const float* __restrict__ W,
        u16* __restrict__ WT, int Kd, int N, int Kmax, int Npad) {
    const float* Wl = W + (size_t)blockIdx.z * Kmax * N;
    u16* WTl = WT + (size_t)blockIdx.z * Npad * Kd;
    __shared__ float t[32][33];
    const int n0 = blockIdx.x * 32, k0 = blockIdx.y * 32;
    const int c = threadIdx.x & 31, rq = (threadIdx.x >> 5) * 4;
    #pragma unroll
    for (int i = 0; i < 4; i++) {
        int n = n0 + c, k = k0 + rq + i;
        t[rq + i][c] = (n < N && k < Kmax) ? Wl[(size_t)k * N + n] : 0.f;
    }
    __syncthreads();
    #pragma unroll
    for (int i = 0; i < 4; i++)
        WTl[(size_t)(n0 + rq + i) * Kd + k0 + c] = f2bf(t[c][rq + i]);
}

// ---- pos-conv weight: w[31][48][768] -> WT[768][1504] bf16 ----
__global__ __launch_bounds__(256) void pw_convert(const float* __restrict__ w,
        u16* __restrict__ WT) {
    __shared__ float t[32][33];
    const int kk0 = blockIdx.x * 32, o0 = blockIdx.y * 32;
    const int c = threadIdx.x & 31, rq = (threadIdx.x >> 5) * 4;
    #pragma unroll
    for (int i = 0; i < 4; i++) {
        int kk = kk0 + rq + i;
        t[rq + i][c] = (kk < 1488) ? w[(size_t)kk * DIMv + o0 + c] : 0.f;
    }
    __syncthreads();
    #pragma unroll
    for (int i = 0; i < 4; i++)
        WT[(size_t)(o0 + rq + i) * PCK + kk0 + c] = f2bf(t[c][rq + i]);
}

// ---- grouped conv K=31 via implicit-im2col MFMA ----
template <int IN_BF, int FUSE>
__global__ __launch_bounds__(256) void posconv_mfma(const void* __restrict__ inv,
        const u16* __restrict__ WT, const float* __restrict__ bias,
        void* __restrict__ outv) {
    __shared__ __align__(16) u16 xs[95 * 48];
    const int t0 = blockIdx.x * 64, g = blockIdx.y, b = blockIdx.z;
    const int tid = threadIdx.x;
    for (int e = tid; e < 95 * 48; e += 256) {
        int rr = e / 48, cc = e % 48;
        int t = t0 - 15 + rr;
        float v = 0.f;
        if (t >= 0 && t < Tv) {
            size_t gi = ((size_t)b * Tv + t) * DIMv + g * 48 + cc;
            v = IN_BF ? bf2f(((const u16*)inv)[gi]) : ((const float*)inv)[gi];
        }
        xs[e] = f2bf(v);
    }
    __syncthreads();
    const int lane = tid & 63, w = tid >> 6;
    const int lr = lane & 15, lq8 = (lane >> 4) * 8, rq = (lane >> 4) * 4;
    const u16* arow = &xs[(w * 16 + lr) * 48 + lq8];
    const u16* brow = &WT[(size_t)(g * 48 + lr) * PCK + lq8];
    f32x4 acc[3] = {};
    #pragma unroll 2
    for (int ks = 0; ks < PCK / 32; ks++) {
        short8v a = *(const short8v*)(arow + ks * 32);
        #pragma unroll
        for (int j = 0; j < 3; j++) {
            short8v bf = *(const short8v*)(brow + (size_t)j * 16 * PCK + ks * 32);
            acc[j] = __builtin_amdgcn_mfma_f32_16x16x32_bf16(a, bf, acc[j], 0, 0, 0);
        }
    }
    #pragma unroll
    for (int j = 0; j < 3; j++) {
        const int o = g * 48 + j * 16 + lr;
        const float bvv = bias[o];
        #pragma unroll
        for (int r = 0; r < 4; r++) {
            const int t = t0 + w * 16 + rq + r;
            float v = acc[j][r] + bvv;
            size_t gi = ((size_t)b * Tv + t) * DIMv + o;
            if (FUSE == 0) ((u16*)outv)[gi] = f2bf(mishf(v));
            else ((float*)outv)[gi] += mishf(v);
        }
    }
}

// ---- time embedding stage 1 ----
__global__ __launch_bounds__(256) void temb1_kernel(const float* __restrict__ timev,
        const float* __restrict__ t_w1, const float* __restrict__ t_b1,
        float* __restrict__ hid) {
    const int b = blockIdx.y;
    const int o = blockIdx.x * 64 + (threadIdx.x & 63);
    const int ks = threadIdx.x >> 6;
    __shared__ float te[256];
    __shared__ float part[4][64];
    {
        int j = threadIdx.x, f = j & 127;
        float fr = expf(-logf(10000.f) / 127.f * (float)f);
        float ang = 1000.f * timev[b] * fr;
        te[j] = (j < 128) ? sinf(ang) : cosf(ang);
    }
    __syncthreads();
    float acc = 0.f;
    #pragma unroll 8
    for (int k = ks * 64; k < ks * 64 + 64; k++) acc += te[k] * t_w1[(size_t)k * DIMv + o];
    part[ks][threadIdx.x & 63] = acc;
    __syncthreads();
    if (threadIdx.x < 64) {
        float r = part[0][threadIdx.x] + part[1][threadIdx.x] + part[2][threadIdx.x] + part[3][threadIdx.x]
                + t_b1[o];
        hid[b * DIMv + o] = siluf(r);
    }
}

// ---- time embedding stage 2 ----
__global__ __launch_bounds__(256) void temb2_kernel(const float* __restrict__ hid,
        const float* __restrict__ t_w2, const float* __restrict__ t_b2,
        float* __restrict__ st_out) {
    const int b = blockIdx.y;
    const int o = blockIdx.x * 64 + (threadIdx.x & 63);
    const int ks = threadIdx.x >> 6;
    __shared__ float hv[DIMv];
    __shared__ float part[4][64];
    for (int j = threadIdx.x; j < DIMv; j += 256) hv[j] = hid[b * DIMv + j];
    __syncthreads();
    float acc = 0.f;
    #pragma unroll 8
    for (int k = ks * 192; k < ks * 192 + 192; k++) acc += hv[k] * t_w2[(size_t)k * DIMv + o];
    part[ks][threadIdx.x & 63] = acc;
    __syncthreads();
    if (threadIdx.x < 64) {
        float r = part[0][threadIdx.x] + part[1][threadIdx.x] + part[2][threadIdx.x] + part[3][threadIdx.x]
                + t_b2[o];
        st_out[b * DIMv + o] = siluf(r);
    }
}

// ---- batched modulation vectors ----
__global__ __launch_bounds__(256) void modvec_kernel(const float* __restrict__ st,
        const float* __restrict__ W, const float* __restrict__ bias,
        float* __restrict__ out, int N) {
    const int l = blockIdx.z, b = blockIdx.y;
    const int o = blockIdx.x * 64 + (threadIdx.x & 63);
    const int ks = threadIdx.x >> 6;
    __shared__ float sv[DIMv];
    __shared__ float part[4][64];
    for (int j = threadIdx.x; j < DIMv; j += 256) sv[j] = st[b * DIMv + j];
    __syncthreads();
    const float* Wl = W + (size_t)l * DIMv * N + o;
    float acc = 0.f;
    #pragma unroll 8
    for (int k = ks * 192; k < ks * 192 + 192; k++) acc += sv[k] * Wl[(size_t)k * N];
    part[ks][threadIdx.x & 63] = acc;
    __syncthreads();
    if (threadIdx.x < 64) {
        float r = part[0][threadIdx.x] + part[1][threadIdx.x] + part[2][threadIdx.x] + part[3][threadIdx.x]
                + bias[(size_t)l * N + o];
        out[((size_t)l * Bv + b) * N + o] = r;
    }
}

// ---- concat [x, cond, temb] -> bf16 ----
__global__ void concat_bf16(const float* __restrict__ x, const float* __restrict__ cond,
                            const float* __restrict__ table, const int* __restrict__ text,
                            u16* __restrict__ cat) {
    size_t i = (size_t)blockIdx.x * 256 + threadIdx.x;
    const size_t total = (size_t)Bv * Tv * KCAT;
    if (i >= total) return;
    int j = (int)(i % KCAT);
    size_t row = i / KCAT;
    int t = (int)(row % Tv), b = (int)(row / Tv);
    float v = 0.f;
    if (j < MELv) v = x[row * MELv + j];
    else if (j < 2 * MELv) v = cond[row * MELv + (j - MELv)];
    else if (j < 712) {
        int idx = (t < NTv) ? (text[b * NTv + t] + 1) : 0;
        v = table[(size_t)idx * TDIMv + (j - 2 * MELv)];
    }
    cat[i] = f2bf(v);
}

// ---- LayerNorm with adaLN modulation; BF=1 writes bf16 ----
template <int BF>
__global__ __launch_bounds__(256) void ln_mod_kernel(const float* __restrict__ h,
        void* __restrict__ outv, const float* __restrict__ modv,
        int sc_off, int sh_off, int mod_stride) {
    const int row = blockIdx.x;
    const int b = row / Tv;
    const float* hr = h + (size_t)row * DIMv;
    float s = 0.f;
    for (int j = threadIdx.x; j < DIMv; j += 256) s += hr[j];
    s = blockReduceSum(s);
    const float m = s / DIMv;
    float v = 0.f;
    for (int j = threadIdx.x; j < DIMv; j += 256) { float d = hr[j] - m; v += d * d; }
    v = blockReduceSum(v);
    const float rstd = rsqrtf(v / DIMv + 1e-6f);
    const float* mb = modv + (size_t)b * mod_stride;
    for (int j = threadIdx.x; j < DIMv; j += 256) {
        float val = (hr[j] - m) * rstd * (1.f + mb[sc_off + j]) + mb[sh_off + j];
        if (BF) ((u16*)outv)[(size_t)row * DIMv + j] = f2bf(val);
        else ((float*)outv)[(size_t)row * DIMv + j] = val;
    }
}

// ---- dwconv for B/C channels only (256 ch), bf16 in/out ----
__global__ void dwconv_bc(const u16* __restrict__ zxb, const float* __restrict__ cw,
                          const float* __restrict__ cb, u16* __restrict__ xbcBC) {
    size_t i = (size_t)blockIdx.x * 256 + threadIdx.x;
    const size_t total = (size_t)Bv * Tv * 32;   // 256/8 chunks per row
    if (i >= total) return;
    const int c8 = (int)(i & 31) * 8;
    const size_t row = i >> 5;
    const int t = (int)(row % Tv);
    const u16* base = zxb + row * DINP + DINNER + c8;
    float acc[8];
    #pragma unroll
    for (int u = 0; u < 8; u++) acc[u] = cb[DINNER + c8 + u];
    #pragma unroll
    for (int k = 0; k < KCONVv; k++) {
        const int d = k - 3;
        if (t + d < 0) continue;
        short8v tv = *(const short8v*)(base + (ptrdiff_t)d * DINP);
        #pragma unroll
        for (int u = 0; u < 8; u++)
            acc[u] += bf2fs(tv[u]) * cw[(DINNER + c8 + u) * KCONVv + k];
    }
    short8v outv;
    #pragma unroll
    for (int u = 0; u < 8; u++) outv[u] = (short)f2bf(siluf(acc[u]));
    *(short8v*)(xbcBC + row * 256 + c8) = outv;
}

// ---- dwconv for x channels, writing TRANSPOSED xT[bc][p][s] (bf16) ----
__global__ __launch_bounds__(256) void dwconvT(const u16* __restrict__ zxb,
        const float* __restrict__ cw, const float* __restrict__ cb,
        u16* __restrict__ xT) {
    __shared__ __align__(16) u16 in_s[67 * 72];   // [s'][p], s' = 0..66 <-> t = c*64 + s' - 3
    const int pb = blockIdx.x;        // 0..23 (64 channels each)
    const int c = blockIdx.y, b = blockIdx.z;
    const int bc = b * CNv + c;
    const int tid = threadIdx.x;
    for (int e = tid; e < 67 * 8; e += 256) {
        int sp = e >> 3, p8 = (e & 7) * 8;
        int t = c * 64 + sp - 3;
        short8v v = {};
        if (t >= 0)
            v = *(const short8v*)&zxb[((size_t)b * Tv + t) * DINP + DINNER + pb * 64 + p8];
        *(short8v*)&in_s[sp * 72 + p8] = v;
    }
    __syncthreads();
    const int p = tid >> 2, sb = (tid & 3) * 16;
    const int ch = pb * 64 + p;
    const float w0 = cw[ch * 4], w1 = cw[ch * 4 + 1], w2 = cw[ch * 4 + 2], w3 = cw[ch * 4 + 3];
    const float bb = cb[ch];
    short8v o0, o1;
    #pragma unroll
    for (int i = 0; i < 16; i++) {
        int s = sb + i;
        float acc = bb + bf2f(in_s[s * 72 + p]) * w0 + bf2f(in_s[(s + 1) * 72 + p]) * w1
                  + bf2f(in_s[(s + 2) * 72 + p]) * w2 + bf2f(in_s[(s + 3) * 72 + p]) * w3;
        short r = (short)f2bf(siluf(acc));
        if (i < 8) o0[i] = r; else o1[i - 8] = r;
    }
    u16* dst = xT + ((size_t)bc * DINNER + ch) * 64 + sb;
    *(short8v*)dst = o0;
    *(short8v*)(dst + 8) = o1;
}

// ---- SSD: CB[q][s] = C.B^T (f32) and BTg[n][s] = B^T (bf16), per (b,c) ----
__global__ __launch_bounds__(256) void ssd_cb(const u16* __restrict__ xbcBC,
        float* __restrict__ CBg, u16* __restrict__ BTg) {
    constexpr int ST = 136;
    __shared__ __align__(16) u16 Cs[64 * ST];
    __shared__ __align__(16) u16 Bs[64 * ST];
    const int c = blockIdx.x, b = blockIdx.y;
    const int bc = b * CNv + c;
    const int tid = threadIdx.x;
    const size_t rowbase = (size_t)b * Tv + (size_t)c * QQv;
    for (int e = tid; e < 64 * 16; e += 256) {
        int r = e >> 4, n8 = (e & 15) * 8;
        const u16* src = &xbcBC[(rowbase + r) * 256];
        *(short8v*)&Bs[r * ST + n8] = *(const short8v*)(src + n8);
        *(short8v*)&Cs[r * ST + n8] = *(const short8v*)(src + NSv + n8);
    }
    __syncthreads();
    // transposed B to global (shared by all 24 heads in part1)
    u16* btg = BTg + (size_t)bc * (NSv * QQv);
    for (int e = tid; e < 128 * 64; e += 256) {
        int n = e >> 6, s = e & 63;
        btg[e] = Bs[s * ST + n];
    }
    const int lane = tid & 63, w = tid >> 6;
    const int lr = lane & 15, lk8 = (lane >> 4) * 8, rq = (lane >> 4) * 4;
    f32x4 acc[4] = {};
    #pragma unroll
    for (int ks = 0; ks < 4; ks++) {
        short8v a = *(const short8v*)&Cs[(w * 16 + lr) * ST + ks * 32 + lk8];
        #pragma unroll
        for (int j = 0; j < 4; j++) {
            short8v bf = *(const short8v*)&Bs[(j * 16 + lr) * ST + ks * 32 + lk8];
            acc[j] = __builtin_amdgcn_mfma_f32_16x16x32_bf16(a, bf, acc[j], 0, 0, 0);
        }
    }
    float* out = CBg + (size_t)bc * 4096;
    #pragma unroll
    for (int j = 0; j < 4; j++)
        #pragma unroll
        for (int r = 0; r < 4; r++)
            out[(w * 16 + rq + r) * 64 + j * 16 + lr] = acc[j][r];
}

// ---- SSD part1: scan; y_in = Wsm' @ xT^T; S = (xT.dtrev) @ B ----
// dt folded into Wsm (y_in) and into BT (S); xT tile is shared by both MFMAs.
__global__ __launch_bounds__(256) void ssd_part1m(const u16* __restrict__ xT,
        const u16* __restrict__ BTg, const u16* __restrict__ zxb,
        const float* __restrict__ dt_bias, const float* __restrict__ A_log,
        const float* __restrict__ CBg, u16* __restrict__ ybuf,
        float* __restrict__ Sg, float* __restrict__ acg, float* __restrict__ atg) {
    constexpr int ST64 = 72;
    __shared__ __align__(16) u16 xTs[64 * ST64];   // [p][s]
    __shared__ __align__(16) u16 Wsm[64 * ST64];   // [q][s]  (cb*exp*dt)
    __shared__ __align__(16) u16 BTs[128 * ST64];  // [n][s]  (B^T * dt*erev)
    __shared__ float ac[64], dts[64], dtrev[64];
    const int h = blockIdx.x, c = blockIdx.y, b = blockIdx.z;
    const int bc = b * CNv + c;
    const int tid = threadIdx.x;
    const size_t rowbase = (size_t)b * Tv + (size_t)c * QQv;
    const size_t bch = ((size_t)bc) * NHv + h;
    // phase A: wave0 scan (+derived), all threads copy xT tile
    if (tid < 64) {
        float raw = bf2f(zxb[(rowbase + tid) * DINP + DINNER + CONVD + h]) + dt_bias[h];
        float dtv = softplusf(raw);
        dts[tid] = dtv;
        float v = dtv * (-expf(A_log[h]));
        #pragma unroll
        for (int off = 1; off < 64; off <<= 1) {
            float t = __shfl_up(v, off, 64);
            if (tid >= off) v += t;
        }
        ac[tid] = v;
        float v63 = __shfl(v, 63, 64);
        dtrev[tid] = dtv * expf(v63 - v);
        acg[bch * 64 + tid] = v;
        if (tid == 63) atg[bch] = expf(v63);
    }
    {
        const u16* src = xT + ((size_t)bc * DINNER + h * PHv) * 64;
        for (int e = tid; e < 64 * 8; e += 256) {
            int p = e >> 3, s8 = (e & 7) * 8;
            *(short8v*)&xTs[p * ST64 + s8] = *(const short8v*)(src + p * 64 + s8);
        }
    }
    __syncthreads();
    // phase B: BT' (scale by dtrev) and Wsm (cb * exp(acq-acs) * dts)
    {
        const u16* btg = BTg + (size_t)bc * (NSv * QQv);
        for (int e = tid; e < 128 * 8; e += 256) {
            int n = e >> 3, s8 = (e & 7) * 8;
            short8v v = *(const short8v*)(btg + n * 64 + s8);
            short8v o;
            #pragma unroll
            for (int u = 0; u < 8; u++)
                o[u] = (short)f2bf(bf2fs(v[u]) * dtrev[s8 + u]);
            *(short8v*)&BTs[n * ST64 + s8] = o;
        }
        const float* cbrow = CBg + (size_t)bc * 4096;
        for (int e = tid; e < 1024; e += 256) {
            int q = e >> 4, s4 = (e & 15) * 4;
            f32x4 cb4 = *(const f32x4*)&cbrow[q * 64 + s4];
            float aq = ac[q];
            #pragma unroll
            for (int u = 0; u < 4; u++) {
                int s = s4 + u;
                float wv = (s <= q) ? cb4[u] * expf(aq - ac[s]) * dts[s] : 0.f;
                Wsm[q * ST64 + s] = f2bf(wv);
            }
        }
    }
    __syncthreads();
    const int lane = tid & 63, w = tid >> 6;
    const int lr = lane & 15, lk8 = (lane >> 4) * 8, rq = (lane >> 4) * 4;
    // y_in[q][p]
    {
        f32x4 acc[4] = {};
        #pragma unroll
        for (int ks = 0; ks < 2; ks++) {
            short8v bf = *(const short8v*)&xTs[(w * 16 + lr) * ST64 + ks * 32 + lk8];
            #pragma unroll
            for (int i = 0; i < 4; i++) {
                short8v a = *(const short8v*)&Wsm[(i * 16 + lr) * ST64 + ks * 32 + lk8];
                acc[i] = __builtin_amdgcn_mfma_f32_16x16x32_bf16(a, bf, acc[i], 0, 0, 0);
            }
        }
        #pragma unroll
        for (int i = 0; i < 4; i++)
            #pragma unroll
            for (int r = 0; r < 4; r++) {
                int q = i * 16 + rq + r, p = w * 16 + lr;
                ybuf[(rowbase + q) * DINNER + h * PHv + p] = f2bf(acc[i][r]);
            }
    }
    // S[p][n]
    {
        f32x4 acc[4][2] = {};
        #pragma unroll
        for (int ks = 0; ks < 2; ks++) {
            short8v a[4];
            #pragma unroll
            for (int i = 0; i < 4; i++)
                a[i] = *(const short8v*)&xTs[(i * 16 + lr) * ST64 + ks * 32 + lk8];
            #pragma unroll
            for (int j = 0; j < 2; j++) {
                short8v bf = *(const short8v*)&BTs[(w * 32 + j * 16 + lr) * ST64 + ks * 32 + lk8];
                #pragma unroll
                for (int i = 0; i < 4; i++)
                    acc[i][j] = __builtin_amdgcn_mfma_f32_16x16x32_bf16(a[i], bf, acc[i][j], 0, 0, 0);
            }
        }
        float* So = Sg + bch * (PHv * NSv);
        #pragma unroll
        for (int i = 0; i < 4; i++)
            #pragma unroll
            for (int j = 0; j < 2; j++)
                #pragma unroll
                for (int r = 0; r < 4; r++)
                    So[(i * 16 + rq + r) * NSv + w * 32 + j * 16 + lr] = acc[i][j][r];
    }
}

// ---- inter-chunk scan ----
__global__ void ssd_scan(float* __restrict__ Sg, const float* __restrict__ atg) {
    int idx = blockIdx.x * 256 + threadIdx.x;
    if (idx >= Bv * NHv * PHv * NSv) return;
    int n = idx % NSv;
    int p = (idx / NSv) % PHv;
    int h = (idx / (NSv * PHv)) % NHv;
    int b = idx / (NSv * PHv * NHv);
    float H = 0.f;
    for (int c = 0; c < CNv; c++) {
        size_t bch = ((size_t)b * CNv + c) * NHv + h;
        size_t off = bch * PHv * NSv + (size_t)p * NSv + n;
        float s = Sg[off];
        float at = atg[bch];
        Sg[off] = H;
        H = at * H + s;
    }
}

// ---- SSD part2: y += (C @ prev^T)*eac + D*x ----
__global__ __launch_bounds__(256) void ssd_part2m(const u16* __restrict__ xbcBC,
        const u16* __restrict__ xT, const float* __restrict__ Sg,
        const float* __restrict__ acg, const float* __restrict__ Dp,
        u16* __restrict__ ybuf) {
    constexpr int ST = 136;
    __shared__ __align__(16) u16 Cs[64 * ST];
    __shared__ __align__(16) u16 Ps[64 * ST];
    __shared__ float eac[64];
    const int h = blockIdx.x, c = blockIdx.y, b = blockIdx.z;
    const int bc = b * CNv + c;
    const int tid = threadIdx.x;
    const size_t rowbase = (size_t)b * Tv + (size_t)c * QQv;
    const size_t bch = ((size_t)bc) * NHv + h;
    if (tid < 64) eac[tid] = expf(acg[bch * 64 + tid]);
    for (int e = tid; e < 64 * 16; e += 256) {
        int r = e >> 4, n8 = (e & 15) * 8;
        *(short8v*)&Cs[r * ST + n8] =
            *(const short8v*)&xbcBC[(rowbase + r) * 256 + NSv + n8];
        const float* src = &Sg[bch * (PHv * NSv) + (size_t)r * NSv + n8];
        f32x4 a = *(const f32x4*)src, b4 = *(const f32x4*)(src + 4);
        short8v o;
        o[0] = (short)f2bf(a[0]); o[1] = (short)f2bf(a[1]);
        o[2] = (short)f2bf(a[2]); o[3] = (short)f2bf(a[3]);
        o[4] = (short)f2bf(b4[0]); o[5] = (short)f2bf(b4[1]);
        o[6] = (short)f2bf(b4[2]); o[7] = (short)f2bf(b4[3]);
        *(short8v*)&Ps[r * ST + n8] = o;
    }
    __syncthreads();
    const int lane = tid & 63, w = tid >> 6;
    const int lr = lane & 15, lk8 = (lane >> 4) * 8, rq = (lane >> 4) * 4;
    f32x4 acc[4] = {};
    #pragma unroll
    for (int ks = 0; ks < 4; ks++) {
        short8v bf = *(const short8v*)&Ps[(w * 16 + lr) * ST + ks * 32 + lk8];
        #pragma unroll
        for (int i = 0; i < 4; i++) {
            short8v a = *(const short8v*)&Cs[(i * 16 + lr) * ST + ks * 32 + lk8];
            acc[i] = __builtin_amdgcn_mfma_f32_16x16x32_bf16(a, bf, acc[i], 0, 0, 0);
        }
    }
    const float Dh = Dp[h];
    const int p = w * 16 + lr;
    const u16* xrow = xT + ((size_t)bc * DINNER + h * PHv + p) * 64;
    #pragma unroll
    for (int i = 0; i < 4; i++)
        #pragma unroll
        for (int r = 0; r < 4; r++) {
            int q = i * 16 + rq + r;
            size_t yi = (rowbase + q) * DINNER + h * PHv + p;
            float xv = bf2f(xrow[q]);
            ybuf[yi] = f2bf(bf2f(ybuf[yi]) + acc[i][r] * eac[q] + Dh * xv);
        }
}

// ---- gate by silu(z), RMS norm, * rms_w (bf16 in/out) ----
__global__ __launch_bounds__(256) void gate_rms_kernel(const u16* __restrict__ y,
        const u16* __restrict__ zxb, const float* __restrict__ rms_w,
        u16* __restrict__ yb) {
    const int row = blockIdx.x;
    const u16* yr = y + (size_t)row * DINNER;
    const u16* zr = zxb + (size_t)row * DINP;
    float vals[8];
    float ss = 0.f;
    const int tid = threadIdx.x;
    if (tid < 192) {
        short8v yv = *(const short8v*)(yr + tid * 8);
        short8v zv = *(const short8v*)(zr + tid * 8);
        #pragma unroll
        for (int u = 0; u < 8; u++) {
            float v = bf2fs(yv[u]) * siluf(bf2fs(zv[u]));
            vals[u] = v;
            ss += v * v;
        }
    }
    ss = blockReduceSum(ss);
    const float scale = rsqrtf(ss / DINNER + 1e-5f);
    if (tid < 192) {
        short8v outv;
        #pragma unroll
        for (int u = 0; u < 8; u++)
            outv[u] = (short)f2bf(vals[u] * scale * rms_w[tid * 8 + u]);
        *(short8v*)(yb + (size_t)row * DINNER + tid * 8) = outv;
    }
}

extern "C" void kernel_launch(void* const* d_in, const int* in_sizes, int n_in,
                              void* d_out, int out_size, void* d_ws, size_t ws_size,
                              hipStream_t stream) {
    int s3 = (in_sizes[3] == Bv * NTv) ? 1 : 0;
    const float* x      = (const float*)d_in[0];
    const float* cond   = (const float*)d_in[1];
    const float* timev  = (const float*)d_in[2];
    const int*   text   = (const int*)(s3 ? d_in[3] : d_in[32]);
    const float* table  = (const float*)d_in[3 + s3];
    const float* inp_w  = (const float*)d_in[4 + s3];
    const float* inp_b  = (const float*)d_in[5 + s3];
    const float* pos_w1 = (const float*)d_in[6 + s3];
    const float* pos_b1 = (const float*)d_in[7 + s3];
    const float* pos_w2 = (const float*)d_in[8 + s3];
    const float* pos_b2 = (const float*)d_in[9 + s3];
    const float* t_w1   = (const float*)d_in[10 + s3];
    const float* t_b1   = (const float*)d_in[11 + s3];
    const float* t_w2   = (const float*)d_in[12 + s3];
    const float* t_b2   = (const float*)d_in[13 + s3];
    const float* adaln_w= (const float*)d_in[14 + s3];
    const float* adaln_b= (const float*)d_in[15 + s3];
    const float* in_w   = (const float*)d_in[16 + s3];
    const float* conv_w = (const float*)d_in[17 + s3];
    const float* conv_b = (const float*)d_in[18 + s3];
    const float* dt_bias= (const float*)d_in[19 + s3];
    const float* A_log  = (const float*)d_in[20 + s3];
    const float* Dp     = (const float*)d_in[21 + s3];
    const float* rms_w  = (const float*)d_in[22 + s3];
    const float* out_w  = (const float*)d_in[23 + s3];
    const float* ff_w1  = (const float*)d_in[24 + s3];
    const float* ff_b1  = (const float*)d_in[25 + s3];
    const float* ff_w2  = (const float*)d_in[26 + s3];
    const float* ff_b2  = (const float*)d_in[27 + s3];
    const float* fin_w  = (const float*)d_in[28 + s3];
    const float* fin_b  = (const float*)d_in[29 + s3];
    const float* proj_w = (const float*)d_in[30 + s3];
    const float* proj_b = (const float*)d_in[31 + s3];

    // ---- workspace layout ----
    float* ws = (float*)d_ws;
    const size_t n_h = (size_t)Bv * Tv * DIMv;
    size_t off = 0;
    auto nx = [&](size_t n) { float* p = ws + off; off += n; return p; };
    float* h_   = nx(n_h);
    float* S_   = nx((size_t)Bv * CNv * NHv * PHv * NSv);
    float* ac_  = nx((size_t)Bv * CNv * NHv * QQv);
    float* at_  = nx((size_t)Bv * CNv * NHv);
    float* CB_  = nx((size_t)Bv * CNv * QQv * QQv);
    float* st_  = nx((size_t)Bv * DIMv);
    float* hid_ = nx((size_t)Bv * DIMv);
    float* mod_ = nx((size_t)DEPTHv * Bv * 6 * DIMv);
    float* fm_  = nx((size_t)Bv * 2 * DIMv);
    off = (off + 15) & ~(size_t)15;
    u16* wtin_  = (u16*)(ws + off);
    u16* wtout_ = wtin_  + (size_t)DEPTHv * 3456 * 768;
    u16* wtff1_ = wtout_ + (size_t)DEPTHv * 768 * 1536;
    u16* wtff2_ = wtff1_ + (size_t)DEPTHv * 1536 * 768;
    u16* wtinp_ = wtff2_ + (size_t)DEPTHv * 768 * 1536;
    u16* wtprj_ = wtinp_ + (size_t)768 * KCAT;
    u16* pwt1_  = wtprj_ + (size_t)128 * 768;
    u16* pwt2_  = pwt1_  + (size_t)768 * PCK;
    u16* zxb_   = pwt2_  + (size_t)768 * PCK;     // 4096x3352
    u16* xbcBC_ = zxb_   + (size_t)4096 * DINP;   // 4096x256
    u16* xT_    = xbcBC_ + (size_t)4096 * 256;    // 64 x 1536 x 64
    u16* BTg_   = xT_    + (size_t)64 * DINNER * 64;  // 64 x 128 x 64
    u16* yb_    = BTg_   + (size_t)64 * NSv * 64; // 4096x1536
    u16* xnb_   = yb_    + (size_t)4096 * 1536;   // 4096x768
    u16* actb_  = xnb_   + (size_t)4096 * 768;    // 4096x1536
    u16* xnb2_  = actb_  + (size_t)4096 * 1536;   // 4096x768
    u16* catb_  = xnb2_  + (size_t)4096 * 768;    // 4096x736

    const int MT = Bv * Tv;

    // ---- batched weight conversions (all layers upfront) ----
    wt_convert_b<<<dim3(3456 / 32, 768 / 32, DEPTHv), 256, 0, stream>>>(
        in_w, wtin_, 768, DINP, DIMv, 3456);
    wt_convert_b<<<dim3(768 / 32, 1536 / 32, DEPTHv), 256, 0, stream>>>(
        out_w, wtout_, 1536, DIMv, DINNER, 768);
    wt_convert_b<<<dim3(1536 / 32, 768 / 32, DEPTHv), 256, 0, stream>>>(
        ff_w1, wtff1_, 768, FFIv, DIMv, 1536);
    wt_convert_b<<<dim3(768 / 32, 1536 / 32, DEPTHv), 256, 0, stream>>>(
        ff_w2, wtff2_, 1536, DIMv, FFIv, 768);
    wt_convert_b<<<dim3(768 / 32, KCAT / 32, 1), 256, 0, stream>>>(
        inp_w, wtinp_, KCAT, DIMv, 712, 768);
    wt_convert_b<<<dim3(128 / 32, 768 / 32, 1), 256, 0, stream>>>(
        proj_w, wtprj_, 768, MELv, DIMv, 128);
    pw_convert<<<dim3(PCK / 32, DIMv / 32), 256, 0, stream>>>(pos_w1, pwt1_);
    pw_convert<<<dim3(PCK / 32, DIMv / 32), 256, 0, stream>>>(pos_w2, pwt2_);

    // time embedding + modulation vectors
    temb1_kernel<<<dim3(DIMv / 64, Bv), 256, 0, stream>>>(timev, t_w1, t_b1, hid_);
    temb2_kernel<<<dim3(DIMv / 64, Bv), 256, 0, stream>>>(hid_, t_w2, t_b2, st_);
    modvec_kernel<<<dim3(6 * DIMv / 64, Bv, DEPTHv), 256, 0, stream>>>(st_, adaln_w, adaln_b, mod_, 6 * DIMv);
    modvec_kernel<<<dim3(2 * DIMv / 64, Bv, 1), 256, 0, stream>>>(st_, fin_w, fin_b, fm_, 2 * DIMv);

    // input concat + projection
    concat_bf16<<<(unsigned)(((size_t)Bv * Tv * KCAT + 255) / 256), 256, 0, stream>>>(
        x, cond, table, text, catb_);
    gemm_bf16<1, 0><<<dim3(6, 64), 256, 0, stream>>>(
        catb_, wtinp_, inp_b, h_, nullptr, MT, DIMv, KCAT, DIMv, nullptr, 0, 0);

    // pos-conv block
    posconv_mfma<0, 0><<<dim3(Tv / 64, 16, Bv), 256, 0, stream>>>(h_, pwt1_, pos_b1, xnb2_);
    posconv_mfma<1, 1><<<dim3(Tv / 64, 16, Bv), 256, 0, stream>>>(xnb2_, pwt2_, pos_b2, h_);

    for (int l = 0; l < DEPTHv; l++) {
        const float* modl = mod_ + (size_t)l * Bv * 6 * DIMv;
        const float* cwl = conv_w + (size_t)l * CONVD * KCONVv;
        const float* cbl = conv_b + (size_t)l * CONVD;
        // ---- MSA/SSD branch ----
        ln_mod_kernel<1><<<MT, 256, 0, stream>>>(h_, xnb_, modl, DIMv, 0, 6 * DIMv);
        gemm_bf16<0, 1><<<dim3(27, 32), 256, 0, stream>>>(
            xnb_, wtin_ + (size_t)l * 3456 * 768, nullptr, nullptr, zxb_,
            MT, DINP, DIMv, DINP, nullptr, 0, 0);
        dwconv_bc<<<(unsigned)(((size_t)Bv * Tv * 32 + 255) / 256), 256, 0, stream>>>(
            zxb_, cwl, cbl, xbcBC_);
        dwconvT<<<dim3(DINNER / 64, CNv, Bv), 256, 0, stream>>>(zxb_, cwl, cbl, xT_);
        ssd_cb<<<dim3(CNv, Bv), 256, 0, stream>>>(xbcBC_, CB_, BTg_);
        ssd_part1m<<<dim3(NHv, CNv, Bv), 256, 0, stream>>>(
            xT_, BTg_, zxb_, dt_bias + l * NHv, A_log + l * NHv, CB_, yb_, S_, ac_, at_);
        ssd_scan<<<(Bv * NHv * PHv * NSv + 255) / 256, 256, 0, stream>>>(S_, at_);
        ssd_part2m<<<dim3(NHv, CNv, Bv), 256, 0, stream>>>(
            xbcBC_, xT_, S_, ac_, Dp + l * NHv, yb_);
        gate_rms_kernel<<<MT, 256, 0, stream>>>(yb_, zxb_, rms_w + (size_t)l * DINNER, actb_);
        gemm_bf16<3, 0><<<dim3(6, 64), 256, 0, stream>>>(
            actb_, wtout_ + (size_t)l * 768 * 1536, nullptr, h_, nullptr,
            MT, DIMv, DINNER, DIMv, modl, 2 * DIMv, 6 * DIMv);
        // ---- MLP branch ----
        ln_mod_kernel<1><<<MT, 256, 0, stream>>>(h_, xnb_, modl, 4 * DIMv, 3 * DIMv, 6 * DIMv);
        gemm_bf16<2, 1><<<dim3(12, 32), 256, 0, stream>>>(
            xnb_, wtff1_ + (size_t)l * 1536 * 768, ff_b1 + (size_t)l * FFIv, nullptr, actb_,
            MT, FFIv, DIMv, FFIv, nullptr, 0, 0);
        gemm_bf16<4, 0><<<dim3(6, 64), 256, 0, stream>>>(
            actb_, wtff2_ + (size_t)l * 768 * 1536, ff_b2 + (size_t)l * DIMv, h_, nullptr,
            MT, DIMv, FFIv, DIMv, modl, 5 * DIMv, 6 * DIMv);
    }

    // final modulated LN + projection
    ln_mod_kernel<1><<<MT, 256, 0, stream>>>(h_, xnb_, fm_, 0, DIMv, 2 * DIMv);
    gemm_bf16<1, 0><<<dim3(1, 64), 256, 0, stream>>>(
        xnb_, wtprj_, proj_b, (float*)d_out, nullptr, MT, MELv, DIMv, MELv, nullptr, 0, 0);
}